// Round 7
// baseline (1784.183 us; speedup 1.0000x reference)
//
#include <hip/hip_runtime.h>
#include <hip/hip_bf16.h>

typedef __bf16 bf16x8 __attribute__((ext_vector_type(8)));
typedef float f32x4 __attribute__((ext_vector_type(4)));
typedef unsigned long long u64;

#define EPSV 1e-5f

__device__ __forceinline__ float bf2f(unsigned short u){
  unsigned int x = ((unsigned int)u) << 16;
  return __builtin_bit_cast(float, x);
}
__device__ __forceinline__ unsigned short f2bf(float f){
  __bf16 b = (__bf16)f;
  return __builtin_bit_cast(unsigned short, b);
}
__device__ __forceinline__ float gelu_exact(float x){
  return 0.5f * x * (1.0f + erff(x * 0.7071067811865476f));
}
__device__ __forceinline__ void gload_lds16(const void* g, void* l){
  __builtin_amdgcn_global_load_lds((const __attribute__((address_space(1))) unsigned int*)g,
                                   (__attribute__((address_space(3))) unsigned int*)l, 16, 0, 0);
}

#define VMGATE4() asm volatile("s_waitcnt vmcnt(4)" ::: "memory")

// ---------------------------------------------------------------------------
// 256x256 (BK=64) 8-wave software-pipelined bf16 MFMA GEMM.
// C = A[M,K] * Bt[N,K]^T (+bias). MODE 0: bias+GELU dual; 1: bias; 3: V^T;
// 4: dual K/V^T split at col 4096.
//
// Pipeline: fragments for phase p+1 are ds_read in phase p; the compiler's
// SSA-tracked auto-lgkmcnt(N) lets phase p's MFMA run while those reads fly
// (LDS pipe streams under the matrix pipe; lockstep cost was MfmaUtil 47%).
// Slice order S1(a0,b0) S4(a1,b0) S2(a0,b1) S3(a1,b1) makes every fragment
// buffer dead before its reload -> no extra registers.
//   PH1: rd a1(kt)[8];           stage B.r64-127(kt+1); MFMA S1
//   PH2: rd b1(kt)[4];           stage A.q1(kt+1);      MFMA S4
//   PH3: -                       stage A.q0(kt+2);      MFMA S2
//   PH4: rd a0,b0(kt+1)[12];     stage B.r0-63(kt+2);   MFMA S3
// Uniform vmcnt(4) after each MFMA (before the closing barrier): anything
// staged >=3 phases earlier is landed; every read's source is staged >=3
// phases before it executes (hand-checked per region). Never drains to 0.
// LDS overwrite hazards: every stage targets a region whose last ds_read was
// >=2 phases (>=4 barriers) earlier. XOR swizzle unchanged (both-sides, G21).
// ---------------------------------------------------------------------------
template<int MODE>
__global__ __launch_bounds__(512, 2)
void gemm256(const unsigned short* __restrict__ A, const unsigned short* __restrict__ B,
             const float* __restrict__ bias0, const float* __restrict__ bias1,
             void* __restrict__ C0v, void* __restrict__ C1v,
             int Kd, int lda, int ldb, int ldc)
{
  __shared__ char smem[131072];  // A: [2 dbuf][2 half][128][64]b16 @0; B same @65536
  const int t = threadIdx.x;
  const int w = t >> 6, l = t & 63;
  const int wm = w >> 2, wn = w & 3;        // wave grid 2(M) x 4(N)
  const int lr = l & 15, lg = l >> 4;
  const int nbx = gridDim.x;
  const int nwg = nbx * gridDim.y;
  int bid = blockIdx.y*nbx + blockIdx.x;
  if ((nwg & 7) == 0) bid = (bid & 7)*(nwg >> 3) + (bid >> 3);
  const int bm0 = (bid / nbx) * 256, bn0 = (bid % nbx) * 256;
  const int nk = Kd >> 6;

  const int srow = t >> 3;                   // staging row-within-quarter 0..63
  const int sslot = t & 7;                   // staging 16B slot

  f32x4 acc[8][4];
  #pragma unroll
  for (int i=0;i<8;++i){
    #pragma unroll
    for (int j=0;j<4;++j){ f32x4 zz = {0.f,0.f,0.f,0.f}; acc[i][j] = zz; }
  }
  bf16x8 a0[4][2], a1[4][2], b0[2][2], b1[2][2];

  auto stage = [&](int kt, int mat, int hf, int q){
    if (kt >= nk) return;
    const int r_h = q*64 + srow;
    const int s_ = sslot ^ ((r_h >> 1) & 7);
    const unsigned short* gp = (mat ? B + (size_t)(bn0 + hf*128 + r_h)*ldb
                                    : A + (size_t)(bm0 + hf*128 + r_h)*lda)
                               + (kt << 6) + s_*8;
    char* lp = smem + mat*65536 + (kt&1)*32768 + hf*16384 + q*8192 + t*16;
    gload_lds16((const void*)gp, (void*)lp);
  };
  auto rdA = [&](int d, int fm, int kk)->bf16x8{
    const int r = fm*16 + lr;
    const int s_ = (kk*4 + lg) ^ ((r >> 1) & 7);
    return *(const bf16x8*)(smem + d*32768 + wm*16384 + r*128 + s_*16);
  };
  auto rdB = [&](int d, int fn, int kk)->bf16x8{
    const int r = (wn&1)*64 + fn*16 + lr;
    const int s_ = (kk*4 + lg) ^ ((r >> 1) & 7);
    return *(const bf16x8*)(smem + 65536 + d*32768 + (wn>>1)*16384 + r*128 + s_*16);
  };

  auto ktile = [&](int kt, int d){
    // ---- PH1: MFMA S1 (a0,b0) ; read a1(kt) ; stage B.r64-127(kt+1) ----
    #pragma unroll
    for (int fm=0; fm<4; ++fm){ a1[fm][0] = rdA(d, fm+4, 0); a1[fm][1] = rdA(d, fm+4, 1); }
    stage(kt+1, 1, 0, 1); stage(kt+1, 1, 1, 1);
    __builtin_amdgcn_s_barrier();
    __builtin_amdgcn_s_setprio(1);
    #pragma unroll
    for (int fm=0; fm<4; ++fm)
      #pragma unroll
      for (int fn=0; fn<2; ++fn)
        #pragma unroll
        for (int kk=0; kk<2; ++kk)
          acc[fm][fn] = __builtin_amdgcn_mfma_f32_16x16x32_bf16(a0[fm][kk], b0[fn][kk], acc[fm][fn], 0,0,0);
    __builtin_amdgcn_s_setprio(0);
    VMGATE4();
    __builtin_amdgcn_s_barrier();
    // ---- PH2: MFMA S4 (a1,b0) ; read b1(kt) ; stage A.q1(kt+1) ----
    #pragma unroll
    for (int fn=0; fn<2; ++fn){ b1[fn][0] = rdB(d, fn+2, 0); b1[fn][1] = rdB(d, fn+2, 1); }
    stage(kt+1, 0, 0, 1); stage(kt+1, 0, 1, 1);
    __builtin_amdgcn_s_barrier();
    __builtin_amdgcn_s_setprio(1);
    #pragma unroll
    for (int fm=0; fm<4; ++fm)
      #pragma unroll
      for (int fn=0; fn<2; ++fn)
        #pragma unroll
        for (int kk=0; kk<2; ++kk)
          acc[fm+4][fn] = __builtin_amdgcn_mfma_f32_16x16x32_bf16(a1[fm][kk], b0[fn][kk], acc[fm+4][fn], 0,0,0);
    __builtin_amdgcn_s_setprio(0);
    VMGATE4();
    __builtin_amdgcn_s_barrier();
    // ---- PH3: MFMA S2 (a0,b1) ; stage A.q0(kt+2) ----
    stage(kt+2, 0, 0, 0); stage(kt+2, 0, 1, 0);
    __builtin_amdgcn_s_barrier();
    __builtin_amdgcn_s_setprio(1);
    #pragma unroll
    for (int fm=0; fm<4; ++fm)
      #pragma unroll
      for (int fn=0; fn<2; ++fn)
        #pragma unroll
        for (int kk=0; kk<2; ++kk)
          acc[fm][fn+2] = __builtin_amdgcn_mfma_f32_16x16x32_bf16(a0[fm][kk], b1[fn][kk], acc[fm][fn+2], 0,0,0);
    __builtin_amdgcn_s_setprio(0);
    VMGATE4();
    __builtin_amdgcn_s_barrier();
    // ---- PH4: MFMA S3 (a1,b1) ; read a0,b0(kt+1) ; stage B.r0-63(kt+2) ----
    if (kt+1 < nk){
      #pragma unroll
      for (int fm=0; fm<4; ++fm){ a0[fm][0] = rdA(d^1, fm, 0); a0[fm][1] = rdA(d^1, fm, 1); }
      #pragma unroll
      for (int fn=0; fn<2; ++fn){ b0[fn][0] = rdB(d^1, fn, 0); b0[fn][1] = rdB(d^1, fn, 1); }
    }
    stage(kt+2, 1, 0, 0); stage(kt+2, 1, 1, 0);
    __builtin_amdgcn_s_barrier();
    __builtin_amdgcn_s_setprio(1);
    #pragma unroll
    for (int fm=0; fm<4; ++fm)
      #pragma unroll
      for (int fn=0; fn<2; ++fn)
        #pragma unroll
        for (int kk=0; kk<2; ++kk)
          acc[fm+4][fn+2] = __builtin_amdgcn_mfma_f32_16x16x32_bf16(a1[fm][kk], b1[fn][kk], acc[fm+4][fn+2], 0,0,0);
    __builtin_amdgcn_s_setprio(0);
    VMGATE4();
    __builtin_amdgcn_s_barrier();
  };

  // prologue: t0 full (Aq0,B063,B64,Aq1) + t1 Aq0 + t1 B063 (12 loads)
  stage(0,0,0,0); stage(0,0,1,0);
  stage(0,1,0,0); stage(0,1,1,0);
  stage(0,1,0,1); stage(0,1,1,1);
  stage(0,0,0,1); stage(0,0,1,1);
  stage(1,0,0,0); stage(1,0,1,0);
  stage(1,1,0,0); stage(1,1,1,0);
  asm volatile("s_waitcnt vmcnt(6)" ::: "memory");   // Aq0(t0)+B(t0) landed
  __builtin_amdgcn_s_barrier();
  #pragma unroll
  for (int fm=0; fm<4; ++fm){ a0[fm][0] = rdA(0, fm, 0); a0[fm][1] = rdA(0, fm, 1); }
  #pragma unroll
  for (int fn=0; fn<2; ++fn){ b0[fn][0] = rdB(0, fn, 0); b0[fn][1] = rdB(0, fn, 1); }
  VMGATE4();                                          // Aq1(t0) landed
  __builtin_amdgcn_s_barrier();

  for (int kt = 0; kt < nk; kt += 2){ ktile(kt, 0); ktile(kt+1, 1); }

  // epilogue
  #pragma unroll
  for (int fm=0; fm<8; ++fm){
    #pragma unroll
    for (int fn=0; fn<4; ++fn){
      const int row0 = bm0 + wm*128 + fm*16 + lg*4;
      const int col  = bn0 + wn*64 + fn*16 + lr;
      f32x4 v = acc[fm][fn];
      if constexpr (MODE == 3){
        unsigned short* C = (unsigned short*)C0v;
        const float bb = bias0[col];
        u64 pack = 0;
        #pragma unroll
        for (int j=0;j<4;++j) pack |= (u64)f2bf(v[j] + bb) << (16*j);
        *(u64*)(C + (size_t)col*256 + (size_t)(row0>>8)*1048576 + (row0&255)) = pack;
      } else if constexpr (MODE == 4){
        if (col < 4096){
          unsigned short* C = (unsigned short*)C0v;
          const float bb = bias0[col];
          #pragma unroll
          for (int j=0;j<4;++j) C[(size_t)(row0+j)*ldc + col] = f2bf(v[j] + bb);
        } else {
          const int c2 = col - 4096;
          unsigned short* C = (unsigned short*)C1v;
          const float bb = bias1[c2];
          u64 pack = 0;
          #pragma unroll
          for (int j=0;j<4;++j) pack |= (u64)f2bf(v[j] + bb) << (16*j);
          *(u64*)(C + (size_t)c2*256 + (size_t)(row0>>8)*1048576 + (row0&255)) = pack;
        }
      } else {
        const bool hi = (MODE == 0) && (col >= 4096);
        unsigned short* C = (unsigned short*)(hi ? C1v : C0v);
        const int c2 = hi ? (col - 4096) : col;
        const float bb = hi ? bias1[c2] : bias0[c2];
        #pragma unroll
        for (int j=0;j<4;++j){
          float x = v[j] + bb;
          if constexpr (MODE==0) x = gelu_exact(x);
          C[(size_t)(row0+j)*ldc + c2] = f2bf(x);
        }
      }
    }
  }
}

// ---------------------------------------------------------------------------
// 128x128 (BK=32) bf16 MFMA GEMM (small attention GEMMs). MODE 2: *scale->fp32.
// ---------------------------------------------------------------------------
template<int MODE>
__global__ __launch_bounds__(256)
void gemm_bt(const unsigned short* __restrict__ A, const unsigned short* __restrict__ B,
             const float* __restrict__ bias, void* __restrict__ Cv,
             int Kd, int lda, int ldb, int ldc,
             long sA2, long sA1, long sB2, long sB1, long sC2, long sC1,
             float scale)
{
  __shared__ unsigned short lds[2][2][4096];
  const int t = threadIdx.x;
  const int w = t >> 6, l = t & 63;
  const int z = blockIdx.z;
  A += (size_t)(z>>2)*sA2 + (size_t)(z&3)*sA1;
  B += (size_t)(z>>2)*sB2 + (size_t)(z&3)*sB1;
  const int bm0 = blockIdx.y * 128, bn0 = blockIdx.x * 128;
  const int nk = Kd >> 5;

  const int sr = l >> 2;
  const int ss = l & 3;

  f32x4 acc[4][4];
  #pragma unroll
  for (int i=0;i<4;++i){
    #pragma unroll
    for (int j=0;j<4;++j){ f32x4 zz = {0.f,0.f,0.f,0.f}; acc[i][j] = zz; }
  }

  const int wm = w >> 1, wn = w & 1;
  const int lr = l & 15, lg = l >> 4;

  auto stage = [&](int kt, int bb){
    const int k0 = kt << 5;
    #pragma unroll
    for (int i=0;i<2;++i){
      const int r  = w*32 + i*16 + sr;
      const int sa = ss ^ ((r>>1)&3);
      const unsigned short* ga = A + (size_t)(bm0 + r)*lda + (k0 + sa*8);
      gload_lds16((const void*)ga, (void*)((char*)&lds[bb][0][0] + w*2048 + i*1024));
      const unsigned short* gb = B + (size_t)(bn0 + r)*ldb + (k0 + sa*8);
      gload_lds16((const void*)gb, (void*)((char*)&lds[bb][1][0] + w*2048 + i*1024));
    }
  };

  int buf = 0;
  stage(0, 0);
  for (int kt=0; kt<nk; ++kt){
    __syncthreads();
    if (kt+1 < nk) stage(kt+1, buf^1);
    bf16x8 av[4], bv[4];
    #pragma unroll
    for (int fm=0; fm<4; ++fm){
      const int row = wm*64 + fm*16 + lr;
      const int sl  = lg ^ ((row>>1)&3);
      av[fm] = *(const bf16x8*)((const char*)&lds[buf][0][0] + row*64 + sl*16);
    }
    #pragma unroll
    for (int fn=0; fn<4; ++fn){
      const int col = wn*64 + fn*16 + lr;
      const int sl  = lg ^ ((col>>1)&3);
      bv[fn] = *(const bf16x8*)((const char*)&lds[buf][1][0] + col*64 + sl*16);
    }
    #pragma unroll
    for (int fm=0; fm<4; ++fm){
      #pragma unroll
      for (int fn=0; fn<4; ++fn)
        acc[fm][fn] = __builtin_amdgcn_mfma_f32_16x16x32_bf16(av[fm], bv[fn], acc[fm][fn], 0,0,0);
    }
    buf ^= 1;
  }

  const size_t coff = (size_t)(z>>2)*sC2 + (size_t)(z&3)*sC1;
  #pragma unroll
  for (int fm=0; fm<4; ++fm){
    #pragma unroll
    for (int fn=0; fn<4; ++fn){
      const int row0 = bm0 + wm*64 + fm*16 + lg*4;
      const int col  = bn0 + wn*64 + fn*16 + lr;
      f32x4 v = acc[fm][fn];
      if constexpr (MODE == 2){
        float* C = (float*)Cv + coff;
        #pragma unroll
        for (int j=0;j<4;++j) C[(size_t)(row0+j)*ldc + col] = v[j]*scale;
      }
    }
  }
}

// ---------------------------------------------------------------------------
__global__ __launch_bounds__(256)
void k_convh(const float* __restrict__ in, unsigned short* __restrict__ out){
  const size_t id = (size_t)blockIdx.x*256 + threadIdx.x;
  float4 v = ((const float4*)in)[id];
  u64 pack = (u64)f2bf(v.x) | ((u64)f2bf(v.y)<<16) | ((u64)f2bf(v.z)<<32) | ((u64)f2bf(v.w)<<48);
  *(u64*)(out + id*4) = pack;
}

__global__ __launch_bounds__(256)
void k_tconv(const float* __restrict__ W, unsigned short* __restrict__ Wt, int Kd, int N){
  __shared__ float lt[64][65];
  const int t = threadIdx.x;
  const int n0 = blockIdx.x*64, k0 = blockIdx.y*64;
  #pragma unroll
  for (int i=0;i<16;++i){
    int lin = i*256 + t; int r = lin>>6, c = lin&63;
    lt[r][c] = W[(size_t)(k0+r)*N + n0 + c];
  }
  __syncthreads();
  #pragma unroll
  for (int i=0;i<16;++i){
    int lin = i*256 + t; int n = lin>>6, k = lin&63;
    Wt[(size_t)(n0+n)*Kd + k0 + k] = f2bf(lt[k][n]);
  }
}

__global__ __launch_bounds__(256)
void k_softmax(const float* __restrict__ S, unsigned short* __restrict__ P){
  const int t = threadIdx.x, w = t>>6, l = t&63;
  const size_t row = (size_t)blockIdx.x*4 + w;
  float4 v = *(const float4*)(S + row*256 + l*4);
  float m = fmaxf(fmaxf(v.x,v.y), fmaxf(v.z,v.w));
  #pragma unroll
  for (int off=32; off; off>>=1) m = fmaxf(m, __shfl_xor(m, off));
  float e0 = expf(v.x-m), e1 = expf(v.y-m), e2 = expf(v.z-m), e3 = expf(v.w-m);
  float s = e0+e1+e2+e3;
  #pragma unroll
  for (int off=32; off; off>>=1) s += __shfl_xor(s, off);
  const float inv = 1.0f/s;
  u64 pack = (u64)f2bf(e0*inv) | ((u64)f2bf(e1*inv)<<16) | ((u64)f2bf(e2*inv)<<32) | ((u64)f2bf(e3*inv)<<48);
  *(u64*)(P + row*256 + l*4) = pack;
}

__device__ __forceinline__ void blkred2(float& a, float& b, float* sred, int t){
  #pragma unroll
  for (int off=32; off; off>>=1){ a += __shfl_xor(a, off); b += __shfl_xor(b, off); }
  __syncthreads();
  if ((t&63)==0){ sred[(t>>6)*2] = a; sred[(t>>6)*2+1] = b; }
  __syncthreads();
  a = sred[0]+sred[2]+sred[4]+sred[6];
  b = sred[1]+sred[3]+sred[5]+sred[7];
}

__global__ __launch_bounds__(256)
void k_stats(const float* __restrict__ h, const float* __restrict__ intf,
             const unsigned short* __restrict__ sp,
             const float* __restrict__ g_pfs, const float* __restrict__ b_pfs,
             const float* __restrict__ g_sfs, const float* __restrict__ b_sfs,
             float* __restrict__ part_p, float* __restrict__ part_s, int g0)
{
  __shared__ float sred[8];
  const int bl = blockIdx.x, grp = blockIdx.y, t = threadIdx.x;
  float zacc[20], wacc[16];
  #pragma unroll
  for (int j=0;j<20;++j) zacc[j]=0.f;
  #pragma unroll
  for (int j=0;j<16;++j) wacc[j]=0.f;
  for (int rr=0; rr<32; ++rr){
    const size_t r = (size_t)bl*256 + grp*32 + rr;
    float hv[4], iv[16], sv[16];
    #pragma unroll
    for (int j=0;j<4;++j) hv[j] = h[r*1024 + j*256 + t];
    float s1=0.f, s2=0.f;
    #pragma unroll
    for (int j=0;j<16;++j){ float x = intf[r*4096 + j*256 + t]; iv[j]=x; s1+=x; s2+=x*x; }
    blkred2(s1,s2,sred,t);
    const float m1 = s1*(1.f/4096.f);
    const float rs1 = rsqrtf(fmaxf(s2*(1.f/4096.f) - m1*m1, 0.f) + EPSV);
    float t1=0.f, t2=0.f;
    #pragma unroll
    for (int j=0;j<4;++j){ t1 += hv[j]; t2 += hv[j]*hv[j]; }
    #pragma unroll
    for (int j=0;j<16;++j){ float y = (iv[j]-m1)*rs1; iv[j]=y; t1+=y; t2+=y*y; }
    blkred2(t1,t2,sred,t);
    const float m2 = t1*(1.f/5120.f);
    const float rs2 = rsqrtf(fmaxf(t2*(1.f/5120.f) - m2*m2, 0.f) + EPSV);
    #pragma unroll
    for (int j=0;j<4;++j){ int idx = j*256+t; zacc[j] += ((hv[j]-m2)*rs2)*g_pfs[idx] + b_pfs[idx]; }
    #pragma unroll
    for (int j=0;j<16;++j){ int idx = 1024 + j*256+t; zacc[4+j] += ((iv[j]-m2)*rs2)*g_pfs[idx] + b_pfs[idx]; }
    float u1=0.f, u2=0.f;
    #pragma unroll
    for (int j=0;j<16;++j){ float x = bf2f(sp[r*4096 + j*256 + t]); sv[j]=x; u1+=x; u2+=x*x; }
    blkred2(u1,u2,sred,t);
    const float m3 = u1*(1.f/4096.f);
    const float rs3 = rsqrtf(fmaxf(u2*(1.f/4096.f) - m3*m3, 0.f) + EPSV);
    #pragma unroll
    for (int j=0;j<16;++j){ int idx = j*256+t; wacc[j] += ((sv[j]-m3)*rs3)*g_sfs[idx] + b_sfs[idx]; }
  }
  const size_t pb = (size_t)(g0 + bl)*8 + grp;
  #pragma unroll
  for (int j=0;j<20;++j) part_p[pb*5120 + j*256 + t] = zacc[j];
  #pragma unroll
  for (int j=0;j<16;++j) part_s[pb*4096 + j*256 + t] = wacc[j];
}

__global__ __launch_bounds__(256)
void k_reduce(const float* __restrict__ part_p, const float* __restrict__ part_s,
              float* __restrict__ xbar, float* __restrict__ ybar){
  int id = blockIdx.x*256 + threadIdx.x;
  if (id < 32*5120){
    const int b = id / 5120, i = id % 5120;
    float s = 0.f;
    for (int g=0; g<8; ++g) s += part_p[((size_t)b*8+g)*5120 + i];
    xbar[(size_t)b*5120 + i] = s * (1.f/256.f);
  } else {
    id -= 32*5120;
    const int b = id / 4096, i = id % 4096;
    float s = 0.f;
    for (int g=0; g<8; ++g) s += part_s[((size_t)b*8+g)*4096 + i];
    ybar[(size_t)b*4096 + i] = s * (1.f/256.f);
  }
}

__global__ __launch_bounds__(256)
void k_proj_part(const float* __restrict__ xbar, const float* __restrict__ ybar,
                 const float* __restrict__ Wpfs, const float* __restrict__ Wsfs,
                 float* __restrict__ pbuf){
  const int path = blockIdx.z;
  const int y = blockIdx.y;
  if (path == 1 && y >= 8) return;
  const int Kp = path ? 4096 : 5120;
  const float* X = path ? ybar : xbar;
  const float* W = path ? Wsfs : Wpfs;
  const int t = threadIdx.x;
  const int col = blockIdx.x*64 + (t & 63);
  const int sub = t >> 6;
  const int k0 = y*512 + sub*128;
  float acc[32];
  #pragma unroll
  for (int b=0;b<32;++b) acc[b] = 0.f;
  for (int i4=0; i4<32; ++i4){
    const int k = k0 + i4*4;
    float wv0 = W[(size_t)(k  )*1024 + col];
    float wv1 = W[(size_t)(k+1)*1024 + col];
    float wv2 = W[(size_t)(k+2)*1024 + col];
    float wv3 = W[(size_t)(k+3)*1024 + col];
    #pragma unroll
    for (int b=0;b<32;++b){
      float4 xv = *(const float4*)(X + (size_t)b*Kp + k);
      acc[b] += xv.x*wv0 + xv.y*wv1 + xv.z*wv2 + xv.w*wv3;
    }
  }
  float* dst = pbuf + ((size_t)(path*40 + y*4 + sub)*32)*1024 + col;
  #pragma unroll
  for (int b=0;b<32;++b) dst[(size_t)b*1024] = acc[b];
}

__global__ __launch_bounds__(256)
void k_projred(const float* __restrict__ pbuf,
               const float* __restrict__ bpfs, const float* __restrict__ bsfs,
               float* __restrict__ tpre, float* __restrict__ spre){
  const int id = blockIdx.x*256 + threadIdx.x;
  const int path = id >> 15;
  const int rem = id & 32767;
  const int b = rem >> 10, col = rem & 1023;
  const int ns = path ? 32 : 40;
  const float* src = pbuf + ((size_t)(path*40)*32 + b)*1024 + col;
  float s = path ? bsfs[col] : bpfs[col];
  for (int g=0; g<ns; ++g) s += src[(size_t)g*32*1024];
  (path ? spre : tpre)[(size_t)b*1024 + col] = s;
}

__global__ __launch_bounds__(256)
void k_lnrow(const float* __restrict__ tpre, const float* __restrict__ spre,
             float* __restrict__ out){
  __shared__ float sred[8];
  const int id = blockIdx.x, t = threadIdx.x;
  const int path = id >> 5, b = id & 31;
  const float* src = (path ? spre : tpre) + (size_t)b*1024;
  float v[4]; float s1=0.f, s2=0.f;
  #pragma unroll
  for (int j=0;j<4;++j){ v[j] = src[j*256+t]; s1 += v[j]; s2 += v[j]*v[j]; }
  blkred2(s1,s2,sred,t);
  const float m = s1*(1.f/1024.f);
  const float rs = rsqrtf(fmaxf(s2*(1.f/1024.f)-m*m,0.f)+EPSV);
  float* dst = out + (path ? 35072 : 2304) + (size_t)b*1024;
  #pragma unroll
  for (int j=0;j<4;++j) dst[j*256+t] = (v[j]-m)*rs;
}

__global__ __launch_bounds__(256)
void k_head(const float* __restrict__ Wpc, const float* __restrict__ bpc,
            const float* __restrict__ Wc0, const float* __restrict__ bc0,
            const float* __restrict__ Wc1, const float* __restrict__ bc1,
            const float* __restrict__ Wc2, const float* __restrict__ bc2,
            float* __restrict__ out){
  __shared__ float slog[16];
  __shared__ int sy;
  const int b = blockIdx.x, t = threadIdx.x, w = t>>6, l = t&63;
  const float* pv = out + 2304 + (size_t)b*1024;
  const float* sv = out + 35072 + (size_t)b*1024;
  #pragma unroll
  for (int jj=0; jj<4; ++jj){
    const int j = w*4 + jj;
    float a = 0.f;
    for (int i=l; i<1024; i+=64) a += pv[i]*Wpc[(size_t)i*16 + j];
    #pragma unroll
    for (int off=32; off; off>>=1) a += __shfl_xor(a, off);
    if (l==0){ const float lgv = a + bpc[j]; slog[j] = lgv; out[b*16 + j] = lgv; }
  }
  __syncthreads();
  if (t==0){
    int best=0; float bvv = slog[0];
    for (int i=1;i<16;++i) if (slog[i] > bvv){ bvv = slog[i]; best = i; }
    sy = best;
  }
  __syncthreads();
  const int y = sy;
  const float* Ws[3] = {Wc0, Wc1, Wc2};
  const float* bs[3] = {bc0, bc1, bc2};
  const int nouts[3] = {8,16,32};
  const int ooff[3]  = {512, 768, 1280};
  for (int hI=0; hI<3; ++hI){
    const int no = nouts[hI];
    for (int n = w; n < no; n += 4){
      const float* wr = Ws[hI] + ((size_t)y*no + n)*1024;
      float a = 0.f;
      for (int i=l; i<1024; i+=64) a += sv[i]*wr[i];
      #pragma unroll
      for (int off=32; off; off>>=1) a += __shfl_xor(a, off);
      if (l==0) out[ooff[hI] + b*no + n] = a + bs[hI][(size_t)y*no + n];
    }
  }
}

// ---------------------------------------------------------------------------
extern "C" void kernel_launch(void* const* d_in, const int* in_sizes, int n_in,
                              void* d_out, int out_size, void* d_ws, size_t ws_size,
                              hipStream_t stream)
{
  const float* h    = (const float*)d_in[0];
  const float* Wpp  = (const float*)d_in[1];
  const float* bpp  = (const float*)d_in[2];
  const float* Wsp  = (const float*)d_in[3];
  const float* bsp  = (const float*)d_in[4];
  const float* Wq   = (const float*)d_in[5];
  const float* bq   = (const float*)d_in[6];
  const float* Wk   = (const float*)d_in[7];
  const float* bk   = (const float*)d_in[8];
  const float* Wv   = (const float*)d_in[9];
  const float* bv   = (const float*)d_in[10];
  const float* g_pfs= (const float*)d_in[11];
  const float* b_pfs= (const float*)d_in[12];
  const float* Wpfs = (const float*)d_in[13];
  const float* bpfs = (const float*)d_in[14];
  const float* g_sfs= (const float*)d_in[15];
  const float* b_sfs= (const float*)d_in[16];
  const float* Wsfs = (const float*)d_in[17];
  const float* bsfs = (const float*)d_in[18];
  const float* Wpc  = (const float*)d_in[19];
  const float* bpc  = (const float*)d_in[20];
  const float* Wc0  = (const float*)d_in[21];
  const float* bc0  = (const float*)d_in[22];
  const float* Wc1  = (const float*)d_in[23];
  const float* bc1  = (const float*)d_in[24];
  const float* Wc2  = (const float*)d_in[25];
  const float* bc2  = (const float*)d_in[26];
  float* out = (float*)d_out;
  char* ws = (char*)d_ws;
  (void)in_sizes; (void)n_in; (void)out_size;

  // ---- adaptive plan selection (host arithmetic only) ----
  struct PlanT { int G, NS, hoist; };
  const PlanT plans[11] = {
    {32,4096,1},{32,4096,0},{16,4096,1},{16,4096,0},{8,4096,1},{8,4096,0},
    {4,4096,0},{2,4096,0},{1,4096,0},{1,2048,0},{1,1024,0}};
  int G = 0, NS = 0, HOIST = 0;
  size_t oWt=0,oWps=0,oWq=0,oWkv=0;
  size_t oPp=0,oPs=0,oXb=0,oYb=0,oTp=0,oSp=0,oPbf=0,oHb=0,oPb=0,oSb=0,oQ=0,oK=0,oVt=0,oS=0,oP=0;
  for (int pi = 0; pi < 11; ++pi){
    const size_t g = plans[pi].G, ns = plans[pi].NS;
    const int hoist = plans[pi].hoist;
    size_t off = 0;
    auto alloc = [&](size_t bytes){ size_t o = off; off += (bytes + 255) & ~255ULL; return o; };
    size_t wt=0, wps=0, wq=0, wkv=0;
    if (hoist){
      wps = alloc(8192ULL*1024*2);
      wq  = alloc(4096ULL*4096*2);
      wkv = alloc(8192ULL*4096*2);
    } else {
      wt = alloc(ns*4096*2);
    }
    size_t pp_ = alloc(32*8*5120*4);
    size_t ps_ = alloc(32*8*4096*4);
    size_t xb = alloc(32*5120*4);
    size_t yb = alloc(32*4096*4);
    size_t tp = alloc(32*1024*4);
    size_t sp_ = alloc(32*1024*4);
    size_t pbf = alloc(2*40*32*1024*4);
    size_t hb = alloc(g*524288);
    size_t pb = alloc(g*2097152);
    size_t sb = alloc(g*2097152);
    size_t q  = alloc(g*2097152);
    size_t k  = alloc(g*2097152);
    size_t vt = alloc(g*2097152);
    size_t s  = alloc(g*1048576);
    size_t p  = alloc(g*524288);
    if (off <= ws_size){
      G = (int)g; NS = (int)ns; HOIST = hoist;
      oWt=wt; oWps=wps; oWq=wq; oWkv=wkv;
      oPp=pp_; oPs=ps_; oXb=xb; oYb=yb; oTp=tp; oSp=sp_; oPbf=pbf;
      oHb=hb; oPb=pb; oSb=sb; oQ=q; oK=k; oVt=vt; oS=s; oP=p;
      break;
    }
  }
  if (!G) return;

  unsigned short* Wt   = (unsigned short*)(ws + oWt);
  unsigned short* WpsT = (unsigned short*)(ws + oWps);
  unsigned short* WqT  = (unsigned short*)(ws + oWq);
  unsigned short* WkvT = (unsigned short*)(ws + oWkv);
  float* part_p = (float*)(ws + oPp);
  float* part_s = (float*)(ws + oPs);
  float* xbar   = (float*)(ws + oXb);
  float* ybar   = (float*)(ws + oYb);
  float* tpre   = (float*)(ws + oTp);
  float* spre   = (float*)(ws + oSp);
  float* pbuf   = (float*)(ws + oPbf);
  unsigned short* h_bf = (unsigned short*)(ws + oHb);
  unsigned short* pp   = (unsigned short*)(ws + oPb);
  unsigned short* sp   = (unsigned short*)(ws + oSb);
  unsigned short* Q    = (unsigned short*)(ws + oQ);
  unsigned short* Kb   = (unsigned short*)(ws + oK);
  unsigned short* Vt   = (unsigned short*)(ws + oVt);
  float*          S    = (float*)(ws + oS);
  unsigned short* P    = (unsigned short*)(ws + oP);
  float*          intf = (float*)(ws + oQ);   // aliases Q+K (contiguous, both dead)

  const float scale = 1.0f/32.0f;
  (void)oK;

  if (HOIST){
    hipLaunchKernelGGL(k_tconv, dim3(64,16), dim3(256), 0, stream, Wpp, WpsT, 1024, 4096);
    hipLaunchKernelGGL(k_tconv, dim3(64,16), dim3(256), 0, stream, Wsp, WpsT + 4096ULL*1024, 1024, 4096);
    hipLaunchKernelGGL(k_tconv, dim3(64,64), dim3(256), 0, stream, Wq, WqT, 4096, 4096);
    hipLaunchKernelGGL(k_tconv, dim3(64,64), dim3(256), 0, stream, Wk, WkvT, 4096, 4096);
    hipLaunchKernelGGL(k_tconv, dim3(64,64), dim3(256), 0, stream, Wv, WkvT + 4096ULL*4096, 4096, 4096);
  }

  for (int g0 = 0; g0 < 32; g0 += G){
    const float* h_g = h + (size_t)g0*262144;

    hipLaunchKernelGGL(k_convh, dim3(G*256), dim3(256), 0, stream, h_g, h_bf);

    if (HOIST){
      hipLaunchKernelGGL(gemm256<0>, dim3(32,G), dim3(512), 0, stream,
                         h_bf, WpsT, bpp, bsp, (void*)pp, (void*)sp, 1024, 1024,1024,4096);
      hipLaunchKernelGGL(gemm256<1>, dim3(16,G), dim3(512), 0, stream,
                         pp, WqT, bq, bq, (void*)Q, (void*)Q, 4096, 4096,4096,4096);
      hipLaunchKernelGGL(gemm256<4>, dim3(32,G), dim3(512), 0, stream,
                         sp, WkvT, bk, bv, (void*)Kb, (void*)Vt, 4096, 4096,4096,4096);
    } else {
      hipLaunchKernelGGL(k_tconv, dim3(64,16), dim3(256), 0, stream, Wpp, Wt, 1024, 4096);
      hipLaunchKernelGGL(gemm256<0>, dim3(16,G), dim3(512), 0, stream,
                         h_bf, Wt, bpp, bpp, (void*)pp, (void*)pp, 1024, 1024,1024,4096);
      for (int nso = 0; nso < 4096; nso += NS){
        hipLaunchKernelGGL(k_tconv, dim3(NS/64,64), dim3(256), 0, stream, Wq + nso, Wt, 4096, 4096);
        hipLaunchKernelGGL(gemm256<1>, dim3(NS/256,G), dim3(512), 0, stream,
                           pp, Wt, bq + nso, bq + nso, (void*)(Q + nso), (void*)(Q + nso), 4096, 4096,4096,4096);
      }
      hipLaunchKernelGGL(k_tconv, dim3(64,16), dim3(256), 0, stream, Wsp, Wt, 1024, 4096);
      hipLaunchKernelGGL(gemm256<0>, dim3(16,G), dim3(512), 0, stream,
                         h_bf, Wt, bsp, bsp, (void*)sp, (void*)sp, 1024, 1024,1024,4096);
      for (int nso = 0; nso < 4096; nso += NS){
        hipLaunchKernelGGL(k_tconv, dim3(NS/64,64), dim3(256), 0, stream, Wk + nso, Wt, 4096, 4096);
        hipLaunchKernelGGL(gemm256<1>, dim3(NS/256,G), dim3(512), 0, stream,
                           sp, Wt, bk + nso, bk + nso, (void*)(Kb + nso), (void*)(Kb + nso), 4096, 4096,4096,4096);
      }
      for (int nso = 0; nso < 4096; nso += NS){
        hipLaunchKernelGGL(k_tconv, dim3(NS/64,64), dim3(256), 0, stream, Wv + nso, Wt, 4096, 4096);
        hipLaunchKernelGGL(gemm256<3>, dim3(NS/256,G), dim3(512), 0, stream,
                           sp, Wt, bv + nso, bv + nso, (void*)(Vt + (size_t)nso*256), (void*)(Vt + (size_t)nso*256), 4096, 4096,4096,256);
      }
    }
    hipLaunchKernelGGL(gemm_bt<2>, dim3(2,2,G*4), dim3(256), 0, stream,
                       Q, Kb, (const float*)nullptr, (void*)S, 1024, 4096,4096,256,
                       1048576L,1024L, 1048576L,1024L, 262144L,65536L, scale);
    hipLaunchKernelGGL(k_softmax, dim3(G*256), dim3(256), 0, stream, S, P);
    hipLaunchKernelGGL(gemm_bt<2>, dim3(8,2,G*4), dim3(256), 0, stream,
                       P, Vt, (const float*)nullptr, (void*)intf, 256, 256,256,4096,
                       262144L,65536L, 1048576L,262144L, 1048576L,1024L, 1.f);
    hipLaunchKernelGGL(k_stats, dim3(G,8), dim3(256), 0, stream,
                       h_g, intf, sp, g_pfs, b_pfs, g_sfs, b_sfs, part_p, part_s, g0);
  }

  hipLaunchKernelGGL(k_reduce, dim3(1152), dim3(256), 0, stream, part_p, part_s, xbar, ybar);
  hipLaunchKernelGGL(k_proj_part, dim3(16,10,2), dim3(256), 0, stream,
                     xbar, ybar, Wpfs, Wsfs, pbuf);
  hipLaunchKernelGGL(k_projred, dim3(256), dim3(256), 0, stream,
                     pbuf, bpfs, bsfs, tpre, spre);
  hipLaunchKernelGGL(k_lnrow, dim3(64), dim3(256), 0, stream, tpre, spre, out);
  hipLaunchKernelGGL(k_head, dim3(32), dim3(256), 0, stream,
                     Wpc, bpc, Wc0, bc0, Wc1, bc1, Wc2, bc2, out);
}

// Round 8
// 1537.547 us; speedup vs baseline: 1.1604x; 1.1604x over previous
//
#include <hip/hip_runtime.h>
#include <hip/hip_bf16.h>

typedef __bf16 bf16x8 __attribute__((ext_vector_type(8)));
typedef float f32x4 __attribute__((ext_vector_type(4)));
typedef unsigned long long u64;

#define EPSV 1e-5f

__device__ __forceinline__ float bf2f(unsigned short u){
  unsigned int x = ((unsigned int)u) << 16;
  return __builtin_bit_cast(float, x);
}
__device__ __forceinline__ unsigned short f2bf(float f){
  __bf16 b = (__bf16)f;
  return __builtin_bit_cast(unsigned short, b);
}
__device__ __forceinline__ float gelu_exact(float x){
  return 0.5f * x * (1.0f + erff(x * 0.7071067811865476f));
}
__device__ __forceinline__ void gload_lds16(const void* g, void* l){
  __builtin_amdgcn_global_load_lds((const __attribute__((address_space(1))) unsigned int*)g,
                                   (__attribute__((address_space(3))) unsigned int*)l, 16, 0, 0);
}

// ---------------------------------------------------------------------------
// 256x256 (BK=64) 8-wave 4-phase bf16 MFMA GEMM (R6 schedule — best measured:
// 125us/137GF, MfmaUtil 47%; two pipelining variants regressed, reverted).
// MODE 0: bias+GELU dual split at col 4096 -> (C0,bias0)/(C1,bias1)
// MODE 1: bias->bf16   MODE 3: V^T   MODE 4: dual K/V^T split at col 4096
// ---------------------------------------------------------------------------
template<int MODE>
__global__ __launch_bounds__(512, 2)
void gemm256(const unsigned short* __restrict__ A, const unsigned short* __restrict__ B,
             const float* __restrict__ bias0, const float* __restrict__ bias1,
             void* __restrict__ C0v, void* __restrict__ C1v,
             int Kd, int lda, int ldb, int ldc)
{
  __shared__ char smem[131072];  // A: [2 dbuf][2 half][128][64]b16 @0; B same @65536
  const int t = threadIdx.x;
  const int w = t >> 6, l = t & 63;
  const int wm = w >> 2, wn = w & 3;        // wave grid 2(M) x 4(N)
  const int lr = l & 15, lg = l >> 4;
  const int nbx = gridDim.x;
  const int nwg = nbx * gridDim.y;
  int bid = blockIdx.y*nbx + blockIdx.x;
  if ((nwg & 7) == 0) bid = (bid & 7)*(nwg >> 3) + (bid >> 3);
  const int bm0 = (bid / nbx) * 256, bn0 = (bid % nbx) * 256;
  const int nk = Kd >> 6;

  const int srow = t >> 3;                   // staging row-within-quarter 0..63
  const int sslot = t & 7;                   // staging 16B slot

  f32x4 acc[8][4];
  #pragma unroll
  for (int i=0;i<8;++i){
    #pragma unroll
    for (int j=0;j<4;++j){ f32x4 zz = {0.f,0.f,0.f,0.f}; acc[i][j] = zz; }
  }
  bf16x8 a0[4][2], a1[4][2], b0[2][2], b1[2][2];

  auto stage = [&](int kt, int mat, int hf, int q){
    if (kt >= nk) return;
    const int r_h = q*64 + srow;
    const int s_ = sslot ^ ((r_h >> 1) & 7);
    const unsigned short* gp = (mat ? B + (size_t)(bn0 + hf*128 + r_h)*ldb
                                    : A + (size_t)(bm0 + hf*128 + r_h)*lda)
                               + (kt << 6) + s_*8;
    char* lp = smem + mat*65536 + (kt&1)*32768 + hf*16384 + q*8192 + t*16;
    gload_lds16((const void*)gp, (void*)lp);
  };
  auto rdA = [&](int d, int fm, int kk)->bf16x8{
    const int r = fm*16 + lr;
    const int s_ = (kk*4 + lg) ^ ((r >> 1) & 7);
    return *(const bf16x8*)(smem + d*32768 + wm*16384 + r*128 + s_*16);
  };
  auto rdB = [&](int d, int fn, int kk)->bf16x8{
    const int r = (wn&1)*64 + fn*16 + lr;
    const int s_ = (kk*4 + lg) ^ ((r >> 1) & 7);
    return *(const bf16x8*)(smem + 65536 + d*32768 + (wn>>1)*16384 + r*128 + s_*16);
  };

  auto ktile = [&](int kt, int d){
    // ---- phase 1 ----
    #pragma unroll
    for (int fm=0; fm<4; ++fm){ a0[fm][0] = rdA(d, fm, 0); a0[fm][1] = rdA(d, fm, 1); }
    #pragma unroll
    for (int fn=0; fn<2; ++fn){ b0[fn][0] = rdB(d, fn, 0); b0[fn][1] = rdB(d, fn, 1); }
    stage(kt+1, 0, 0, 1); stage(kt+1, 0, 1, 1);
    __builtin_amdgcn_s_barrier();
    __builtin_amdgcn_sched_barrier(0);
    __builtin_amdgcn_s_setprio(1);
    #pragma unroll
    for (int fm=0; fm<4; ++fm)
      #pragma unroll
      for (int fn=0; fn<2; ++fn)
        #pragma unroll
        for (int kk=0; kk<2; ++kk)
          acc[fm][fn] = __builtin_amdgcn_mfma_f32_16x16x32_bf16(a0[fm][kk], b0[fn][kk], acc[fm][fn], 0,0,0);
    __builtin_amdgcn_s_setprio(0);
    __builtin_amdgcn_s_barrier();
    // ---- phase 2 ----
    #pragma unroll
    for (int fn=0; fn<2; ++fn){ b1[fn][0] = rdB(d, fn+2, 0); b1[fn][1] = rdB(d, fn+2, 1); }
    stage(kt+2, 0, 0, 0); stage(kt+2, 0, 1, 0);
    __builtin_amdgcn_s_barrier();
    __builtin_amdgcn_sched_barrier(0);
    __builtin_amdgcn_s_setprio(1);
    #pragma unroll
    for (int fm=0; fm<4; ++fm)
      #pragma unroll
      for (int fn=0; fn<2; ++fn)
        #pragma unroll
        for (int kk=0; kk<2; ++kk)
          acc[fm][fn+2] = __builtin_amdgcn_mfma_f32_16x16x32_bf16(a0[fm][kk], b1[fn][kk], acc[fm][fn+2], 0,0,0);
    __builtin_amdgcn_s_setprio(0);
    __builtin_amdgcn_s_barrier();
    // ---- phase 3 ----
    #pragma unroll
    for (int fm=0; fm<4; ++fm){ a1[fm][0] = rdA(d, fm+4, 0); a1[fm][1] = rdA(d, fm+4, 1); }
    stage(kt+2, 1, 0, 0); stage(kt+2, 1, 1, 0);
    __builtin_amdgcn_s_barrier();
    __builtin_amdgcn_sched_barrier(0);
    __builtin_amdgcn_s_setprio(1);
    #pragma unroll
    for (int fm=0; fm<4; ++fm)
      #pragma unroll
      for (int fn=0; fn<2; ++fn)
        #pragma unroll
        for (int kk=0; kk<2; ++kk)
          acc[fm+4][fn+2] = __builtin_amdgcn_mfma_f32_16x16x32_bf16(a1[fm][kk], b1[fn][kk], acc[fm+4][fn+2], 0,0,0);
    __builtin_amdgcn_s_setprio(0);
    __builtin_amdgcn_s_barrier();
    // ---- phase 4 ---- (no ds_reads: reuses a1 + b0 from registers)
    stage(kt+2, 1, 0, 1); stage(kt+2, 1, 1, 1);
    __builtin_amdgcn_s_setprio(1);
    #pragma unroll
    for (int fm=0; fm<4; ++fm)
      #pragma unroll
      for (int fn=0; fn<2; ++fn)
        #pragma unroll
        for (int kk=0; kk<2; ++kk)
          acc[fm+4][fn] = __builtin_amdgcn_mfma_f32_16x16x32_bf16(a1[fm][kk], b0[fn][kk], acc[fm+4][fn], 0,0,0);
    __builtin_amdgcn_s_setprio(0);
    if (kt + 2 < nk) { asm volatile("s_waitcnt vmcnt(6)" ::: "memory"); }
    else             { asm volatile("s_waitcnt vmcnt(0)" ::: "memory"); }
    __builtin_amdgcn_s_barrier();
  };

  // prologue: tile0 fully (8 quarters), tile1 minus A-q1 (6 quarters)
  stage(0,0,0,0); stage(0,0,1,0); stage(0,0,0,1); stage(0,0,1,1);
  stage(0,1,0,0); stage(0,1,1,0); stage(0,1,0,1); stage(0,1,1,1);
  stage(1,0,0,0); stage(1,0,1,0);
  stage(1,1,0,0); stage(1,1,1,0); stage(1,1,0,1); stage(1,1,1,1);
  asm volatile("s_waitcnt vmcnt(6)" ::: "memory");
  __builtin_amdgcn_s_barrier();

  for (int kt = 0; kt < nk; kt += 2){ ktile(kt, 0); ktile(kt+1, 1); }

  // epilogue
  #pragma unroll
  for (int fm=0; fm<8; ++fm){
    #pragma unroll
    for (int fn=0; fn<4; ++fn){
      const int row0 = bm0 + wm*128 + fm*16 + lg*4;
      const int col  = bn0 + wn*64 + fn*16 + lr;
      f32x4 v = acc[fm][fn];
      if constexpr (MODE == 3){
        unsigned short* C = (unsigned short*)C0v;
        const float bb = bias0[col];
        u64 pack = 0;
        #pragma unroll
        for (int j=0;j<4;++j) pack |= (u64)f2bf(v[j] + bb) << (16*j);
        *(u64*)(C + (size_t)col*256 + (size_t)(row0>>8)*1048576 + (row0&255)) = pack;
      } else if constexpr (MODE == 4){
        if (col < 4096){
          unsigned short* C = (unsigned short*)C0v;
          const float bb = bias0[col];
          #pragma unroll
          for (int j=0;j<4;++j) C[(size_t)(row0+j)*ldc + col] = f2bf(v[j] + bb);
        } else {
          const int c2 = col - 4096;
          unsigned short* C = (unsigned short*)C1v;
          const float bb = bias1[c2];
          u64 pack = 0;
          #pragma unroll
          for (int j=0;j<4;++j) pack |= (u64)f2bf(v[j] + bb) << (16*j);
          *(u64*)(C + (size_t)c2*256 + (size_t)(row0>>8)*1048576 + (row0&255)) = pack;
        }
      } else {
        const bool hi = (MODE == 0) && (col >= 4096);
        unsigned short* C = (unsigned short*)(hi ? C1v : C0v);
        const int c2 = hi ? (col - 4096) : col;
        const float bb = hi ? bias1[c2] : bias0[c2];
        #pragma unroll
        for (int j=0;j<4;++j){
          float x = v[j] + bb;
          if constexpr (MODE==0) x = gelu_exact(x);
          C[(size_t)(row0+j)*ldc + c2] = f2bf(x);
        }
      }
    }
  }
}

// ---------------------------------------------------------------------------
// 128x128 (BK=32) bf16 MFMA GEMM (small attention GEMMs). MODE 2: *scale->fp32.
// ---------------------------------------------------------------------------
template<int MODE>
__global__ __launch_bounds__(256)
void gemm_bt(const unsigned short* __restrict__ A, const unsigned short* __restrict__ B,
             const float* __restrict__ bias, void* __restrict__ Cv,
             int Kd, int lda, int ldb, int ldc,
             long sA2, long sA1, long sB2, long sB1, long sC2, long sC1,
             float scale)
{
  __shared__ unsigned short lds[2][2][4096];
  const int t = threadIdx.x;
  const int w = t >> 6, l = t & 63;
  const int z = blockIdx.z;
  A += (size_t)(z>>2)*sA2 + (size_t)(z&3)*sA1;
  B += (size_t)(z>>2)*sB2 + (size_t)(z&3)*sB1;
  const int bm0 = blockIdx.y * 128, bn0 = blockIdx.x * 128;
  const int nk = Kd >> 5;

  const int sr = l >> 2;
  const int ss = l & 3;

  f32x4 acc[4][4];
  #pragma unroll
  for (int i=0;i<4;++i){
    #pragma unroll
    for (int j=0;j<4;++j){ f32x4 zz = {0.f,0.f,0.f,0.f}; acc[i][j] = zz; }
  }

  const int wm = w >> 1, wn = w & 1;
  const int lr = l & 15, lg = l >> 4;

  auto stage = [&](int kt, int bb){
    const int k0 = kt << 5;
    #pragma unroll
    for (int i=0;i<2;++i){
      const int r  = w*32 + i*16 + sr;
      const int sa = ss ^ ((r>>1)&3);
      const unsigned short* ga = A + (size_t)(bm0 + r)*lda + (k0 + sa*8);
      gload_lds16((const void*)ga, (void*)((char*)&lds[bb][0][0] + w*2048 + i*1024));
      const unsigned short* gb = B + (size_t)(bn0 + r)*ldb + (k0 + sa*8);
      gload_lds16((const void*)gb, (void*)((char*)&lds[bb][1][0] + w*2048 + i*1024));
    }
  };

  int buf = 0;
  stage(0, 0);
  for (int kt=0; kt<nk; ++kt){
    __syncthreads();
    if (kt+1 < nk) stage(kt+1, buf^1);
    bf16x8 av[4], bv[4];
    #pragma unroll
    for (int fm=0; fm<4; ++fm){
      const int row = wm*64 + fm*16 + lr;
      const int sl  = lg ^ ((row>>1)&3);
      av[fm] = *(const bf16x8*)((const char*)&lds[buf][0][0] + row*64 + sl*16);
    }
    #pragma unroll
    for (int fn=0; fn<4; ++fn){
      const int col = wn*64 + fn*16 + lr;
      const int sl  = lg ^ ((col>>1)&3);
      bv[fn] = *(const bf16x8*)((const char*)&lds[buf][1][0] + col*64 + sl*16);
    }
    #pragma unroll
    for (int fm=0; fm<4; ++fm){
      #pragma unroll
      for (int fn=0; fn<4; ++fn)
        acc[fm][fn] = __builtin_amdgcn_mfma_f32_16x16x32_bf16(av[fm], bv[fn], acc[fm][fn], 0,0,0);
    }
    buf ^= 1;
  }

  const size_t coff = (size_t)(z>>2)*sC2 + (size_t)(z&3)*sC1;
  #pragma unroll
  for (int fm=0; fm<4; ++fm){
    #pragma unroll
    for (int fn=0; fn<4; ++fn){
      const int row0 = bm0 + wm*64 + fm*16 + lg*4;
      const int col  = bn0 + wn*64 + fn*16 + lr;
      f32x4 v = acc[fm][fn];
      if constexpr (MODE == 2){
        float* C = (float*)Cv + coff;
        #pragma unroll
        for (int j=0;j<4;++j) C[(size_t)(row0+j)*ldc + col] = v[j]*scale;
      }
    }
  }
}

// ---------------------------------------------------------------------------
__global__ __launch_bounds__(256)
void k_convh(const float* __restrict__ in, unsigned short* __restrict__ out){
  const size_t id = (size_t)blockIdx.x*256 + threadIdx.x;
  float4 v = ((const float4*)in)[id];
  u64 pack = (u64)f2bf(v.x) | ((u64)f2bf(v.y)<<16) | ((u64)f2bf(v.z)<<32) | ((u64)f2bf(v.w)<<48);
  *(u64*)(out + id*4) = pack;
}

__global__ __launch_bounds__(256)
void k_tconv(const float* __restrict__ W, unsigned short* __restrict__ Wt, int Kd, int N){
  __shared__ float lt[64][65];
  const int t = threadIdx.x;
  const int n0 = blockIdx.x*64, k0 = blockIdx.y*64;
  #pragma unroll
  for (int i=0;i<16;++i){
    int lin = i*256 + t; int r = lin>>6, c = lin&63;
    lt[r][c] = W[(size_t)(k0+r)*N + n0 + c];
  }
  __syncthreads();
  #pragma unroll
  for (int i=0;i<16;++i){
    int lin = i*256 + t; int n = lin>>6, k = lin&63;
    Wt[(size_t)(n0+n)*Kd + k0 + k] = f2bf(lt[k][n]);
  }
}

__global__ __launch_bounds__(256)
void k_softmax(const float* __restrict__ S, unsigned short* __restrict__ P){
  const int t = threadIdx.x, w = t>>6, l = t&63;
  const size_t row = (size_t)blockIdx.x*4 + w;
  float4 v = *(const float4*)(S + row*256 + l*4);
  float m = fmaxf(fmaxf(v.x,v.y), fmaxf(v.z,v.w));
  #pragma unroll
  for (int off=32; off; off>>=1) m = fmaxf(m, __shfl_xor(m, off));
  float e0 = expf(v.x-m), e1 = expf(v.y-m), e2 = expf(v.z-m), e3 = expf(v.w-m);
  float s = e0+e1+e2+e3;
  #pragma unroll
  for (int off=32; off; off>>=1) s += __shfl_xor(s, off);
  const float inv = 1.0f/s;
  u64 pack = (u64)f2bf(e0*inv) | ((u64)f2bf(e1*inv)<<16) | ((u64)f2bf(e2*inv)<<32) | ((u64)f2bf(e3*inv)<<48);
  *(u64*)(P + row*256 + l*4) = pack;
}

__device__ __forceinline__ void blkred2(float& a, float& b, float* sred, int t){
  #pragma unroll
  for (int off=32; off; off>>=1){ a += __shfl_xor(a, off); b += __shfl_xor(b, off); }
  __syncthreads();
  if ((t&63)==0){ sred[(t>>6)*2] = a; sred[(t>>6)*2+1] = b; }
  __syncthreads();
  a = sred[0]+sred[2]+sred[4]+sred[6];
  b = sred[1]+sred[3]+sred[5]+sred[7];
}

__global__ __launch_bounds__(256)
void k_stats(const float* __restrict__ h, const float* __restrict__ intf,
             const unsigned short* __restrict__ sp,
             const float* __restrict__ g_pfs, const float* __restrict__ b_pfs,
             const float* __restrict__ g_sfs, const float* __restrict__ b_sfs,
             float* __restrict__ part_p, float* __restrict__ part_s, int g0)
{
  __shared__ float sred[8];
  const int bl = blockIdx.x, grp = blockIdx.y, t = threadIdx.x;
  float zacc[20], wacc[16];
  #pragma unroll
  for (int j=0;j<20;++j) zacc[j]=0.f;
  #pragma unroll
  for (int j=0;j<16;++j) wacc[j]=0.f;
  for (int rr=0; rr<32; ++rr){
    const size_t r = (size_t)bl*256 + grp*32 + rr;
    float hv[4], iv[16], sv[16];
    #pragma unroll
    for (int j=0;j<4;++j) hv[j] = h[r*1024 + j*256 + t];
    float s1=0.f, s2=0.f;
    #pragma unroll
    for (int j=0;j<16;++j){ float x = intf[r*4096 + j*256 + t]; iv[j]=x; s1+=x; s2+=x*x; }
    blkred2(s1,s2,sred,t);
    const float m1 = s1*(1.f/4096.f);
    const float rs1 = rsqrtf(fmaxf(s2*(1.f/4096.f) - m1*m1, 0.f) + EPSV);
    float t1=0.f, t2=0.f;
    #pragma unroll
    for (int j=0;j<4;++j){ t1 += hv[j]; t2 += hv[j]*hv[j]; }
    #pragma unroll
    for (int j=0;j<16;++j){ float y = (iv[j]-m1)*rs1; iv[j]=y; t1+=y; t2+=y*y; }
    blkred2(t1,t2,sred,t);
    const float m2 = t1*(1.f/5120.f);
    const float rs2 = rsqrtf(fmaxf(t2*(1.f/5120.f) - m2*m2, 0.f) + EPSV);
    #pragma unroll
    for (int j=0;j<4;++j){ int idx = j*256+t; zacc[j] += ((hv[j]-m2)*rs2)*g_pfs[idx] + b_pfs[idx]; }
    #pragma unroll
    for (int j=0;j<16;++j){ int idx = 1024 + j*256+t; zacc[4+j] += ((iv[j]-m2)*rs2)*g_pfs[idx] + b_pfs[idx]; }
    float u1=0.f, u2=0.f;
    #pragma unroll
    for (int j=0;j<16;++j){ float x = bf2f(sp[r*4096 + j*256 + t]); sv[j]=x; u1+=x; u2+=x*x; }
    blkred2(u1,u2,sred,t);
    const float m3 = u1*(1.f/4096.f);
    const float rs3 = rsqrtf(fmaxf(u2*(1.f/4096.f) - m3*m3, 0.f) + EPSV);
    #pragma unroll
    for (int j=0;j<16;++j){ int idx = j*256+t; wacc[j] += ((sv[j]-m3)*rs3)*g_sfs[idx] + b_sfs[idx]; }
  }
  const size_t pb = (size_t)(g0 + bl)*8 + grp;
  #pragma unroll
  for (int j=0;j<20;++j) part_p[pb*5120 + j*256 + t] = zacc[j];
  #pragma unroll
  for (int j=0;j<16;++j) part_s[pb*4096 + j*256 + t] = wacc[j];
}

__global__ __launch_bounds__(256)
void k_reduce(const float* __restrict__ part_p, const float* __restrict__ part_s,
              float* __restrict__ xbar, float* __restrict__ ybar){
  int id = blockIdx.x*256 + threadIdx.x;
  if (id < 32*5120){
    const int b = id / 5120, i = id % 5120;
    float s = 0.f;
    for (int g=0; g<8; ++g) s += part_p[((size_t)b*8+g)*5120 + i];
    xbar[(size_t)b*5120 + i] = s * (1.f/256.f);
  } else {
    id -= 32*5120;
    const int b = id / 4096, i = id % 4096;
    float s = 0.f;
    for (int g=0; g<8; ++g) s += part_s[((size_t)b*8+g)*4096 + i];
    ybar[(size_t)b*4096 + i] = s * (1.f/256.f);
  }
}

__global__ __launch_bounds__(256)
void k_proj_part(const float* __restrict__ xbar, const float* __restrict__ ybar,
                 const float* __restrict__ Wpfs, const float* __restrict__ Wsfs,
                 float* __restrict__ pbuf){
  const int path = blockIdx.z;
  const int y = blockIdx.y;
  if (path == 1 && y >= 8) return;
  const int Kp = path ? 4096 : 5120;
  const float* X = path ? ybar : xbar;
  const float* W = path ? Wsfs : Wpfs;
  const int t = threadIdx.x;
  const int col = blockIdx.x*64 + (t & 63);
  const int sub = t >> 6;
  const int k0 = y*512 + sub*128;
  float acc[32];
  #pragma unroll
  for (int b=0;b<32;++b) acc[b] = 0.f;
  for (int i4=0; i4<32; ++i4){
    const int k = k0 + i4*4;
    float wv0 = W[(size_t)(k  )*1024 + col];
    float wv1 = W[(size_t)(k+1)*1024 + col];
    float wv2 = W[(size_t)(k+2)*1024 + col];
    float wv3 = W[(size_t)(k+3)*1024 + col];
    #pragma unroll
    for (int b=0;b<32;++b){
      float4 xv = *(const float4*)(X + (size_t)b*Kp + k);
      acc[b] += xv.x*wv0 + xv.y*wv1 + xv.z*wv2 + xv.w*wv3;
    }
  }
  float* dst = pbuf + ((size_t)(path*40 + y*4 + sub)*32)*1024 + col;
  #pragma unroll
  for (int b=0;b<32;++b) dst[(size_t)b*1024] = acc[b];
}

__global__ __launch_bounds__(256)
void k_projred(const float* __restrict__ pbuf,
               const float* __restrict__ bpfs, const float* __restrict__ bsfs,
               float* __restrict__ tpre, float* __restrict__ spre){
  const int id = blockIdx.x*256 + threadIdx.x;
  const int path = id >> 15;
  const int rem = id & 32767;
  const int b = rem >> 10, col = rem & 1023;
  const int ns = path ? 32 : 40;
  const float* src = pbuf + ((size_t)(path*40)*32 + b)*1024 + col;
  float s = path ? bsfs[col] : bpfs[col];
  for (int g=0; g<ns; ++g) s += src[(size_t)g*32*1024];
  (path ? spre : tpre)[(size_t)b*1024 + col] = s;
}

__global__ __launch_bounds__(256)
void k_lnrow(const float* __restrict__ tpre, const float* __restrict__ spre,
             float* __restrict__ out){
  __shared__ float sred[8];
  const int id = blockIdx.x, t = threadIdx.x;
  const int path = id >> 5, b = id & 31;
  const float* src = (path ? spre : tpre) + (size_t)b*1024;
  float v[4]; float s1=0.f, s2=0.f;
  #pragma unroll
  for (int j=0;j<4;++j){ v[j] = src[j*256+t]; s1 += v[j]; s2 += v[j]*v[j]; }
  blkred2(s1,s2,sred,t);
  const float m = s1*(1.f/1024.f);
  const float rs = rsqrtf(fmaxf(s2*(1.f/1024.f)-m*m,0.f)+EPSV);
  float* dst = out + (path ? 35072 : 2304) + (size_t)b*1024;
  #pragma unroll
  for (int j=0;j<4;++j) dst[j*256+t] = (v[j]-m)*rs;
}

__global__ __launch_bounds__(256)
void k_head(const float* __restrict__ Wpc, const float* __restrict__ bpc,
            const float* __restrict__ Wc0, const float* __restrict__ bc0,
            const float* __restrict__ Wc1, const float* __restrict__ bc1,
            const float* __restrict__ Wc2, const float* __restrict__ bc2,
            float* __restrict__ out){
  __shared__ float slog[16];
  __shared__ int sy;
  const int b = blockIdx.x, t = threadIdx.x, w = t>>6, l = t&63;
  const float* pv = out + 2304 + (size_t)b*1024;
  const float* sv = out + 35072 + (size_t)b*1024;
  #pragma unroll
  for (int jj=0; jj<4; ++jj){
    const int j = w*4 + jj;
    float a = 0.f;
    for (int i=l; i<1024; i+=64) a += pv[i]*Wpc[(size_t)i*16 + j];
    #pragma unroll
    for (int off=32; off; off>>=1) a += __shfl_xor(a, off);
    if (l==0){ const float lgv = a + bpc[j]; slog[j] = lgv; out[b*16 + j] = lgv; }
  }
  __syncthreads();
  if (t==0){
    int best=0; float bvv = slog[0];
    for (int i=1;i<16;++i) if (slog[i] > bvv){ bvv = slog[i]; best = i; }
    sy = best;
  }
  __syncthreads();
  const int y = sy;
  const float* Ws[3] = {Wc0, Wc1, Wc2};
  const float* bs[3] = {bc0, bc1, bc2};
  const int nouts[3] = {8,16,32};
  const int ooff[3]  = {512, 768, 1280};
  for (int hI=0; hI<3; ++hI){
    const int no = nouts[hI];
    for (int n = w; n < no; n += 4){
      const float* wr = Ws[hI] + ((size_t)y*no + n)*1024;
      float a = 0.f;
      for (int i=l; i<1024; i+=64) a += sv[i]*wr[i];
      #pragma unroll
      for (int off=32; off; off>>=1) a += __shfl_xor(a, off);
      if (l==0) out[ooff[hI] + b*no + n] = a + bs[hI][(size_t)y*no + n];
    }
  }
}

// ---------------------------------------------------------------------------
extern "C" void kernel_launch(void* const* d_in, const int* in_sizes, int n_in,
                              void* d_out, int out_size, void* d_ws, size_t ws_size,
                              hipStream_t stream)
{
  const float* h    = (const float*)d_in[0];
  const float* Wpp  = (const float*)d_in[1];
  const float* bpp  = (const float*)d_in[2];
  const float* Wsp  = (const float*)d_in[3];
  const float* bsp  = (const float*)d_in[4];
  const float* Wq   = (const float*)d_in[5];
  const float* bq   = (const float*)d_in[6];
  const float* Wk   = (const float*)d_in[7];
  const float* bk   = (const float*)d_in[8];
  const float* Wv   = (const float*)d_in[9];
  const float* bv   = (const float*)d_in[10];
  const float* g_pfs= (const float*)d_in[11];
  const float* b_pfs= (const float*)d_in[12];
  const float* Wpfs = (const float*)d_in[13];
  const float* bpfs = (const float*)d_in[14];
  const float* g_sfs= (const float*)d_in[15];
  const float* b_sfs= (const float*)d_in[16];
  const float* Wsfs = (const float*)d_in[17];
  const float* bsfs = (const float*)d_in[18];
  const float* Wpc  = (const float*)d_in[19];
  const float* bpc  = (const float*)d_in[20];
  const float* Wc0  = (const float*)d_in[21];
  const float* bc0  = (const float*)d_in[22];
  const float* Wc1  = (const float*)d_in[23];
  const float* bc1  = (const float*)d_in[24];
  const float* Wc2  = (const float*)d_in[25];
  const float* bc2  = (const float*)d_in[26];
  float* out = (float*)d_out;
  char* ws = (char*)d_ws;
  (void)in_sizes; (void)n_in; (void)out_size;

  // ---- adaptive plan selection (host arithmetic only) ----
  // mode 2: hoist all weights once (needs ~300 MiB)
  // mode 1: 64 MiB Wt -> merged ppsp + merged KV dispatches (~253 MiB)
  // mode 0: 32 MiB (or NS-slab) Wt, separate dispatches (~221 MiB)
  // S/P alias the pp buffer (pp dead after the Q GEMM) in all modes.
  struct PlanT { int G, NS, mode; };
  const PlanT plans[12] = {
    {16,4096,2},{16,4096,1},{16,4096,0},{8,4096,2},{8,4096,1},{8,4096,0},
    {4,4096,0},{2,4096,0},{1,4096,0},{1,4096,0},{1,2048,0},{1,1024,0}};
  int G = 0, NS = 0, MODE_ = 0;
  size_t oWt=0,oWps=0,oWq=0,oWkv=0;
  size_t oPp=0,oPs=0,oXb=0,oYb=0,oTp=0,oSp=0,oPbf=0,oHb=0,oPb=0,oSb=0,oQ=0,oK=0,oVt=0;
  for (int pi = 0; pi < 12; ++pi){
    const size_t g = plans[pi].G, ns = plans[pi].NS;
    const int mode = plans[pi].mode;
    size_t off = 0;
    auto alloc = [&](size_t bytes){ size_t o = off; off += (bytes + 255) & ~255ULL; return o; };
    size_t wt=0, wps=0, wq=0, wkv=0;
    if (mode == 2){
      wps = alloc(8192ULL*1024*2);
      wq  = alloc(4096ULL*4096*2);
      wkv = alloc(8192ULL*4096*2);
    } else if (mode == 1){
      wt = alloc(8192ULL*4096*2);      // 64 MiB shared
    } else {
      wt = alloc(ns*4096*2);
    }
    size_t pp_ = alloc(32*8*5120*4);
    size_t ps_ = alloc(32*8*4096*4);
    size_t xb = alloc(32*5120*4);
    size_t yb = alloc(32*4096*4);
    size_t tp = alloc(32*1024*4);
    size_t sp_ = alloc(32*1024*4);
    size_t pbf = alloc(2*40*32*1024*4);
    size_t hb = alloc(g*524288);
    size_t pb = alloc(g*2097152);     // pp; later aliased by S (g*1MB) + P (g*0.5MB)
    size_t sb = alloc(g*2097152);
    size_t q  = alloc(g*2097152);
    size_t k  = alloc(g*2097152);
    size_t vt = alloc(g*2097152);
    if (off <= ws_size){
      G = (int)g; NS = (int)ns; MODE_ = mode;
      oWt=wt; oWps=wps; oWq=wq; oWkv=wkv;
      oPp=pp_; oPs=ps_; oXb=xb; oYb=yb; oTp=tp; oSp=sp_; oPbf=pbf;
      oHb=hb; oPb=pb; oSb=sb; oQ=q; oK=k; oVt=vt;
      break;
    }
  }
  if (!G) return;

  unsigned short* Wt   = (unsigned short*)(ws + oWt);
  unsigned short* WpsT = (unsigned short*)(ws + oWps);
  unsigned short* WqT  = (unsigned short*)(ws + oWq);
  unsigned short* WkvT = (unsigned short*)(ws + oWkv);
  float* part_p = (float*)(ws + oPp);
  float* part_s = (float*)(ws + oPs);
  float* xbar   = (float*)(ws + oXb);
  float* ybar   = (float*)(ws + oYb);
  float* tpre   = (float*)(ws + oTp);
  float* spre   = (float*)(ws + oSp);
  float* pbuf   = (float*)(ws + oPbf);
  unsigned short* h_bf = (unsigned short*)(ws + oHb);
  unsigned short* pp   = (unsigned short*)(ws + oPb);
  unsigned short* sp   = (unsigned short*)(ws + oSb);
  unsigned short* Q    = (unsigned short*)(ws + oQ);
  unsigned short* Kb   = (unsigned short*)(ws + oK);
  unsigned short* Vt   = (unsigned short*)(ws + oVt);
  float*          S    = (float*)(ws + oPb);                              // alias pp
  unsigned short* P    = (unsigned short*)(ws + oPb + (size_t)G*1048576); // alias pp tail
  float*          intf = (float*)(ws + oQ);   // aliases Q+K (contiguous, both dead)

  const float scale = 1.0f/32.0f;
  (void)oK;

  if (MODE_ == 2){
    hipLaunchKernelGGL(k_tconv, dim3(64,16), dim3(256), 0, stream, Wpp, WpsT, 1024, 4096);
    hipLaunchKernelGGL(k_tconv, dim3(64,16), dim3(256), 0, stream, Wsp, WpsT + 4096ULL*1024, 1024, 4096);
    hipLaunchKernelGGL(k_tconv, dim3(64,64), dim3(256), 0, stream, Wq, WqT, 4096, 4096);
    hipLaunchKernelGGL(k_tconv, dim3(64,64), dim3(256), 0, stream, Wk, WkvT, 4096, 4096);
    hipLaunchKernelGGL(k_tconv, dim3(64,64), dim3(256), 0, stream, Wv, WkvT + 4096ULL*4096, 4096, 4096);
  }

  for (int g0 = 0; g0 < 32; g0 += G){
    const float* h_g = h + (size_t)g0*262144;

    hipLaunchKernelGGL(k_convh, dim3(G*256), dim3(256), 0, stream, h_g, h_bf);

    if (MODE_ == 2){
      hipLaunchKernelGGL(gemm256<0>, dim3(32,G), dim3(512), 0, stream,
                         h_bf, WpsT, bpp, bsp, (void*)pp, (void*)sp, 1024, 1024,1024,4096);
      hipLaunchKernelGGL(gemm256<1>, dim3(16,G), dim3(512), 0, stream,
                         pp, WqT, bq, bq, (void*)Q, (void*)Q, 4096, 4096,4096,4096);
      hipLaunchKernelGGL(gemm256<4>, dim3(32,G), dim3(512), 0, stream,
                         sp, WkvT, bk, bv, (void*)Kb, (void*)Vt, 4096, 4096,4096,4096);
    } else if (MODE_ == 1){
      // pp,sp merged (weights converted into shared 64MiB Wt each group)
      hipLaunchKernelGGL(k_tconv, dim3(64,16), dim3(256), 0, stream, Wpp, Wt, 1024, 4096);
      hipLaunchKernelGGL(k_tconv, dim3(64,16), dim3(256), 0, stream, Wsp, Wt + 4096ULL*1024, 1024, 4096);
      hipLaunchKernelGGL(gemm256<0>, dim3(32,G), dim3(512), 0, stream,
                         h_bf, Wt, bpp, bsp, (void*)pp, (void*)sp, 1024, 1024,1024,4096);
      hipLaunchKernelGGL(k_tconv, dim3(64,64), dim3(256), 0, stream, Wq, Wt, 4096, 4096);
      hipLaunchKernelGGL(gemm256<1>, dim3(16,G), dim3(512), 0, stream,
                         pp, Wt, bq, bq, (void*)Q, (void*)Q, 4096, 4096,4096,4096);
      hipLaunchKernelGGL(k_tconv, dim3(64,64), dim3(256), 0, stream, Wk, Wt, 4096, 4096);
      hipLaunchKernelGGL(k_tconv, dim3(64,64), dim3(256), 0, stream, Wv, Wt + 4096ULL*4096, 4096, 4096);
      hipLaunchKernelGGL(gemm256<4>, dim3(32,G), dim3(512), 0, stream,
                         sp, Wt, bk, bv, (void*)Kb, (void*)Vt, 4096, 4096,4096,4096);
    } else {
      hipLaunchKernelGGL(k_tconv, dim3(64,16), dim3(256), 0, stream, Wpp, Wt, 1024, 4096);
      hipLaunchKernelGGL(gemm256<0>, dim3(16,G), dim3(512), 0, stream,
                         h_bf, Wt, bpp, bpp, (void*)pp, (void*)pp, 1024, 1024,1024,4096);
      for (int nso = 0; nso < 4096; nso += NS){
        hipLaunchKernelGGL(k_tconv, dim3(NS/64,64), dim3(256), 0, stream, Wq + nso, Wt, 4096, 4096);
        hipLaunchKernelGGL(gemm256<1>, dim3(NS/256,G), dim3(512), 0, stream,
                           pp, Wt, bq + nso, bq + nso, (void*)(Q + nso), (void*)(Q + nso), 4096, 4096,4096,4096);
      }
      hipLaunchKernelGGL(k_tconv, dim3(64,16), dim3(256), 0, stream, Wsp, Wt, 1024, 4096);
      hipLaunchKernelGGL(gemm256<0>, dim3(16,G), dim3(512), 0, stream,
                         h_bf, Wt, bsp, bsp, (void*)sp, (void*)sp, 1024, 1024,1024,4096);
      for (int nso = 0; nso < 4096; nso += NS){
        hipLaunchKernelGGL(k_tconv, dim3(NS/64,64), dim3(256), 0, stream, Wk + nso, Wt, 4096, 4096);
        hipLaunchKernelGGL(gemm256<1>, dim3(NS/256,G), dim3(512), 0, stream,
                           sp, Wt, bk + nso, bk + nso, (void*)(Kb + nso), (void*)(Kb + nso), 4096, 4096,4096,4096);
      }
      for (int nso = 0; nso < 4096; nso += NS){
        hipLaunchKernelGGL(k_tconv, dim3(NS/64,64), dim3(256), 0, stream, Wv + nso, Wt, 4096, 4096);
        hipLaunchKernelGGL(gemm256<3>, dim3(NS/256,G), dim3(512), 0, stream,
                           sp, Wt, bv + nso, bv + nso, (void*)(Vt + (size_t)nso*256), (void*)(Vt + (size_t)nso*256), 4096, 4096,4096,256);
      }
    }
    // S = scale * Q K^T (z = b_local*4 + h) ; softmax ; intf = P V (fp32)
    hipLaunchKernelGGL(gemm_bt<2>, dim3(2,2,G*4), dim3(256), 0, stream,
                       Q, Kb, (const float*)nullptr, (void*)S, 1024, 4096,4096,256,
                       1048576L,1024L, 1048576L,1024L, 262144L,65536L, scale);
    hipLaunchKernelGGL(k_softmax, dim3(G*256), dim3(256), 0, stream, S, P);
    hipLaunchKernelGGL(gemm_bt<2>, dim3(8,2,G*4), dim3(256), 0, stream,
                       P, Vt, (const float*)nullptr, (void*)intf, 256, 256,256,4096,
                       262144L,65536L, 1048576L,262144L, 1048576L,1024L, 1.f);
    hipLaunchKernelGGL(k_stats, dim3(G,8), dim3(256), 0, stream,
                       h_g, intf, sp, g_pfs, b_pfs, g_sfs, b_sfs, part_p, part_s, g0);
  }

  hipLaunchKernelGGL(k_reduce, dim3(1152), dim3(256), 0, stream, part_p, part_s, xbar, ybar);
  hipLaunchKernelGGL(k_proj_part, dim3(16,10,2), dim3(256), 0, stream,
                     xbar, ybar, Wpfs, Wsfs, pbuf);
  hipLaunchKernelGGL(k_projred, dim3(256), dim3(256), 0, stream,
                     pbuf, bpfs, bsfs, tpre, spre);
  hipLaunchKernelGGL(k_lnrow, dim3(64), dim3(256), 0, stream, tpre, spre, out);
  hipLaunchKernelGGL(k_head, dim3(32), dim3(256), 0, stream,
                     Wpc, bpc, Wc0, bc0, Wc1, bc1, Wc2, bc2, out);
}

// Round 9
// 1399.896 us; speedup vs baseline: 1.2745x; 1.0983x over previous
//
#include <hip/hip_runtime.h>
#include <hip/hip_bf16.h>

typedef __bf16 bf16x8 __attribute__((ext_vector_type(8)));
typedef float f32x4 __attribute__((ext_vector_type(4)));
typedef unsigned long long u64;

#define EPSV 1e-5f

__device__ __forceinline__ float bf2f(unsigned short u){
  unsigned int x = ((unsigned int)u) << 16;
  return __builtin_bit_cast(float, x);
}
__device__ __forceinline__ unsigned short f2bf(float f){
  __bf16 b = (__bf16)f;
  return __builtin_bit_cast(unsigned short, b);
}
__device__ __forceinline__ float gelu_exact(float x){
  return 0.5f * x * (1.0f + erff(x * 0.7071067811865476f));
}
__device__ __forceinline__ void gload_lds16(const void* g, void* l){
  __builtin_amdgcn_global_load_lds((const __attribute__((address_space(1))) unsigned int*)g,
                                   (__attribute__((address_space(3))) unsigned int*)l, 16, 0, 0);
}

// ---------------------------------------------------------------------------
// 256x256 (BK=64) 8-wave 4-phase bf16 MFMA GEMM — SINGLE barrier per phase.
// Phase = {ds_reads(p); stage; s_barrier; [auto-lgkm]; setprio MFMA setprio}.
// Removing the post-MFMA barrier lets a wave that finishes MFMA(p) start its
// reads(p+1) while other waves still MFMA -> LDS pipe streams under MFMA
// (lockstep cost: LDS 2300cyc + MFMA 2480cyc serial = measured 4690cyc/tile).
// Legality: every stage targets a region whose last ds_read is >=2 phases
// earlier, with >=1 barrier separating read-completion from the stage:
//   ph1 stage A-q1(kt+1,d^1): read ph3(kt-1); lgkm0(ph3) < bar(ph4) < stage ✓
//   ph3 stage A-q0(kt+2,d):   read ph1(kt);   lgkm0(ph1) < bar(ph2) < stage ✓
//   ph3 stage B-q0(kt+2,d):   read ph1(kt);   same ✓
//   ph4 stage B-q1(kt+2,d):   read ph2(kt);   lgkm0(ph2) < bar(ph3) < stage ✓
// vmcnt(6) at ph4 end: newest 6 = ph3(kt)x4 + ph4(kt)x2 (all tile kt+2), so
// everything of tile kt+1 has landed before ph1(kt+1) reads it. Tail: vmcnt(0).
// MODE 0: bias+GELU dual split @4096; 1: bias; 3: V^T; 4: dual K/V^T @4096.
// ---------------------------------------------------------------------------
template<int MODE>
__global__ __launch_bounds__(512, 2)
void gemm256(const unsigned short* __restrict__ A, const unsigned short* __restrict__ B,
             const float* __restrict__ bias0, const float* __restrict__ bias1,
             void* __restrict__ C0v, void* __restrict__ C1v,
             int Kd, int lda, int ldb, int ldc)
{
  __shared__ char smem[131072];  // A: [2 dbuf][2 half][128][64]b16 @0; B same @65536
  const int t = threadIdx.x;
  const int w = t >> 6, l = t & 63;
  const int wm = w >> 2, wn = w & 3;        // wave grid 2(M) x 4(N)
  const int lr = l & 15, lg = l >> 4;
  const int nbx = gridDim.x;
  const int nwg = nbx * gridDim.y;
  int bid = blockIdx.y*nbx + blockIdx.x;
  if ((nwg & 7) == 0) bid = (bid & 7)*(nwg >> 3) + (bid >> 3);
  const int bm0 = (bid / nbx) * 256, bn0 = (bid % nbx) * 256;
  const int nk = Kd >> 6;

  const int srow = t >> 3;                   // staging row-within-quarter 0..63
  const int sslot = t & 7;                   // staging 16B slot

  f32x4 acc[8][4];
  #pragma unroll
  for (int i=0;i<8;++i){
    #pragma unroll
    for (int j=0;j<4;++j){ f32x4 zz = {0.f,0.f,0.f,0.f}; acc[i][j] = zz; }
  }
  bf16x8 a0[4][2], a1[4][2], b0[2][2], b1[2][2];

  auto stage = [&](int kt, int mat, int hf, int q){
    if (kt >= nk) return;
    const int r_h = q*64 + srow;
    const int s_ = sslot ^ ((r_h >> 1) & 7);
    const unsigned short* gp = (mat ? B + (size_t)(bn0 + hf*128 + r_h)*ldb
                                    : A + (size_t)(bm0 + hf*128 + r_h)*lda)
                               + (kt << 6) + s_*8;
    char* lp = smem + mat*65536 + (kt&1)*32768 + hf*16384 + q*8192 + t*16;
    gload_lds16((const void*)gp, (void*)lp);
  };
  auto rdA = [&](int d, int fm, int kk)->bf16x8{
    const int r = fm*16 + lr;
    const int s_ = (kk*4 + lg) ^ ((r >> 1) & 7);
    return *(const bf16x8*)(smem + d*32768 + wm*16384 + r*128 + s_*16);
  };
  auto rdB = [&](int d, int fn, int kk)->bf16x8{
    const int r = (wn&1)*64 + fn*16 + lr;
    const int s_ = (kk*4 + lg) ^ ((r >> 1) & 7);
    return *(const bf16x8*)(smem + 65536 + d*32768 + (wn>>1)*16384 + r*128 + s_*16);
  };

  auto ktile = [&](int kt, int d){
    // ---- phase 1: rd a0(8)+b0(4); stage A-q1(kt+1); MFMA S1(a0,b0) ----
    #pragma unroll
    for (int fm=0; fm<4; ++fm){ a0[fm][0] = rdA(d, fm, 0); a0[fm][1] = rdA(d, fm, 1); }
    #pragma unroll
    for (int fn=0; fn<2; ++fn){ b0[fn][0] = rdB(d, fn, 0); b0[fn][1] = rdB(d, fn, 1); }
    stage(kt+1, 0, 0, 1); stage(kt+1, 0, 1, 1);
    __builtin_amdgcn_s_barrier();
    __builtin_amdgcn_s_setprio(1);
    #pragma unroll
    for (int fm=0; fm<4; ++fm)
      #pragma unroll
      for (int fn=0; fn<2; ++fn)
        #pragma unroll
        for (int kk=0; kk<2; ++kk)
          acc[fm][fn] = __builtin_amdgcn_mfma_f32_16x16x32_bf16(a0[fm][kk], b0[fn][kk], acc[fm][fn], 0,0,0);
    __builtin_amdgcn_s_setprio(0);
    // ---- phase 2: rd b1(4); MFMA S2(a0,b1) ----
    #pragma unroll
    for (int fn=0; fn<2; ++fn){ b1[fn][0] = rdB(d, fn+2, 0); b1[fn][1] = rdB(d, fn+2, 1); }
    __builtin_amdgcn_s_barrier();
    __builtin_amdgcn_s_setprio(1);
    #pragma unroll
    for (int fm=0; fm<4; ++fm)
      #pragma unroll
      for (int fn=0; fn<2; ++fn)
        #pragma unroll
        for (int kk=0; kk<2; ++kk)
          acc[fm][fn+2] = __builtin_amdgcn_mfma_f32_16x16x32_bf16(a0[fm][kk], b1[fn][kk], acc[fm][fn+2], 0,0,0);
    __builtin_amdgcn_s_setprio(0);
    // ---- phase 3: rd a1(8); stage A-q0(kt+2)+B-q0(kt+2); MFMA S3(a1,b1) ----
    #pragma unroll
    for (int fm=0; fm<4; ++fm){ a1[fm][0] = rdA(d, fm+4, 0); a1[fm][1] = rdA(d, fm+4, 1); }
    stage(kt+2, 0, 0, 0); stage(kt+2, 0, 1, 0);
    stage(kt+2, 1, 0, 0); stage(kt+2, 1, 1, 0);
    __builtin_amdgcn_s_barrier();
    __builtin_amdgcn_s_setprio(1);
    #pragma unroll
    for (int fm=0; fm<4; ++fm)
      #pragma unroll
      for (int fn=0; fn<2; ++fn)
        #pragma unroll
        for (int kk=0; kk<2; ++kk)
          acc[fm+4][fn+2] = __builtin_amdgcn_mfma_f32_16x16x32_bf16(a1[fm][kk], b1[fn][kk], acc[fm+4][fn+2], 0,0,0);
    __builtin_amdgcn_s_setprio(0);
    // ---- phase 4: stage B-q1(kt+2); MFMA S4(a1,b0); vmcnt gate ----
    stage(kt+2, 1, 0, 1); stage(kt+2, 1, 1, 1);
    __builtin_amdgcn_s_barrier();
    __builtin_amdgcn_s_setprio(1);
    #pragma unroll
    for (int fm=0; fm<4; ++fm)
      #pragma unroll
      for (int fn=0; fn<2; ++fn)
        #pragma unroll
        for (int kk=0; kk<2; ++kk)
          acc[fm+4][fn] = __builtin_amdgcn_mfma_f32_16x16x32_bf16(a1[fm][kk], b0[fn][kk], acc[fm+4][fn], 0,0,0);
    __builtin_amdgcn_s_setprio(0);
    if (kt + 2 < nk) { asm volatile("s_waitcnt vmcnt(6)" ::: "memory"); }
    else             { asm volatile("s_waitcnt vmcnt(0)" ::: "memory"); }
  };

  // prologue mirrors steady state: tile0 all 8 quarters; tile1 A-q0,B-q0,B-q1
  stage(0,0,0,0); stage(0,0,1,0); stage(0,0,0,1); stage(0,0,1,1);
  stage(0,1,0,0); stage(0,1,1,0); stage(0,1,0,1); stage(0,1,1,1);
  stage(1,0,0,0); stage(1,0,1,0);
  stage(1,1,0,0); stage(1,1,1,0);
  stage(1,1,0,1); stage(1,1,1,1);
  asm volatile("s_waitcnt vmcnt(6)" ::: "memory");   // tile0 landed
  __builtin_amdgcn_s_barrier();

  for (int kt = 0; kt < nk; kt += 2){ ktile(kt, 0); ktile(kt+1, 1); }

  // epilogue
  #pragma unroll
  for (int fm=0; fm<8; ++fm){
    #pragma unroll
    for (int fn=0; fn<4; ++fn){
      const int row0 = bm0 + wm*128 + fm*16 + lg*4;
      const int col  = bn0 + wn*64 + fn*16 + lr;
      f32x4 v = acc[fm][fn];
      if constexpr (MODE == 3){
        unsigned short* C = (unsigned short*)C0v;
        const float bb = bias0[col];
        u64 pack = 0;
        #pragma unroll
        for (int j=0;j<4;++j) pack |= (u64)f2bf(v[j] + bb) << (16*j);
        *(u64*)(C + (size_t)col*256 + (size_t)(row0>>8)*1048576 + (row0&255)) = pack;
      } else if constexpr (MODE == 4){
        if (col < 4096){
          unsigned short* C = (unsigned short*)C0v;
          const float bb = bias0[col];
          #pragma unroll
          for (int j=0;j<4;++j) C[(size_t)(row0+j)*ldc + col] = f2bf(v[j] + bb);
        } else {
          const int c2 = col - 4096;
          unsigned short* C = (unsigned short*)C1v;
          const float bb = bias1[c2];
          u64 pack = 0;
          #pragma unroll
          for (int j=0;j<4;++j) pack |= (u64)f2bf(v[j] + bb) << (16*j);
          *(u64*)(C + (size_t)c2*256 + (size_t)(row0>>8)*1048576 + (row0&255)) = pack;
        }
      } else {
        const bool hi = (MODE == 0) && (col >= 4096);
        unsigned short* C = (unsigned short*)(hi ? C1v : C0v);
        const int c2 = hi ? (col - 4096) : col;
        const float bb = hi ? bias1[c2] : bias0[c2];
        #pragma unroll
        for (int j=0;j<4;++j){
          float x = v[j] + bb;
          if constexpr (MODE==0) x = gelu_exact(x);
          C[(size_t)(row0+j)*ldc + c2] = f2bf(x);
        }
      }
    }
  }
}

// ---------------------------------------------------------------------------
// 128x128 (BK=32) bf16 MFMA GEMM (small attention GEMMs). MODE 2: *scale->fp32.
// ---------------------------------------------------------------------------
template<int MODE>
__global__ __launch_bounds__(256)
void gemm_bt(const unsigned short* __restrict__ A, const unsigned short* __restrict__ B,
             const float* __restrict__ bias, void* __restrict__ Cv,
             int Kd, int lda, int ldb, int ldc,
             long sA2, long sA1, long sB2, long sB1, long sC2, long sC1,
             float scale)
{
  __shared__ unsigned short lds[2][2][4096];
  const int t = threadIdx.x;
  const int w = t >> 6, l = t & 63;
  const int z = blockIdx.z;
  A += (size_t)(z>>2)*sA2 + (size_t)(z&3)*sA1;
  B += (size_t)(z>>2)*sB2 + (size_t)(z&3)*sB1;
  const int bm0 = blockIdx.y * 128, bn0 = blockIdx.x * 128;
  const int nk = Kd >> 5;

  const int sr = l >> 2;
  const int ss = l & 3;

  f32x4 acc[4][4];
  #pragma unroll
  for (int i=0;i<4;++i){
    #pragma unroll
    for (int j=0;j<4;++j){ f32x4 zz = {0.f,0.f,0.f,0.f}; acc[i][j] = zz; }
  }

  const int wm = w >> 1, wn = w & 1;
  const int lr = l & 15, lg = l >> 4;

  auto stage = [&](int kt, int bb){
    const int k0 = kt << 5;
    #pragma unroll
    for (int i=0;i<2;++i){
      const int r  = w*32 + i*16 + sr;
      const int sa = ss ^ ((r>>1)&3);
      const unsigned short* ga = A + (size_t)(bm0 + r)*lda + (k0 + sa*8);
      gload_lds16((const void*)ga, (void*)((char*)&lds[bb][0][0] + w*2048 + i*1024));
      const unsigned short* gb = B + (size_t)(bn0 + r)*ldb + (k0 + sa*8);
      gload_lds16((const void*)gb, (void*)((char*)&lds[bb][1][0] + w*2048 + i*1024));
    }
  };

  int buf = 0;
  stage(0, 0);
  for (int kt=0; kt<nk; ++kt){
    __syncthreads();
    if (kt+1 < nk) stage(kt+1, buf^1);
    bf16x8 av[4], bv[4];
    #pragma unroll
    for (int fm=0; fm<4; ++fm){
      const int row = wm*64 + fm*16 + lr;
      const int sl  = lg ^ ((row>>1)&3);
      av[fm] = *(const bf16x8*)((const char*)&lds[buf][0][0] + row*64 + sl*16);
    }
    #pragma unroll
    for (int fn=0; fn<4; ++fn){
      const int col = wn*64 + fn*16 + lr;
      const int sl  = lg ^ ((col>>1)&3);
      bv[fn] = *(const bf16x8*)((const char*)&lds[buf][1][0] + col*64 + sl*16);
    }
    #pragma unroll
    for (int fm=0; fm<4; ++fm){
      #pragma unroll
      for (int fn=0; fn<4; ++fn)
        acc[fm][fn] = __builtin_amdgcn_mfma_f32_16x16x32_bf16(av[fm], bv[fn], acc[fm][fn], 0,0,0);
    }
    buf ^= 1;
  }

  const size_t coff = (size_t)(z>>2)*sC2 + (size_t)(z&3)*sC1;
  #pragma unroll
  for (int fm=0; fm<4; ++fm){
    #pragma unroll
    for (int fn=0; fn<4; ++fn){
      const int row0 = bm0 + wm*64 + fm*16 + lg*4;
      const int col  = bn0 + wn*64 + fn*16 + lr;
      f32x4 v = acc[fm][fn];
      if constexpr (MODE == 2){
        float* C = (float*)Cv + coff;
        #pragma unroll
        for (int j=0;j<4;++j) C[(size_t)(row0+j)*ldc + col] = v[j]*scale;
      }
    }
  }
}

// ---------------------------------------------------------------------------
__global__ __launch_bounds__(256)
void k_convh(const float* __restrict__ in, unsigned short* __restrict__ out){
  const size_t id = (size_t)blockIdx.x*256 + threadIdx.x;
  float4 v = ((const float4*)in)[id];
  u64 pack = (u64)f2bf(v.x) | ((u64)f2bf(v.y)<<16) | ((u64)f2bf(v.z)<<32) | ((u64)f2bf(v.w)<<48);
  *(u64*)(out + id*4) = pack;
}

__global__ __launch_bounds__(256)
void k_tconv(const float* __restrict__ W, unsigned short* __restrict__ Wt, int Kd, int N){
  __shared__ float lt[64][65];
  const int t = threadIdx.x;
  const int n0 = blockIdx.x*64, k0 = blockIdx.y*64;
  #pragma unroll
  for (int i=0;i<16;++i){
    int lin = i*256 + t; int r = lin>>6, c = lin&63;
    lt[r][c] = W[(size_t)(k0+r)*N + n0 + c];
  }
  __syncthreads();
  #pragma unroll
  for (int i=0;i<16;++i){
    int lin = i*256 + t; int n = lin>>6, k = lin&63;
    Wt[(size_t)(n0+n)*Kd + k0 + k] = f2bf(lt[k][n]);
  }
}

__global__ __launch_bounds__(256)
void k_softmax(const float* __restrict__ S, unsigned short* __restrict__ P){
  const int t = threadIdx.x, w = t>>6, l = t&63;
  const size_t row = (size_t)blockIdx.x*4 + w;
  float4 v = *(const float4*)(S + row*256 + l*4);
  float m = fmaxf(fmaxf(v.x,v.y), fmaxf(v.z,v.w));
  #pragma unroll
  for (int off=32; off; off>>=1) m = fmaxf(m, __shfl_xor(m, off));
  float e0 = expf(v.x-m), e1 = expf(v.y-m), e2 = expf(v.z-m), e3 = expf(v.w-m);
  float s = e0+e1+e2+e3;
  #pragma unroll
  for (int off=32; off; off>>=1) s += __shfl_xor(s, off);
  const float inv = 1.0f/s;
  u64 pack = (u64)f2bf(e0*inv) | ((u64)f2bf(e1*inv)<<16) | ((u64)f2bf(e2*inv)<<32) | ((u64)f2bf(e3*inv)<<48);
  *(u64*)(P + row*256 + l*4) = pack;
}

__device__ __forceinline__ void blkred2(float& a, float& b, float* sred, int t){
  #pragma unroll
  for (int off=32; off; off>>=1){ a += __shfl_xor(a, off); b += __shfl_xor(b, off); }
  __syncthreads();
  if ((t&63)==0){ sred[(t>>6)*2] = a; sred[(t>>6)*2+1] = b; }
  __syncthreads();
  a = sred[0]+sred[2]+sred[4]+sred[6];
  b = sred[1]+sred[3]+sred[5]+sred[7];
}

// 16 row-groups per batch (256 blocks at G=16 — was 128, half the GPU idle)
__global__ __launch_bounds__(256)
void k_stats(const float* __restrict__ h, const float* __restrict__ intf,
             const unsigned short* __restrict__ sp,
             const float* __restrict__ g_pfs, const float* __restrict__ b_pfs,
             const float* __restrict__ g_sfs, const float* __restrict__ b_sfs,
             float* __restrict__ part_p, float* __restrict__ part_s, int g0)
{
  __shared__ float sred[8];
  const int bl = blockIdx.x, grp = blockIdx.y, t = threadIdx.x;
  float zacc[20], wacc[16];
  #pragma unroll
  for (int j=0;j<20;++j) zacc[j]=0.f;
  #pragma unroll
  for (int j=0;j<16;++j) wacc[j]=0.f;
  for (int rr=0; rr<16; ++rr){
    const size_t r = (size_t)bl*256 + grp*16 + rr;
    float hv[4], iv[16], sv[16];
    #pragma unroll
    for (int j=0;j<4;++j) hv[j] = h[r*1024 + j*256 + t];
    float s1=0.f, s2=0.f;
    #pragma unroll
    for (int j=0;j<16;++j){ float x = intf[r*4096 + j*256 + t]; iv[j]=x; s1+=x; s2+=x*x; }
    blkred2(s1,s2,sred,t);
    const float m1 = s1*(1.f/4096.f);
    const float rs1 = rsqrtf(fmaxf(s2*(1.f/4096.f) - m1*m1, 0.f) + EPSV);
    float t1=0.f, t2=0.f;
    #pragma unroll
    for (int j=0;j<4;++j){ t1 += hv[j]; t2 += hv[j]*hv[j]; }
    #pragma unroll
    for (int j=0;j<16;++j){ float y = (iv[j]-m1)*rs1; iv[j]=y; t1+=y; t2+=y*y; }
    blkred2(t1,t2,sred,t);
    const float m2 = t1*(1.f/5120.f);
    const float rs2 = rsqrtf(fmaxf(t2*(1.f/5120.f) - m2*m2, 0.f) + EPSV);
    #pragma unroll
    for (int j=0;j<4;++j){ int idx = j*256+t; zacc[j] += ((hv[j]-m2)*rs2)*g_pfs[idx] + b_pfs[idx]; }
    #pragma unroll
    for (int j=0;j<16;++j){ int idx = 1024 + j*256+t; zacc[4+j] += ((iv[j]-m2)*rs2)*g_pfs[idx] + b_pfs[idx]; }
    float u1=0.f, u2=0.f;
    #pragma unroll
    for (int j=0;j<16;++j){ float x = bf2f(sp[r*4096 + j*256 + t]); sv[j]=x; u1+=x; u2+=x*x; }
    blkred2(u1,u2,sred,t);
    const float m3 = u1*(1.f/4096.f);
    const float rs3 = rsqrtf(fmaxf(u2*(1.f/4096.f) - m3*m3, 0.f) + EPSV);
    #pragma unroll
    for (int j=0;j<16;++j){ int idx = j*256+t; wacc[j] += ((sv[j]-m3)*rs3)*g_sfs[idx] + b_sfs[idx]; }
  }
  const size_t pb = (size_t)(g0 + bl)*16 + grp;
  #pragma unroll
  for (int j=0;j<20;++j) part_p[pb*5120 + j*256 + t] = zacc[j];
  #pragma unroll
  for (int j=0;j<16;++j) part_s[pb*4096 + j*256 + t] = wacc[j];
}

__global__ __launch_bounds__(256)
void k_reduce(const float* __restrict__ part_p, const float* __restrict__ part_s,
              float* __restrict__ xbar, float* __restrict__ ybar){
  int id = blockIdx.x*256 + threadIdx.x;
  if (id < 32*5120){
    const int b = id / 5120, i = id % 5120;
    float s = 0.f;
    for (int g=0; g<16; ++g) s += part_p[((size_t)b*16+g)*5120 + i];
    xbar[(size_t)b*5120 + i] = s * (1.f/256.f);
  } else {
    id -= 32*5120;
    const int b = id / 4096, i = id % 4096;
    float s = 0.f;
    for (int g=0; g<16; ++g) s += part_s[((size_t)b*16+g)*4096 + i];
    ybar[(size_t)b*4096 + i] = s * (1.f/256.f);
  }
}

__global__ __launch_bounds__(256)
void k_proj_part(const float* __restrict__ xbar, const float* __restrict__ ybar,
                 const float* __restrict__ Wpfs, const float* __restrict__ Wsfs,
                 float* __restrict__ pbuf){
  const int path = blockIdx.z;
  const int y = blockIdx.y;
  if (path == 1 && y >= 8) return;
  const int Kp = path ? 4096 : 5120;
  const float* X = path ? ybar : xbar;
  const float* W = path ? Wsfs : Wpfs;
  const int t = threadIdx.x;
  const int col = blockIdx.x*64 + (t & 63);
  const int sub = t >> 6;
  const int k0 = y*512 + sub*128;
  float acc[32];
  #pragma unroll
  for (int b=0;b<32;++b) acc[b] = 0.f;
  for (int i4=0; i4<32; ++i4){
    const int k = k0 + i4*4;
    float wv0 = W[(size_t)(k  )*1024 + col];
    float wv1 = W[(size_t)(k+1)*1024 + col];
    float wv2 = W[(size_t)(k+2)*1024 + col];
    float wv3 = W[(size_t)(k+3)*1024 + col];
    #pragma unroll
    for (int b=0;b<32;++b){
      float4 xv = *(const float4*)(X + (size_t)b*Kp + k);
      acc[b] += xv.x*wv0 + xv.y*wv1 + xv.z*wv2 + xv.w*wv3;
    }
  }
  float* dst = pbuf + ((size_t)(path*40 + y*4 + sub)*32)*1024 + col;
  #pragma unroll
  for (int b=0;b<32;++b) dst[(size_t)b*1024] = acc[b];
}

__global__ __launch_bounds__(256)
void k_projred(const float* __restrict__ pbuf,
               const float* __restrict__ bpfs, const float* __restrict__ bsfs,
               float* __restrict__ tpre, float* __restrict__ spre){
  const int id = blockIdx.x*256 + threadIdx.x;
  const int path = id >> 15;
  const int rem = id & 32767;
  const int b = rem >> 10, col = rem & 1023;
  const int ns = path ? 32 : 40;
  const float* src = pbuf + ((size_t)(path*40)*32 + b)*1024 + col;
  float s = path ? bsfs[col] : bpfs[col];
  for (int g=0; g<ns; ++g) s += src[(size_t)g*32*1024];
  (path ? spre : tpre)[(size_t)b*1024 + col] = s;
}

__global__ __launch_bounds__(256)
void k_lnrow(const float* __restrict__ tpre, const float* __restrict__ spre,
             float* __restrict__ out){
  __shared__ float sred[8];
  const int id = blockIdx.x, t = threadIdx.x;
  const int path = id >> 5, b = id & 31;
  const float* src = (path ? spre : tpre) + (size_t)b*1024;
  float v[4]; float s1=0.f, s2=0.f;
  #pragma unroll
  for (int j=0;j<4;++j){ v[j] = src[j*256+t]; s1 += v[j]; s2 += v[j]*v[j]; }
  blkred2(s1,s2,sred,t);
  const float m = s1*(1.f/1024.f);
  const float rs = rsqrtf(fmaxf(s2*(1.f/1024.f)-m*m,0.f)+EPSV);
  float* dst = out + (path ? 35072 : 2304) + (size_t)b*1024;
  #pragma unroll
  for (int j=0;j<4;++j) dst[j*256+t] = (v[j]-m)*rs;
}

__global__ __launch_bounds__(256)
void k_head(const float* __restrict__ Wpc, const float* __restrict__ bpc,
            const float* __restrict__ Wc0, const float* __restrict__ bc0,
            const float* __restrict__ Wc1, const float* __restrict__ bc1,
            const float* __restrict__ Wc2, const float* __restrict__ bc2,
            float* __restrict__ out){
  __shared__ float slog[16];
  __shared__ int sy;
  const int b = blockIdx.x, t = threadIdx.x, w = t>>6, l = t&63;
  const float* pv = out + 2304 + (size_t)b*1024;
  const float* sv = out + 35072 + (size_t)b*1024;
  #pragma unroll
  for (int jj=0; jj<4; ++jj){
    const int j = w*4 + jj;
    float a = 0.f;
    for (int i=l; i<1024; i+=64) a += pv[i]*Wpc[(size_t)i*16 + j];
    #pragma unroll
    for (int off=32; off; off>>=1) a += __shfl_xor(a, off);
    if (l==0){ const float lgv = a + bpc[j]; slog[j] = lgv; out[b*16 + j] = lgv; }
  }
  __syncthreads();
  if (t==0){
    int best=0; float bvv = slog[0];
    for (int i=1;i<16;++i) if (slog[i] > bvv){ bvv = slog[i]; best = i; }
    sy = best;
  }
  __syncthreads();
  const int y = sy;
  const float* Ws[3] = {Wc0, Wc1, Wc2};
  const float* bs[3] = {bc0, bc1, bc2};
  const int nouts[3] = {8,16,32};
  const int ooff[3]  = {512, 768, 1280};
  for (int hI=0; hI<3; ++hI){
    const int no = nouts[hI];
    for (int n = w; n < no; n += 4){
      const float* wr = Ws[hI] + ((size_t)y*no + n)*1024;
      float a = 0.f;
      for (int i=l; i<1024; i+=64) a += sv[i]*wr[i];
      #pragma unroll
      for (int off=32; off; off>>=1) a += __shfl_xor(a, off);
      if (l==0) out[ooff[hI] + b*no + n] = a + bs[hI][(size_t)y*no + n];
    }
  }
}

// ---------------------------------------------------------------------------
extern "C" void kernel_launch(void* const* d_in, const int* in_sizes, int n_in,
                              void* d_out, int out_size, void* d_ws, size_t ws_size,
                              hipStream_t stream)
{
  const float* h    = (const float*)d_in[0];
  const float* Wpp  = (const float*)d_in[1];
  const float* bpp  = (const float*)d_in[2];
  const float* Wsp  = (const float*)d_in[3];
  const float* bsp  = (const float*)d_in[4];
  const float* Wq   = (const float*)d_in[5];
  const float* bq   = (const float*)d_in[6];
  const float* Wk   = (const float*)d_in[7];
  const float* bk   = (const float*)d_in[8];
  const float* Wv   = (const float*)d_in[9];
  const float* bv   = (const float*)d_in[10];
  const float* g_pfs= (const float*)d_in[11];
  const float* b_pfs= (const float*)d_in[12];
  const float* Wpfs = (const float*)d_in[13];
  const float* bpfs = (const float*)d_in[14];
  const float* g_sfs= (const float*)d_in[15];
  const float* b_sfs= (const float*)d_in[16];
  const float* Wsfs = (const float*)d_in[17];
  const float* bsfs = (const float*)d_in[18];
  const float* Wpc  = (const float*)d_in[19];
  const float* bpc  = (const float*)d_in[20];
  const float* Wc0  = (const float*)d_in[21];
  const float* bc0  = (const float*)d_in[22];
  const float* Wc1  = (const float*)d_in[23];
  const float* bc1  = (const float*)d_in[24];
  const float* Wc2  = (const float*)d_in[25];
  const float* bc2  = (const float*)d_in[26];
  float* out = (float*)d_out;
  char* ws = (char*)d_ws;
  (void)in_sizes; (void)n_in; (void)out_size;

  // ---- adaptive plan (mode 0 only: isolate the gemm256 schedule change) ----
  struct PlanT { int G, NS; };
  const PlanT plans[6] = {{16,4096},{8,4096},{4,4096},{2,4096},{1,4096},{1,1024}};
  int G = 0, NS = 0;
  size_t oWt=0,oPp=0,oPs=0,oXb=0,oYb=0,oTp=0,oSp=0,oPbf=0,oHb=0,oPb=0,oSb=0,oQ=0,oK=0,oVt=0;
  for (int pi = 0; pi < 6; ++pi){
    const size_t g = plans[pi].G, ns = plans[pi].NS;
    size_t off = 0;
    auto alloc = [&](size_t bytes){ size_t o = off; off += (bytes + 255) & ~255ULL; return o; };
    size_t wt = alloc(ns*4096*2);
    size_t pp_ = alloc(32ULL*16*5120*4);
    size_t ps_ = alloc(32ULL*16*4096*4);
    size_t xb = alloc(32*5120*4);
    size_t yb = alloc(32*4096*4);
    size_t tp = alloc(32*1024*4);
    size_t sp_ = alloc(32*1024*4);
    size_t pbf = alloc(2*40*32*1024*4);
    size_t hb = alloc(g*524288);
    size_t pb = alloc(g*2097152);     // pp; aliased later by S (g*1MB) + P (g*0.5MB)
    size_t sb = alloc(g*2097152);
    size_t q  = alloc(g*2097152);
    size_t k  = alloc(g*2097152);
    size_t vt = alloc(g*2097152);
    if (off <= ws_size){
      G = (int)g; NS = (int)ns;
      oWt=wt; oPp=pp_; oPs=ps_; oXb=xb; oYb=yb; oTp=tp; oSp=sp_; oPbf=pbf;
      oHb=hb; oPb=pb; oSb=sb; oQ=q; oK=k; oVt=vt;
      break;
    }
  }
  if (!G) return;

  unsigned short* Wt   = (unsigned short*)(ws + oWt);
  float* part_p = (float*)(ws + oPp);
  float* part_s = (float*)(ws + oPs);
  float* xbar   = (float*)(ws + oXb);
  float* ybar   = (float*)(ws + oYb);
  float* tpre   = (float*)(ws + oTp);
  float* spre   = (float*)(ws + oSp);
  float* pbuf   = (float*)(ws + oPbf);
  unsigned short* h_bf = (unsigned short*)(ws + oHb);
  unsigned short* pp   = (unsigned short*)(ws + oPb);
  unsigned short* sp   = (unsigned short*)(ws + oSb);
  unsigned short* Q    = (unsigned short*)(ws + oQ);
  unsigned short* Kb   = (unsigned short*)(ws + oK);
  unsigned short* Vt   = (unsigned short*)(ws + oVt);
  float*          S    = (float*)(ws + oPb);                              // alias pp
  unsigned short* P    = (unsigned short*)(ws + oPb + (size_t)G*1048576); // alias pp tail
  float*          intf = (float*)(ws + oQ);   // aliases Q+K (contiguous, both dead)

  const float scale = 1.0f/32.0f;
  (void)oK;

  for (int g0 = 0; g0 < 32; g0 += G){
    const float* h_g = h + (size_t)g0*262144;

    hipLaunchKernelGGL(k_convh, dim3(G*256), dim3(256), 0, stream, h_g, h_bf);

    hipLaunchKernelGGL(k_tconv, dim3(64,16), dim3(256), 0, stream, Wpp, Wt, 1024, 4096);
    hipLaunchKernelGGL(gemm256<0>, dim3(16,G), dim3(512), 0, stream,
                       h_bf, Wt, bpp, bpp, (void*)pp, (void*)pp, 1024, 1024,1024,4096);
    for (int nso = 0; nso < 4096; nso += NS){
      hipLaunchKernelGGL(k_tconv, dim3(NS/64,64), dim3(256), 0, stream, Wq + nso, Wt, 4096, 4096);
      hipLaunchKernelGGL(gemm256<1>, dim3(NS/256,G), dim3(512), 0, stream,
                         pp, Wt, bq + nso, bq + nso, (void*)(Q + nso), (void*)(Q + nso), 4096, 4096,4096,4096);
    }
    hipLaunchKernelGGL(k_tconv, dim3(64,16), dim3(256), 0, stream, Wsp, Wt, 1024, 4096);
    hipLaunchKernelGGL(gemm256<0>, dim3(16,G), dim3(512), 0, stream,
                       h_bf, Wt, bsp, bsp, (void*)sp, (void*)sp, 1024, 1024,1024,4096);
    for (int nso = 0; nso < 4096; nso += NS){
      hipLaunchKernelGGL(k_tconv, dim3(NS/64,64), dim3(256), 0, stream, Wk + nso, Wt, 4096, 4096);
      hipLaunchKernelGGL(gemm256<1>, dim3(NS/256,G), dim3(512), 0, stream,
                         sp, Wt, bk + nso, bk + nso, (void*)(Kb + nso), (void*)(Kb + nso), 4096, 4096,4096,4096);
    }
    for (int nso = 0; nso < 4096; nso += NS){
      hipLaunchKernelGGL(k_tconv, dim3(NS/64,64), dim3(256), 0, stream, Wv + nso, Wt, 4096, 4096);
      hipLaunchKernelGGL(gemm256<3>, dim3(NS/256,G), dim3(512), 0, stream,
                         sp, Wt, bv + nso, bv + nso, (void*)(Vt + (size_t)nso*256), (void*)(Vt + (size_t)nso*256), 4096, 4096,4096,256);
    }
    // S = scale * Q K^T (z = b_local*4 + h) ; softmax ; intf = P V (fp32)
    hipLaunchKernelGGL(gemm_bt<2>, dim3(2,2,G*4), dim3(256), 0, stream,
                       Q, Kb, (const float*)nullptr, (void*)S, 1024, 4096,4096,256,
                       1048576L,1024L, 1048576L,1024L, 262144L,65536L, scale);
    hipLaunchKernelGGL(k_softmax, dim3(G*256), dim3(256), 0, stream, S, P);
    hipLaunchKernelGGL(gemm_bt<2>, dim3(8,2,G*4), dim3(256), 0, stream,
                       P, Vt, (const float*)nullptr, (void*)intf, 256, 256,256,4096,
                       262144L,65536L, 1048576L,262144L, 1048576L,1024L, 1.f);
    hipLaunchKernelGGL(k_stats, dim3(G,16), dim3(256), 0, stream,
                       h_g, intf, sp, g_pfs, b_pfs, g_sfs, b_sfs, part_p, part_s, g0);
  }

  hipLaunchKernelGGL(k_reduce, dim3(1152), dim3(256), 0, stream, part_p, part_s, xbar, ybar);
  hipLaunchKernelGGL(k_proj_part, dim3(16,10,2), dim3(256), 0, stream,
                     xbar, ybar, Wpfs, Wsfs, pbuf);
  hipLaunchKernelGGL(k_projred, dim3(256), dim3(256), 0, stream,
                     pbuf, bpfs, bsfs, tpre, spre);
  hipLaunchKernelGGL(k_lnrow, dim3(64), dim3(256), 0, stream, tpre, spre, out);
  hipLaunchKernelGGL(k_head, dim3(32), dim3(256), 0, stream,
                     Wpc, bpc, Wc0, bc0, Wc1, bc1, Wc2, bc2, out);
}

// Round 10
// 1318.128 us; speedup vs baseline: 1.3536x; 1.0620x over previous
//
#include <hip/hip_runtime.h>
#include <hip/hip_bf16.h>

typedef __bf16 bf16x8 __attribute__((ext_vector_type(8)));
typedef float f32x4 __attribute__((ext_vector_type(4)));
typedef unsigned long long u64;

#define EPSV 1e-5f

__device__ __forceinline__ float bf2f(unsigned short u){
  unsigned int x = ((unsigned int)u) << 16;
  return __builtin_bit_cast(float, x);
}
__device__ __forceinline__ unsigned short f2bf(float f){
  __bf16 b = (__bf16)f;
  return __builtin_bit_cast(unsigned short, b);
}
__device__ __forceinline__ float gelu_exact(float x){
  return 0.5f * x * (1.0f + erff(x * 0.7071067811865476f));
}
__device__ __forceinline__ void gload_lds16(const void* g, void* l){
  __builtin_amdgcn_global_load_lds((const __attribute__((address_space(1))) unsigned int*)g,
                                   (__attribute__((address_space(3))) unsigned int*)l, 16, 0, 0);
}

// ---------------------------------------------------------------------------
// 256x256 (BK=64) 8-wave 4-phase bf16 MFMA GEMM — SINGLE barrier per phase
// (R9 schedule, best measured: 113us, MfmaUtil 52%). Stages issued before
// ds_reads so HBM latency starts earlier; hazard proof unchanged (stage
// placement relative to barriers identical — see R9 comments):
//   ph1 stage A-q1(kt+1,d^1): read ph3(kt-1); consumed before bar(ph4) ✓
//   ph3 stage A-q0/B-q0(kt+2,d): read ph1/ph2(kt); consumed before bar ✓
//   ph4 stage B-q1(kt+2,d): read ph2(kt) ✓
// vmcnt(6) at tile end keeps tile kt+1 landed before its ph1 reads.
// MODE 0: bias+GELU dual @4096; 1: bias; 3: V^T; 4: dual K/V^T @4096.
// ---------------------------------------------------------------------------
template<int MODE>
__global__ __launch_bounds__(512, 2)
void gemm256(const unsigned short* __restrict__ A, const unsigned short* __restrict__ B,
             const float* __restrict__ bias0, const float* __restrict__ bias1,
             void* __restrict__ C0v, void* __restrict__ C1v,
             int Kd, int lda, int ldb, int ldc)
{
  __shared__ char smem[131072];
  const int t = threadIdx.x;
  const int w = t >> 6, l = t & 63;
  const int wm = w >> 2, wn = w & 3;
  const int lr = l & 15, lg = l >> 4;
  const int nbx = gridDim.x;
  const int nwg = nbx * gridDim.y;
  int bid = blockIdx.y*nbx + blockIdx.x;
  if ((nwg & 7) == 0) bid = (bid & 7)*(nwg >> 3) + (bid >> 3);
  const int bm0 = (bid / nbx) * 256, bn0 = (bid % nbx) * 256;
  const int nk = Kd >> 6;

  const int srow = t >> 3;
  const int sslot = t & 7;

  f32x4 acc[8][4];
  #pragma unroll
  for (int i=0;i<8;++i){
    #pragma unroll
    for (int j=0;j<4;++j){ f32x4 zz = {0.f,0.f,0.f,0.f}; acc[i][j] = zz; }
  }
  bf16x8 a0[4][2], a1[4][2], b0[2][2], b1[2][2];

  auto stage = [&](int kt, int mat, int hf, int q){
    if (kt >= nk) return;
    const int r_h = q*64 + srow;
    const int s_ = sslot ^ ((r_h >> 1) & 7);
    const unsigned short* gp = (mat ? B + (size_t)(bn0 + hf*128 + r_h)*ldb
                                    : A + (size_t)(bm0 + hf*128 + r_h)*lda)
                               + (kt << 6) + s_*8;
    char* lp = smem + mat*65536 + (kt&1)*32768 + hf*16384 + q*8192 + t*16;
    gload_lds16((const void*)gp, (void*)lp);
  };
  auto rdA = [&](int d, int fm, int kk)->bf16x8{
    const int r = fm*16 + lr;
    const int s_ = (kk*4 + lg) ^ ((r >> 1) & 7);
    return *(const bf16x8*)(smem + d*32768 + wm*16384 + r*128 + s_*16);
  };
  auto rdB = [&](int d, int fn, int kk)->bf16x8{
    const int r = (wn&1)*64 + fn*16 + lr;
    const int s_ = (kk*4 + lg) ^ ((r >> 1) & 7);
    return *(const bf16x8*)(smem + 65536 + d*32768 + (wn>>1)*16384 + r*128 + s_*16);
  };

  auto ktile = [&](int kt, int d){
    // ---- phase 1: stage A-q1(kt+1); rd a0(8)+b0(4); MFMA S1(a0,b0) ----
    stage(kt+1, 0, 0, 1); stage(kt+1, 0, 1, 1);
    #pragma unroll
    for (int fm=0; fm<4; ++fm){ a0[fm][0] = rdA(d, fm, 0); a0[fm][1] = rdA(d, fm, 1); }
    #pragma unroll
    for (int fn=0; fn<2; ++fn){ b0[fn][0] = rdB(d, fn, 0); b0[fn][1] = rdB(d, fn, 1); }
    __builtin_amdgcn_s_barrier();
    __builtin_amdgcn_s_setprio(1);
    #pragma unroll
    for (int fm=0; fm<4; ++fm)
      #pragma unroll
      for (int fn=0; fn<2; ++fn)
        #pragma unroll
        for (int kk=0; kk<2; ++kk)
          acc[fm][fn] = __builtin_amdgcn_mfma_f32_16x16x32_bf16(a0[fm][kk], b0[fn][kk], acc[fm][fn], 0,0,0);
    __builtin_amdgcn_s_setprio(0);
    // ---- phase 2: rd b1(4); MFMA S2(a0,b1) ----
    #pragma unroll
    for (int fn=0; fn<2; ++fn){ b1[fn][0] = rdB(d, fn+2, 0); b1[fn][1] = rdB(d, fn+2, 1); }
    __builtin_amdgcn_s_barrier();
    __builtin_amdgcn_s_setprio(1);
    #pragma unroll
    for (int fm=0; fm<4; ++fm)
      #pragma unroll
      for (int fn=0; fn<2; ++fn)
        #pragma unroll
        for (int kk=0; kk<2; ++kk)
          acc[fm][fn+2] = __builtin_amdgcn_mfma_f32_16x16x32_bf16(a0[fm][kk], b1[fn][kk], acc[fm][fn+2], 0,0,0);
    __builtin_amdgcn_s_setprio(0);
    // ---- phase 3: stage A-q0+B-q0(kt+2); rd a1(8); MFMA S3(a1,b1) ----
    stage(kt+2, 0, 0, 0); stage(kt+2, 0, 1, 0);
    stage(kt+2, 1, 0, 0); stage(kt+2, 1, 1, 0);
    #pragma unroll
    for (int fm=0; fm<4; ++fm){ a1[fm][0] = rdA(d, fm+4, 0); a1[fm][1] = rdA(d, fm+4, 1); }
    __builtin_amdgcn_s_barrier();
    __builtin_amdgcn_s_setprio(1);
    #pragma unroll
    for (int fm=0; fm<4; ++fm)
      #pragma unroll
      for (int fn=0; fn<2; ++fn)
        #pragma unroll
        for (int kk=0; kk<2; ++kk)
          acc[fm+4][fn+2] = __builtin_amdgcn_mfma_f32_16x16x32_bf16(a1[fm][kk], b1[fn][kk], acc[fm+4][fn+2], 0,0,0);
    __builtin_amdgcn_s_setprio(0);
    // ---- phase 4: stage B-q1(kt+2); MFMA S4(a1,b0); vmcnt gate ----
    stage(kt+2, 1, 0, 1); stage(kt+2, 1, 1, 1);
    __builtin_amdgcn_s_barrier();
    __builtin_amdgcn_s_setprio(1);
    #pragma unroll
    for (int fm=0; fm<4; ++fm)
      #pragma unroll
      for (int fn=0; fn<2; ++fn)
        #pragma unroll
        for (int kk=0; kk<2; ++kk)
          acc[fm+4][fn] = __builtin_amdgcn_mfma_f32_16x16x32_bf16(a1[fm][kk], b0[fn][kk], acc[fm+4][fn], 0,0,0);
    __builtin_amdgcn_s_setprio(0);
    if (kt + 2 < nk) { asm volatile("s_waitcnt vmcnt(6)" ::: "memory"); }
    else             { asm volatile("s_waitcnt vmcnt(0)" ::: "memory"); }
  };

  // prologue
  stage(0,0,0,0); stage(0,0,1,0); stage(0,0,0,1); stage(0,0,1,1);
  stage(0,1,0,0); stage(0,1,1,0); stage(0,1,0,1); stage(0,1,1,1);
  stage(1,0,0,0); stage(1,0,1,0);
  stage(1,1,0,0); stage(1,1,1,0);
  stage(1,1,0,1); stage(1,1,1,1);
  asm volatile("s_waitcnt vmcnt(6)" ::: "memory");
  __builtin_amdgcn_s_barrier();

  for (int kt = 0; kt < nk; kt += 2){ ktile(kt, 0); ktile(kt+1, 1); }

  // epilogue
  #pragma unroll
  for (int fm=0; fm<8; ++fm){
    #pragma unroll
    for (int fn=0; fn<4; ++fn){
      const int row0 = bm0 + wm*128 + fm*16 + lg*4;
      const int col  = bn0 + wn*64 + fn*16 + lr;
      f32x4 v = acc[fm][fn];
      if constexpr (MODE == 3){
        unsigned short* C = (unsigned short*)C0v;
        const float bb = bias0[col];
        u64 pack = 0;
        #pragma unroll
        for (int j=0;j<4;++j) pack |= (u64)f2bf(v[j] + bb) << (16*j);
        *(u64*)(C + (size_t)col*256 + (size_t)(row0>>8)*1048576 + (row0&255)) = pack;
      } else if constexpr (MODE == 4){
        if (col < 4096){
          unsigned short* C = (unsigned short*)C0v;
          const float bb = bias0[col];
          #pragma unroll
          for (int j=0;j<4;++j) C[(size_t)(row0+j)*ldc + col] = f2bf(v[j] + bb);
        } else {
          const int c2 = col - 4096;
          unsigned short* C = (unsigned short*)C1v;
          const float bb = bias1[c2];
          u64 pack = 0;
          #pragma unroll
          for (int j=0;j<4;++j) pack |= (u64)f2bf(v[j] + bb) << (16*j);
          *(u64*)(C + (size_t)c2*256 + (size_t)(row0>>8)*1048576 + (row0&255)) = pack;
        }
      } else {
        const bool hi = (MODE == 0) && (col >= 4096);
        unsigned short* C = (unsigned short*)(hi ? C1v : C0v);
        const int c2 = hi ? (col - 4096) : col;
        const float bb = hi ? bias1[c2] : bias0[c2];
        #pragma unroll
        for (int j=0;j<4;++j){
          float x = v[j] + bb;
          if constexpr (MODE==0) x = gelu_exact(x);
          C[(size_t)(row0+j)*ldc + c2] = f2bf(x);
        }
      }
    }
  }
}

// ---------------------------------------------------------------------------
// 128x128 (BK=32) bf16 MFMA GEMM (small attention GEMMs). MODE 2: *scale->fp32.
// ---------------------------------------------------------------------------
template<int MODE>
__global__ __launch_bounds__(256)
void gemm_bt(const unsigned short* __restrict__ A, const unsigned short* __restrict__ B,
             const float* __restrict__ bias, void* __restrict__ Cv,
             int Kd, int lda, int ldb, int ldc,
             long sA2, long sA1, long sB2, long sB1, long sC2, long sC1,
             float scale)
{
  __shared__ unsigned short lds[2][2][4096];
  const int t = threadIdx.x;
  const int w = t >> 6, l = t & 63;
  const int z = blockIdx.z;
  A += (size_t)(z>>2)*sA2 + (size_t)(z&3)*sA1;
  B += (size_t)(z>>2)*sB2 + (size_t)(z&3)*sB1;
  const int bm0 = blockIdx.y * 128, bn0 = blockIdx.x * 128;
  const int nk = Kd >> 5;

  const int sr = l >> 2;
  const int ss = l & 3;

  f32x4 acc[4][4];
  #pragma unroll
  for (int i=0;i<4;++i){
    #pragma unroll
    for (int j=0;j<4;++j){ f32x4 zz = {0.f,0.f,0.f,0.f}; acc[i][j] = zz; }
  }

  const int wm = w >> 1, wn = w & 1;
  const int lr = l & 15, lg = l >> 4;

  auto stage = [&](int kt, int bb){
    const int k0 = kt << 5;
    #pragma unroll
    for (int i=0;i<2;++i){
      const int r  = w*32 + i*16 + sr;
      const int sa = ss ^ ((r>>1)&3);
      const unsigned short* ga = A + (size_t)(bm0 + r)*lda + (k0 + sa*8);
      gload_lds16((const void*)ga, (void*)((char*)&lds[bb][0][0] + w*2048 + i*1024));
      const unsigned short* gb = B + (size_t)(bn0 + r)*ldb + (k0 + sa*8);
      gload_lds16((const void*)gb, (void*)((char*)&lds[bb][1][0] + w*2048 + i*1024));
    }
  };

  int buf = 0;
  stage(0, 0);
  for (int kt=0; kt<nk; ++kt){
    __syncthreads();
    if (kt+1 < nk) stage(kt+1, buf^1);
    bf16x8 av[4], bv[4];
    #pragma unroll
    for (int fm=0; fm<4; ++fm){
      const int row = wm*64 + fm*16 + lr;
      const int sl  = lg ^ ((row>>1)&3);
      av[fm] = *(const bf16x8*)((const char*)&lds[buf][0][0] + row*64 + sl*16);
    }
    #pragma unroll
    for (int fn=0; fn<4; ++fn){
      const int col = wn*64 + fn*16 + lr;
      const int sl  = lg ^ ((col>>1)&3);
      bv[fn] = *(const bf16x8*)((const char*)&lds[buf][1][0] + col*64 + sl*16);
    }
    #pragma unroll
    for (int fm=0; fm<4; ++fm){
      #pragma unroll
      for (int fn=0; fn<4; ++fn)
        acc[fm][fn] = __builtin_amdgcn_mfma_f32_16x16x32_bf16(av[fm], bv[fn], acc[fm][fn], 0,0,0);
    }
    buf ^= 1;
  }

  const size_t coff = (size_t)(z>>2)*sC2 + (size_t)(z&3)*sC1;
  #pragma unroll
  for (int fm=0; fm<4; ++fm){
    #pragma unroll
    for (int fn=0; fn<4; ++fn){
      const int row0 = bm0 + wm*64 + fm*16 + lg*4;
      const int col  = bn0 + wn*64 + fn*16 + lr;
      f32x4 v = acc[fm][fn];
      if constexpr (MODE == 2){
        float* C = (float*)Cv + coff;
        #pragma unroll
        for (int j=0;j<4;++j) C[(size_t)(row0+j)*ldc + col] = v[j]*scale;
      }
    }
  }
}

// ---------------------------------------------------------------------------
__global__ __launch_bounds__(256)
void k_convh(const float* __restrict__ in, unsigned short* __restrict__ out){
  const size_t id = (size_t)blockIdx.x*256 + threadIdx.x;
  float4 v = ((const float4*)in)[id];
  u64 pack = (u64)f2bf(v.x) | ((u64)f2bf(v.y)<<16) | ((u64)f2bf(v.z)<<32) | ((u64)f2bf(v.w)<<48);
  *(u64*)(out + id*4) = pack;
}

__global__ __launch_bounds__(256)
void k_tconv(const float* __restrict__ W, unsigned short* __restrict__ Wt, int Kd, int N){
  __shared__ float lt[64][65];
  const int t = threadIdx.x;
  const int n0 = blockIdx.x*64, k0 = blockIdx.y*64;
  #pragma unroll
  for (int i=0;i<16;++i){
    int lin = i*256 + t; int r = lin>>6, c = lin&63;
    lt[r][c] = W[(size_t)(k0+r)*N + n0 + c];
  }
  __syncthreads();
  #pragma unroll
  for (int i=0;i<16;++i){
    int lin = i*256 + t; int n = lin>>6, k = lin&63;
    Wt[(size_t)(n0+n)*Kd + k0 + k] = f2bf(lt[k][n]);
  }
}

__global__ __launch_bounds__(256)
void k_softmax(const float* __restrict__ S, unsigned short* __restrict__ P){
  const int t = threadIdx.x, w = t>>6, l = t&63;
  const size_t row = (size_t)blockIdx.x*4 + w;
  float4 v = *(const float4*)(S + row*256 + l*4);
  float m = fmaxf(fmaxf(v.x,v.y), fmaxf(v.z,v.w));
  #pragma unroll
  for (int off=32; off; off>>=1) m = fmaxf(m, __shfl_xor(m, off));
  float e0 = expf(v.x-m), e1 = expf(v.y-m), e2 = expf(v.z-m), e3 = expf(v.w-m);
  float s = e0+e1+e2+e3;
  #pragma unroll
  for (int off=32; off; off>>=1) s += __shfl_xor(s, off);
  const float inv = 1.0f/s;
  u64 pack = (u64)f2bf(e0*inv) | ((u64)f2bf(e1*inv)<<16) | ((u64)f2bf(e2*inv)<<32) | ((u64)f2bf(e3*inv)<<48);
  *(u64*)(P + row*256 + l*4) = pack;
}

__device__ __forceinline__ void blkred2(float& a, float& b, float* sred, int t){
  #pragma unroll
  for (int off=32; off; off>>=1){ a += __shfl_xor(a, off); b += __shfl_xor(b, off); }
  __syncthreads();
  if ((t&63)==0){ sred[(t>>6)*2] = a; sred[(t>>6)*2+1] = b; }
  __syncthreads();
  a = sred[0]+sred[2]+sred[4]+sred[6];
  b = sred[1]+sred[3]+sred[5]+sred[7];
}

__global__ __launch_bounds__(256)
void k_stats(const float* __restrict__ h, const float* __restrict__ intf,
             const unsigned short* __restrict__ sp,
             const float* __restrict__ g_pfs, const float* __restrict__ b_pfs,
             const float* __restrict__ g_sfs, const float* __restrict__ b_sfs,
             float* __restrict__ part_p, float* __restrict__ part_s, int g0)
{
  __shared__ float sred[8];
  const int bl = blockIdx.x, grp = blockIdx.y, t = threadIdx.x;
  float zacc[20], wacc[16];
  #pragma unroll
  for (int j=0;j<20;++j) zacc[j]=0.f;
  #pragma unroll
  for (int j=0;j<16;++j) wacc[j]=0.f;
  for (int rr=0; rr<16; ++rr){
    const size_t r = (size_t)bl*256 + grp*16 + rr;
    float hv[4], iv[16], sv[16];
    #pragma unroll
    for (int j=0;j<4;++j) hv[j] = h[r*1024 + j*256 + t];
    float s1=0.f, s2=0.f;
    #pragma unroll
    for (int j=0;j<16;++j){ float x = intf[r*4096 + j*256 + t]; iv[j]=x; s1+=x; s2+=x*x; }
    blkred2(s1,s2,sred,t);
    const float m1 = s1*(1.f/4096.f);
    const float rs1 = rsqrtf(fmaxf(s2*(1.f/4096.f) - m1*m1, 0.f) + EPSV);
    float t1=0.f, t2=0.f;
    #pragma unroll
    for (int j=0;j<4;++j){ t1 += hv[j]; t2 += hv[j]*hv[j]; }
    #pragma unroll
    for (int j=0;j<16;++j){ float y = (iv[j]-m1)*rs1; iv[j]=y; t1+=y; t2+=y*y; }
    blkred2(t1,t2,sred,t);
    const float m2 = t1*(1.f/5120.f);
    const float rs2 = rsqrtf(fmaxf(t2*(1.f/5120.f) - m2*m2, 0.f) + EPSV);
    #pragma unroll
    for (int j=0;j<4;++j){ int idx = j*256+t; zacc[j] += ((hv[j]-m2)*rs2)*g_pfs[idx] + b_pfs[idx]; }
    #pragma unroll
    for (int j=0;j<16;++j){ int idx = 1024 + j*256+t; zacc[4+j] += ((iv[j]-m2)*rs2)*g_pfs[idx] + b_pfs[idx]; }
    float u1=0.f, u2=0.f;
    #pragma unroll
    for (int j=0;j<16;++j){ float x = bf2f(sp[r*4096 + j*256 + t]); sv[j]=x; u1+=x; u2+=x*x; }
    blkred2(u1,u2,sred,t);
    const float m3 = u1*(1.f/4096.f);
    const float rs3 = rsqrtf(fmaxf(u2*(1.f/4096.f) - m3*m3, 0.f) + EPSV);
    #pragma unroll
    for (int j=0;j<16;++j){ int idx = j*256+t; wacc[j] += ((sv[j]-m3)*rs3)*g_sfs[idx] + b_sfs[idx]; }
  }
  const size_t pb = (size_t)(g0 + bl)*16 + grp;
  #pragma unroll
  for (int j=0;j<20;++j) part_p[pb*5120 + j*256 + t] = zacc[j];
  #pragma unroll
  for (int j=0;j<16;++j) part_s[pb*4096 + j*256 + t] = wacc[j];
}

__global__ __launch_bounds__(256)
void k_reduce(const float* __restrict__ part_p, const float* __restrict__ part_s,
              float* __restrict__ xbar, float* __restrict__ ybar){
  int id = blockIdx.x*256 + threadIdx.x;
  if (id < 32*5120){
    const int b = id / 5120, i = id % 5120;
    float s = 0.f;
    for (int g=0; g<16; ++g) s += part_p[((size_t)b*16+g)*5120 + i];
    xbar[(size_t)b*5120 + i] = s * (1.f/256.f);
  } else {
    id -= 32*5120;
    const int b = id / 4096, i = id % 4096;
    float s = 0.f;
    for (int g=0; g<16; ++g) s += part_s[((size_t)b*16+g)*4096 + i];
    ybar[(size_t)b*4096 + i] = s * (1.f/256.f);
  }
}

__global__ __launch_bounds__(256)
void k_proj_part(const float* __restrict__ xbar, const float* __restrict__ ybar,
                 const float* __restrict__ Wpfs, const float* __restrict__ Wsfs,
                 float* __restrict__ pbuf){
  const int path = blockIdx.z;
  const int y = blockIdx.y;
  if (path == 1 && y >= 8) return;
  const int Kp = path ? 4096 : 5120;
  const float* X = path ? ybar : xbar;
  const float* W = path ? Wsfs : Wpfs;
  const int t = threadIdx.x;
  const int col = blockIdx.x*64 + (t & 63);
  const int sub = t >> 6;
  const int k0 = y*512 + sub*128;
  float acc[32];
  #pragma unroll
  for (int b=0;b<32;++b) acc[b] = 0.f;
  for (int i4=0; i4<32; ++i4){
    const int k = k0 + i4*4;
    float wv0 = W[(size_t)(k  )*1024 + col];
    float wv1 = W[(size_t)(k+1)*1024 + col];
    float wv2 = W[(size_t)(k+2)*1024 + col];
    float wv3 = W[(size_t)(k+3)*1024 + col];
    #pragma unroll
    for (int b=0;b<32;++b){
      float4 xv = *(const float4*)(X + (size_t)b*Kp + k);
      acc[b] += xv.x*wv0 + xv.y*wv1 + xv.z*wv2 + xv.w*wv3;
    }
  }
  float* dst = pbuf + ((size_t)(path*40 + y*4 + sub)*32)*1024 + col;
  #pragma unroll
  for (int b=0;b<32;++b) dst[(size_t)b*1024] = acc[b];
}

__global__ __launch_bounds__(256)
void k_projred(const float* __restrict__ pbuf,
               const float* __restrict__ bpfs, const float* __restrict__ bsfs,
               float* __restrict__ tpre, float* __restrict__ spre){
  const int id = blockIdx.x*256 + threadIdx.x;
  const int path = id >> 15;
  const int rem = id & 32767;
  const int b = rem >> 10, col = rem & 1023;
  const int ns = path ? 32 : 40;
  const float* src = pbuf + ((size_t)(path*40)*32 + b)*1024 + col;
  float s = path ? bsfs[col] : bpfs[col];
  for (int g=0; g<ns; ++g) s += src[(size_t)g*32*1024];
  (path ? spre : tpre)[(size_t)b*1024 + col] = s;
}

__global__ __launch_bounds__(256)
void k_lnrow(const float* __restrict__ tpre, const float* __restrict__ spre,
             float* __restrict__ out){
  __shared__ float sred[8];
  const int id = blockIdx.x, t = threadIdx.x;
  const int path = id >> 5, b = id & 31;
  const float* src = (path ? spre : tpre) + (size_t)b*1024;
  float v[4]; float s1=0.f, s2=0.f;
  #pragma unroll
  for (int j=0;j<4;++j){ v[j] = src[j*256+t]; s1 += v[j]; s2 += v[j]*v[j]; }
  blkred2(s1,s2,sred,t);
  const float m = s1*(1.f/1024.f);
  const float rs = rsqrtf(fmaxf(s2*(1.f/1024.f)-m*m,0.f)+EPSV);
  float* dst = out + (path ? 35072 : 2304) + (size_t)b*1024;
  #pragma unroll
  for (int j=0;j<4;++j) dst[j*256+t] = (v[j]-m)*rs;
}

__global__ __launch_bounds__(256)
void k_head(const float* __restrict__ Wpc, const float* __restrict__ bpc,
            const float* __restrict__ Wc0, const float* __restrict__ bc0,
            const float* __restrict__ Wc1, const float* __restrict__ bc1,
            const float* __restrict__ Wc2, const float* __restrict__ bc2,
            float* __restrict__ out){
  __shared__ float slog[16];
  __shared__ int sy;
  const int b = blockIdx.x, t = threadIdx.x, w = t>>6, l = t&63;
  const float* pv = out + 2304 + (size_t)b*1024;
  const float* sv = out + 35072 + (size_t)b*1024;
  #pragma unroll
  for (int jj=0; jj<4; ++jj){
    const int j = w*4 + jj;
    float a = 0.f;
    for (int i=l; i<1024; i+=64) a += pv[i]*Wpc[(size_t)i*16 + j];
    #pragma unroll
    for (int off=32; off; off>>=1) a += __shfl_xor(a, off);
    if (l==0){ const float lgv = a + bpc[j]; slog[j] = lgv; out[b*16 + j] = lgv; }
  }
  __syncthreads();
  if (t==0){
    int best=0; float bvv = slog[0];
    for (int i=1;i<16;++i) if (slog[i] > bvv){ bvv = slog[i]; best = i; }
    sy = best;
  }
  __syncthreads();
  const int y = sy;
  const float* Ws[3] = {Wc0, Wc1, Wc2};
  const float* bs[3] = {bc0, bc1, bc2};
  const int nouts[3] = {8,16,32};
  const int ooff[3]  = {512, 768, 1280};
  for (int hI=0; hI<3; ++hI){
    const int no = nouts[hI];
    for (int n = w; n < no; n += 4){
      const float* wr = Ws[hI] + ((size_t)y*no + n)*1024;
      float a = 0.f;
      for (int i=l; i<1024; i+=64) a += sv[i]*wr[i];
      #pragma unroll
      for (int off=32; off; off>>=1) a += __shfl_xor(a, off);
      if (l==0) out[ooff[hI] + b*no + n] = a + bs[hI][(size_t)y*no + n];
    }
  }
}

// ---------------------------------------------------------------------------
extern "C" void kernel_launch(void* const* d_in, const int* in_sizes, int n_in,
                              void* d_out, int out_size, void* d_ws, size_t ws_size,
                              hipStream_t stream)
{
  const float* h    = (const float*)d_in[0];
  const float* Wpp  = (const float*)d_in[1];
  const float* bpp  = (const float*)d_in[2];
  const float* Wsp  = (const float*)d_in[3];
  const float* bsp  = (const float*)d_in[4];
  const float* Wq   = (const float*)d_in[5];
  const float* bq   = (const float*)d_in[6];
  const float* Wk   = (const float*)d_in[7];
  const float* bk   = (const float*)d_in[8];
  const float* Wv   = (const float*)d_in[9];
  const float* bv   = (const float*)d_in[10];
  const float* g_pfs= (const float*)d_in[11];
  const float* b_pfs= (const float*)d_in[12];
  const float* Wpfs = (const float*)d_in[13];
  const float* bpfs = (const float*)d_in[14];
  const float* g_sfs= (const float*)d_in[15];
  const float* b_sfs= (const float*)d_in[16];
  const float* Wsfs = (const float*)d_in[17];
  const float* bsfs = (const float*)d_in[18];
  const float* Wpc  = (const float*)d_in[19];
  const float* bpc  = (const float*)d_in[20];
  const float* Wc0  = (const float*)d_in[21];
  const float* bc0  = (const float*)d_in[22];
  const float* Wc1  = (const float*)d_in[23];
  const float* bc1  = (const float*)d_in[24];
  const float* Wc2  = (const float*)d_in[25];
  const float* bc2  = (const float*)d_in[26];
  float* out = (float*)d_out;
  char* ws = (char*)d_ws;
  (void)in_sizes; (void)n_in; (void)out_size;

  // ---- plan selection ----
  // HOIST (G=16, ~285MB): all 5 weights converted ONCE; aliases:
  //   pp -> Kb region (pp dead before K-gemm), h_bf -> Vt region (dead before
  //   V-gemm), intf -> Q+Kb (contiguous), pbuf -> Q, S/P own 24MB slab.
  // FALLBACK (mode 0, R9-identical): per-group tconv, S/P alias pp.
  struct PlanT { int G, NS, hoist; };
  const PlanT plans[7] = {{16,4096,1},{16,4096,0},{8,4096,0},{4,4096,0},{2,4096,0},{1,4096,0},{1,1024,0}};
  int G = 0, NS = 0, HOIST = 0;
  size_t oWt=0,oWps=0,oWq=0,oWk2=0,oWv2=0,oSP=0;
  size_t oPp=0,oPs=0,oXb=0,oYb=0,oTp=0,oSp=0,oPbf=0,oHb=0,oPb=0,oSb=0,oQ=0,oK=0,oVt=0;
  for (int pi = 0; pi < 7; ++pi){
    const size_t g = plans[pi].G, ns = plans[pi].NS;
    const int hoist = plans[pi].hoist;
    size_t off = 0;
    auto alloc = [&](size_t bytes){ size_t o = off; off += (bytes + 255) & ~255ULL; return o; };
    size_t wt=0, wps=0, wq=0, wk2=0, wv2=0, sp2=0, pbf=0, hb=0, pb=0;
    size_t pp_, ps_, xb, yb, tp, sp_, sb, q, k, vt;
    if (hoist){
      wps = alloc(8192ULL*1024*2);          // [Wpp^T ; Wsp^T] 16MB
      wq  = alloc(4096ULL*4096*2);          // 32MB
      wk2 = alloc(4096ULL*4096*2);          // 32MB
      wv2 = alloc(4096ULL*4096*2);          // 32MB
      pp_ = alloc(32ULL*16*5120*4);
      ps_ = alloc(32ULL*16*4096*4);
      xb = alloc(32*5120*4); yb = alloc(32*4096*4);
      tp = alloc(32*1024*4); sp_ = alloc(32*1024*4);
      sb = alloc(g*2097152);                // sp
      q  = alloc(g*2097152);                // Q   (pbuf aliases; intf low half)
      k  = alloc(g*2097152);                // Kb  (pp aliases; intf high half)
      vt = alloc(g*2097152);                // Vt  (h_bf aliases)
      sp2 = alloc(g*1572864);               // S (g*1MB) + P (g*0.5MB)
      pbf = q; hb = vt; pb = k;
    } else {
      wt = alloc(ns*4096*2);
      pp_ = alloc(32ULL*16*5120*4);
      ps_ = alloc(32ULL*16*4096*4);
      xb = alloc(32*5120*4); yb = alloc(32*4096*4);
      tp = alloc(32*1024*4); sp_ = alloc(32*1024*4);
      pbf = alloc(2*40*32*1024*4);
      hb = alloc(g*524288);
      pb = alloc(g*2097152);                // pp; S/P alias
      sb = alloc(g*2097152);
      q  = alloc(g*2097152);
      k  = alloc(g*2097152);
      vt = alloc(g*2097152);
      sp2 = pb;                             // S/P alias pp
    }
    if (off <= ws_size){
      G = (int)g; NS = (int)ns; HOIST = hoist;
      oWt=wt; oWps=wps; oWq=wq; oWk2=wk2; oWv2=wv2; oSP=sp2;
      oPp=pp_; oPs=ps_; oXb=xb; oYb=yb; oTp=tp; oSp=sp_; oPbf=pbf;
      oHb=hb; oPb=pb; oSb=sb; oQ=q; oK=k; oVt=vt;
      break;
    }
  }
  if (!G) return;

  unsigned short* Wt   = (unsigned short*)(ws + oWt);
  unsigned short* WpsT = (unsigned short*)(ws + oWps);
  unsigned short* WqT  = (unsigned short*)(ws + oWq);
  unsigned short* WkT  = (unsigned short*)(ws + oWk2);
  unsigned short* WvT  = (unsigned short*)(ws + oWv2);
  float* part_p = (float*)(ws + oPp);
  float* part_s = (float*)(ws + oPs);
  float* xbar   = (float*)(ws + oXb);
  float* ybar   = (float*)(ws + oYb);
  float* tpre   = (float*)(ws + oTp);
  float* spre   = (float*)(ws + oSp);
  float* pbuf   = (float*)(ws + oPbf);
  unsigned short* h_bf = (unsigned short*)(ws + oHb);
  unsigned short* pp   = (unsigned short*)(ws + oPb);
  unsigned short* sp   = (unsigned short*)(ws + oSb);
  unsigned short* Q    = (unsigned short*)(ws + oQ);
  unsigned short* Kb   = (unsigned short*)(ws + oK);
  unsigned short* Vt   = (unsigned short*)(ws + oVt);
  float*          S    = (float*)(ws + oSP);
  unsigned short* P    = (unsigned short*)(ws + oSP + (size_t)G*1048576);
  float*          intf = (float*)(ws + oQ);   // spans Q+Kb (contiguous, both dead)

  const float scale = 1.0f/32.0f;
  (void)oK;

  if (HOIST){
    hipLaunchKernelGGL(k_tconv, dim3(64,16), dim3(256), 0, stream, Wpp, WpsT, 1024, 4096);
    hipLaunchKernelGGL(k_tconv, dim3(64,16), dim3(256), 0, stream, Wsp, WpsT + 4096ULL*1024, 1024, 4096);
    hipLaunchKernelGGL(k_tconv, dim3(64,64), dim3(256), 0, stream, Wq, WqT, 4096, 4096);
    hipLaunchKernelGGL(k_tconv, dim3(64,64), dim3(256), 0, stream, Wk, WkT, 4096, 4096);
    hipLaunchKernelGGL(k_tconv, dim3(64,64), dim3(256), 0, stream, Wv, WvT, 4096, 4096);
  }

  for (int g0 = 0; g0 < 32; g0 += G){
    const float* h_g = h + (size_t)g0*262144;

    hipLaunchKernelGGL(k_convh, dim3(G*256), dim3(256), 0, stream, h_g, h_bf);

    if (HOIST){
      hipLaunchKernelGGL(gemm256<0>, dim3(16,G), dim3(512), 0, stream,
                         h_bf, WpsT, bpp, bpp, (void*)pp, (void*)pp, 1024, 1024,1024,4096);
      hipLaunchKernelGGL(gemm256<1>, dim3(16,G), dim3(512), 0, stream,
                         pp, WqT, bq, bq, (void*)Q, (void*)Q, 4096, 4096,4096,4096);
      hipLaunchKernelGGL(gemm256<0>, dim3(16,G), dim3(512), 0, stream,
                         h_bf, WpsT + 4096ULL*1024, bsp, bsp, (void*)sp, (void*)sp, 1024, 1024,1024,4096);
      hipLaunchKernelGGL(gemm256<1>, dim3(16,G), dim3(512), 0, stream,
                         sp, WkT, bk, bk, (void*)Kb, (void*)Kb, 4096, 4096,4096,4096);
      hipLaunchKernelGGL(gemm256<3>, dim3(16,G), dim3(512), 0, stream,
                         sp, WvT, bv, bv, (void*)Vt, (void*)Vt, 4096, 4096,4096,256);
    } else {
      hipLaunchKernelGGL(k_tconv, dim3(64,16), dim3(256), 0, stream, Wpp, Wt, 1024, 4096);
      hipLaunchKernelGGL(gemm256<0>, dim3(16,G), dim3(512), 0, stream,
                         h_bf, Wt, bpp, bpp, (void*)pp, (void*)pp, 1024, 1024,1024,4096);
      for (int nso = 0; nso < 4096; nso += NS){
        hipLaunchKernelGGL(k_tconv, dim3(NS/64,64), dim3(256), 0, stream, Wq + nso, Wt, 4096, 4096);
        hipLaunchKernelGGL(gemm256<1>, dim3(NS/256,G), dim3(512), 0, stream,
                           pp, Wt, bq + nso, bq + nso, (void*)(Q + nso), (void*)(Q + nso), 4096, 4096,4096,4096);
      }
      hipLaunchKernelGGL(k_tconv, dim3(64,16), dim3(256), 0, stream, Wsp, Wt, 1024, 4096);
      hipLaunchKernelGGL(gemm256<0>, dim3(16,G), dim3(512), 0, stream,
                         h_bf, Wt, bsp, bsp, (void*)sp, (void*)sp, 1024, 1024,1024,4096);
      for (int nso = 0; nso < 4096; nso += NS){
        hipLaunchKernelGGL(k_tconv, dim3(NS/64,64), dim3(256), 0, stream, Wk + nso, Wt, 4096, 4096);
        hipLaunchKernelGGL(gemm256<1>, dim3(NS/256,G), dim3(512), 0, stream,
                           sp, Wt, bk + nso, bk + nso, (void*)(Kb + nso), (void*)(Kb + nso), 4096, 4096,4096,4096);
      }
      for (int nso = 0; nso < 4096; nso += NS){
        hipLaunchKernelGGL(k_tconv, dim3(NS/64,64), dim3(256), 0, stream, Wv + nso, Wt, 4096, 4096);
        hipLaunchKernelGGL(gemm256<3>, dim3(NS/256,G), dim3(512), 0, stream,
                           sp, Wt, bv + nso, bv + nso, (void*)(Vt + (size_t)nso*256), (void*)(Vt + (size_t)nso*256), 4096, 4096,4096,256);
      }
    }
    // S = scale * Q K^T (z = b_local*4 + h) ; softmax ; intf = P V (fp32)
    hipLaunchKernelGGL(gemm_bt<2>, dim3(2,2,G*4), dim3(256), 0, stream,
                       Q, Kb, (const float*)nullptr, (void*)S, 1024, 4096,4096,256,
                       1048576L,1024L, 1048576L,1024L, 262144L,65536L, scale);
    hipLaunchKernelGGL(k_softmax, dim3(G*256), dim3(256), 0, stream, S, P);
    hipLaunchKernelGGL(gemm_bt<2>, dim3(8,2,G*4), dim3(256), 0, stream,
                       P, Vt, (const float*)nullptr, (void*)intf, 256, 256,256,4096,
                       262144L,65536L, 1048576L,262144L, 1048576L,1024L, 1.f);
    hipLaunchKernelGGL(k_stats, dim3(G,16), dim3(256), 0, stream,
                       h_g, intf, sp, g_pfs, b_pfs, g_sfs, b_sfs, part_p, part_s, g0);
  }

  hipLaunchKernelGGL(k_reduce, dim3(1152), dim3(256), 0, stream, part_p, part_s, xbar, ybar);
  hipLaunchKernelGGL(k_proj_part, dim3(16,10,2), dim3(256), 0, stream,
                     xbar, ybar, Wpfs, Wsfs, pbuf);
  hipLaunchKernelGGL(k_projred, dim3(256), dim3(256), 0, stream,
                     pbuf, bpfs, bsfs, tpre, spre);
  hipLaunchKernelGGL(k_lnrow, dim3(64), dim3(256), 0, stream, tpre, spre, out);
  hipLaunchKernelGGL(k_head, dim3(32), dim3(256), 0, stream,
                     Wpc, bpc, Wc0, bc0, Wc1, bc1, Wc2, bc2, out);
}

// Round 11
// 1307.036 us; speedup vs baseline: 1.3651x; 1.0085x over previous
//
#include <hip/hip_runtime.h>
#include <hip/hip_bf16.h>

typedef __bf16 bf16x8 __attribute__((ext_vector_type(8)));
typedef float f32x4 __attribute__((ext_vector_type(4)));
typedef unsigned long long u64;

#define EPSV 1e-5f

__device__ __forceinline__ float bf2f(unsigned short u){
  unsigned int x = ((unsigned int)u) << 16;
  return __builtin_bit_cast(float, x);
}
__device__ __forceinline__ unsigned short f2bf(float f){
  __bf16 b = (__bf16)f;
  return __builtin_bit_cast(unsigned short, b);
}
__device__ __forceinline__ float gelu_exact(float x){
  return 0.5f * x * (1.0f + erff(x * 0.7071067811865476f));
}
__device__ __forceinline__ void gload_lds16(const void* g, void* l){
  __builtin_amdgcn_global_load_lds((const __attribute__((address_space(1))) unsigned int*)g,
                                   (__attribute__((address_space(3))) unsigned int*)l, 16, 0, 0);
}

// ---------------------------------------------------------------------------
// 256x256 (BK=64) 8-wave 4-phase bf16 MFMA GEMM — SINGLE barrier per phase
// (R9 schedule, best measured: 113us / 1207 TF, MfmaUtil 52%). FROZEN.
// MODE 0: bias+GELU dual @4096; 1: bias; 3: V^T; 4: dual K/V^T @4096.
// ---------------------------------------------------------------------------
template<int MODE>
__global__ __launch_bounds__(512, 2)
void gemm256(const unsigned short* __restrict__ A, const unsigned short* __restrict__ B,
             const float* __restrict__ bias0, const float* __restrict__ bias1,
             void* __restrict__ C0v, void* __restrict__ C1v,
             int Kd, int lda, int ldb, int ldc)
{
  __shared__ char smem[131072];
  const int t = threadIdx.x;
  const int w = t >> 6, l = t & 63;
  const int wm = w >> 2, wn = w & 3;
  const int lr = l & 15, lg = l >> 4;
  const int nbx = gridDim.x;
  const int nwg = nbx * gridDim.y;
  int bid = blockIdx.y*nbx + blockIdx.x;
  if ((nwg & 7) == 0) bid = (bid & 7)*(nwg >> 3) + (bid >> 3);
  const int bm0 = (bid / nbx) * 256, bn0 = (bid % nbx) * 256;
  const int nk = Kd >> 6;

  const int srow = t >> 3;
  const int sslot = t & 7;

  f32x4 acc[8][4];
  #pragma unroll
  for (int i=0;i<8;++i){
    #pragma unroll
    for (int j=0;j<4;++j){ f32x4 zz = {0.f,0.f,0.f,0.f}; acc[i][j] = zz; }
  }
  bf16x8 a0[4][2], a1[4][2], b0[2][2], b1[2][2];

  auto stage = [&](int kt, int mat, int hf, int q){
    if (kt >= nk) return;
    const int r_h = q*64 + srow;
    const int s_ = sslot ^ ((r_h >> 1) & 7);
    const unsigned short* gp = (mat ? B + (size_t)(bn0 + hf*128 + r_h)*ldb
                                    : A + (size_t)(bm0 + hf*128 + r_h)*lda)
                               + (kt << 6) + s_*8;
    char* lp = smem + mat*65536 + (kt&1)*32768 + hf*16384 + q*8192 + t*16;
    gload_lds16((const void*)gp, (void*)lp);
  };
  auto rdA = [&](int d, int fm, int kk)->bf16x8{
    const int r = fm*16 + lr;
    const int s_ = (kk*4 + lg) ^ ((r >> 1) & 7);
    return *(const bf16x8*)(smem + d*32768 + wm*16384 + r*128 + s_*16);
  };
  auto rdB = [&](int d, int fn, int kk)->bf16x8{
    const int r = (wn&1)*64 + fn*16 + lr;
    const int s_ = (kk*4 + lg) ^ ((r >> 1) & 7);
    return *(const bf16x8*)(smem + 65536 + d*32768 + (wn>>1)*16384 + r*128 + s_*16);
  };

  auto ktile = [&](int kt, int d){
    // ---- phase 1: stage A-q1(kt+1); rd a0(8)+b0(4); MFMA S1(a0,b0) ----
    stage(kt+1, 0, 0, 1); stage(kt+1, 0, 1, 1);
    #pragma unroll
    for (int fm=0; fm<4; ++fm){ a0[fm][0] = rdA(d, fm, 0); a0[fm][1] = rdA(d, fm, 1); }
    #pragma unroll
    for (int fn=0; fn<2; ++fn){ b0[fn][0] = rdB(d, fn, 0); b0[fn][1] = rdB(d, fn, 1); }
    __builtin_amdgcn_s_barrier();
    __builtin_amdgcn_s_setprio(1);
    #pragma unroll
    for (int fm=0; fm<4; ++fm)
      #pragma unroll
      for (int fn=0; fn<2; ++fn)
        #pragma unroll
        for (int kk=0; kk<2; ++kk)
          acc[fm][fn] = __builtin_amdgcn_mfma_f32_16x16x32_bf16(a0[fm][kk], b0[fn][kk], acc[fm][fn], 0,0,0);
    __builtin_amdgcn_s_setprio(0);
    // ---- phase 2: rd b1(4); MFMA S2(a0,b1) ----
    #pragma unroll
    for (int fn=0; fn<2; ++fn){ b1[fn][0] = rdB(d, fn+2, 0); b1[fn][1] = rdB(d, fn+2, 1); }
    __builtin_amdgcn_s_barrier();
    __builtin_amdgcn_s_setprio(1);
    #pragma unroll
    for (int fm=0; fm<4; ++fm)
      #pragma unroll
      for (int fn=0; fn<2; ++fn)
        #pragma unroll
        for (int kk=0; kk<2; ++kk)
          acc[fm][fn+2] = __builtin_amdgcn_mfma_f32_16x16x32_bf16(a0[fm][kk], b1[fn][kk], acc[fm][fn+2], 0,0,0);
    __builtin_amdgcn_s_setprio(0);
    // ---- phase 3: stage A-q0+B-q0(kt+2); rd a1(8); MFMA S3(a1,b1) ----
    stage(kt+2, 0, 0, 0); stage(kt+2, 0, 1, 0);
    stage(kt+2, 1, 0, 0); stage(kt+2, 1, 1, 0);
    #pragma unroll
    for (int fm=0; fm<4; ++fm){ a1[fm][0] = rdA(d, fm+4, 0); a1[fm][1] = rdA(d, fm+4, 1); }
    __builtin_amdgcn_s_barrier();
    __builtin_amdgcn_s_setprio(1);
    #pragma unroll
    for (int fm=0; fm<4; ++fm)
      #pragma unroll
      for (int fn=0; fn<2; ++fn)
        #pragma unroll
        for (int kk=0; kk<2; ++kk)
          acc[fm+4][fn+2] = __builtin_amdgcn_mfma_f32_16x16x32_bf16(a1[fm][kk], b1[fn][kk], acc[fm+4][fn+2], 0,0,0);
    __builtin_amdgcn_s_setprio(0);
    // ---- phase 4: stage B-q1(kt+2); MFMA S4(a1,b0); vmcnt gate ----
    stage(kt+2, 1, 0, 1); stage(kt+2, 1, 1, 1);
    __builtin_amdgcn_s_barrier();
    __builtin_amdgcn_s_setprio(1);
    #pragma unroll
    for (int fm=0; fm<4; ++fm)
      #pragma unroll
      for (int fn=0; fn<2; ++fn)
        #pragma unroll
        for (int kk=0; kk<2; ++kk)
          acc[fm+4][fn] = __builtin_amdgcn_mfma_f32_16x16x32_bf16(a1[fm][kk], b0[fn][kk], acc[fm+4][fn], 0,0,0);
    __builtin_amdgcn_s_setprio(0);
    if (kt + 2 < nk) { asm volatile("s_waitcnt vmcnt(6)" ::: "memory"); }
    else             { asm volatile("s_waitcnt vmcnt(0)" ::: "memory"); }
  };

  // prologue
  stage(0,0,0,0); stage(0,0,1,0); stage(0,0,0,1); stage(0,0,1,1);
  stage(0,1,0,0); stage(0,1,1,0); stage(0,1,0,1); stage(0,1,1,1);
  stage(1,0,0,0); stage(1,0,1,0);
  stage(1,1,0,0); stage(1,1,1,0);
  stage(1,1,0,1); stage(1,1,1,1);
  asm volatile("s_waitcnt vmcnt(6)" ::: "memory");
  __builtin_amdgcn_s_barrier();

  for (int kt = 0; kt < nk; kt += 2){ ktile(kt, 0); ktile(kt+1, 1); }

  // epilogue
  #pragma unroll
  for (int fm=0; fm<8; ++fm){
    #pragma unroll
    for (int fn=0; fn<4; ++fn){
      const int row0 = bm0 + wm*128 + fm*16 + lg*4;
      const int col  = bn0 + wn*64 + fn*16 + lr;
      f32x4 v = acc[fm][fn];
      if constexpr (MODE == 3){
        unsigned short* C = (unsigned short*)C0v;
        const float bb = bias0[col];
        u64 pack = 0;
        #pragma unroll
        for (int j=0;j<4;++j) pack |= (u64)f2bf(v[j] + bb) << (16*j);
        *(u64*)(C + (size_t)col*256 + (size_t)(row0>>8)*1048576 + (row0&255)) = pack;
      } else if constexpr (MODE == 4){
        if (col < 4096){
          unsigned short* C = (unsigned short*)C0v;
          const float bb = bias0[col];
          #pragma unroll
          for (int j=0;j<4;++j) C[(size_t)(row0+j)*ldc + col] = f2bf(v[j] + bb);
        } else {
          const int c2 = col - 4096;
          unsigned short* C = (unsigned short*)C1v;
          const float bb = bias1[c2];
          u64 pack = 0;
          #pragma unroll
          for (int j=0;j<4;++j) pack |= (u64)f2bf(v[j] + bb) << (16*j);
          *(u64*)(C + (size_t)c2*256 + (size_t)(row0>>8)*1048576 + (row0&255)) = pack;
        }
      } else {
        const bool hi = (MODE == 0) && (col >= 4096);
        unsigned short* C = (unsigned short*)(hi ? C1v : C0v);
        const int c2 = hi ? (col - 4096) : col;
        const float bb = hi ? bias1[c2] : bias0[c2];
        #pragma unroll
        for (int j=0;j<4;++j){
          float x = v[j] + bb;
          if constexpr (MODE==0) x = gelu_exact(x);
          C[(size_t)(row0+j)*ldc + c2] = f2bf(x);
        }
      }
    }
  }
}

// ---------------------------------------------------------------------------
// 128x128 (BK=32) bf16 MFMA GEMM (small attention GEMMs). MODE 2: *scale->fp32.
// ---------------------------------------------------------------------------
template<int MODE>
__global__ __launch_bounds__(256)
void gemm_bt(const unsigned short* __restrict__ A, const unsigned short* __restrict__ B,
             const float* __restrict__ bias, void* __restrict__ Cv,
             int Kd, int lda, int ldb, int ldc,
             long sA2, long sA1, long sB2, long sB1, long sC2, long sC1,
             float scale)
{
  __shared__ unsigned short lds[2][2][4096];
  const int t = threadIdx.x;
  const int w = t >> 6, l = t & 63;
  const int z = blockIdx.z;
  A += (size_t)(z>>2)*sA2 + (size_t)(z&3)*sA1;
  B += (size_t)(z>>2)*sB2 + (size_t)(z&3)*sB1;
  const int bm0 = blockIdx.y * 128, bn0 = blockIdx.x * 128;
  const int nk = Kd >> 5;

  const int sr = l >> 2;
  const int ss = l & 3;

  f32x4 acc[4][4];
  #pragma unroll
  for (int i=0;i<4;++i){
    #pragma unroll
    for (int j=0;j<4;++j){ f32x4 zz = {0.f,0.f,0.f,0.f}; acc[i][j] = zz; }
  }

  const int wm = w >> 1, wn = w & 1;
  const int lr = l & 15, lg = l >> 4;

  auto stage = [&](int kt, int bb){
    const int k0 = kt << 5;
    #pragma unroll
    for (int i=0;i<2;++i){
      const int r  = w*32 + i*16 + sr;
      const int sa = ss ^ ((r>>1)&3);
      const unsigned short* ga = A + (size_t)(bm0 + r)*lda + (k0 + sa*8);
      gload_lds16((const void*)ga, (void*)((char*)&lds[bb][0][0] + w*2048 + i*1024));
      const unsigned short* gb = B + (size_t)(bn0 + r)*ldb + (k0 + sa*8);
      gload_lds16((const void*)gb, (void*)((char*)&lds[bb][1][0] + w*2048 + i*1024));
    }
  };

  int buf = 0;
  stage(0, 0);
  for (int kt=0; kt<nk; ++kt){
    __syncthreads();
    if (kt+1 < nk) stage(kt+1, buf^1);
    bf16x8 av[4], bv[4];
    #pragma unroll
    for (int fm=0; fm<4; ++fm){
      const int row = wm*64 + fm*16 + lr;
      const int sl  = lg ^ ((row>>1)&3);
      av[fm] = *(const bf16x8*)((const char*)&lds[buf][0][0] + row*64 + sl*16);
    }
    #pragma unroll
    for (int fn=0; fn<4; ++fn){
      const int col = wn*64 + fn*16 + lr;
      const int sl  = lg ^ ((col>>1)&3);
      bv[fn] = *(const bf16x8*)((const char*)&lds[buf][1][0] + col*64 + sl*16);
    }
    #pragma unroll
    for (int fm=0; fm<4; ++fm){
      #pragma unroll
      for (int fn=0; fn<4; ++fn)
        acc[fm][fn] = __builtin_amdgcn_mfma_f32_16x16x32_bf16(av[fm], bv[fn], acc[fm][fn], 0,0,0);
    }
    buf ^= 1;
  }

  const size_t coff = (size_t)(z>>2)*sC2 + (size_t)(z&3)*sC1;
  #pragma unroll
  for (int fm=0; fm<4; ++fm){
    #pragma unroll
    for (int fn=0; fn<4; ++fn){
      const int row0 = bm0 + wm*64 + fm*16 + lg*4;
      const int col  = bn0 + wn*64 + fn*16 + lr;
      f32x4 v = acc[fm][fn];
      if constexpr (MODE == 2){
        float* C = (float*)Cv + coff;
        #pragma unroll
        for (int j=0;j<4;++j) C[(size_t)(row0+j)*ldc + col] = v[j]*scale;
      }
    }
  }
}

// ---------------------------------------------------------------------------
__global__ __launch_bounds__(256)
void k_convh(const float* __restrict__ in, unsigned short* __restrict__ out){
  const size_t id = (size_t)blockIdx.x*256 + threadIdx.x;
  float4 v = ((const float4*)in)[id];
  u64 pack = (u64)f2bf(v.x) | ((u64)f2bf(v.y)<<16) | ((u64)f2bf(v.z)<<32) | ((u64)f2bf(v.w)<<48);
  *(u64*)(out + id*4) = pack;
}

__global__ __launch_bounds__(256)
void k_tconv(const float* __restrict__ W, unsigned short* __restrict__ Wt, int Kd, int N){
  __shared__ float lt[64][65];
  const int t = threadIdx.x;
  const int n0 = blockIdx.x*64, k0 = blockIdx.y*64;
  #pragma unroll
  for (int i=0;i<16;++i){
    int lin = i*256 + t; int r = lin>>6, c = lin&63;
    lt[r][c] = W[(size_t)(k0+r)*N + n0 + c];
  }
  __syncthreads();
  #pragma unroll
  for (int i=0;i<16;++i){
    int lin = i*256 + t; int n = lin>>6, k = lin&63;
    Wt[(size_t)(n0+n)*Kd + k0 + k] = f2bf(lt[k][n]);
  }
}

__global__ __launch_bounds__(256)
void k_softmax(const float* __restrict__ S, unsigned short* __restrict__ P){
  const int t = threadIdx.x, w = t>>6, l = t&63;
  const size_t row = (size_t)blockIdx.x*4 + w;
  float4 v = *(const float4*)(S + row*256 + l*4);
  float m = fmaxf(fmaxf(v.x,v.y), fmaxf(v.z,v.w));
  #pragma unroll
  for (int off=32; off; off>>=1) m = fmaxf(m, __shfl_xor(m, off));
  float e0 = expf(v.x-m), e1 = expf(v.y-m), e2 = expf(v.z-m), e3 = expf(v.w-m);
  float s = e0+e1+e2+e3;
  #pragma unroll
  for (int off=32; off; off>>=1) s += __shfl_xor(s, off);
  const float inv = 1.0f/s;
  u64 pack = (u64)f2bf(e0*inv) | ((u64)f2bf(e1*inv)<<16) | ((u64)f2bf(e2*inv)<<32) | ((u64)f2bf(e3*inv)<<48);
  *(u64*)(P + row*256 + l*4) = pack;
}

__device__ __forceinline__ void blkred2(float& a, float& b, float* sred, int t){
  #pragma unroll
  for (int off=32; off; off>>=1){ a += __shfl_xor(a, off); b += __shfl_xor(b, off); }
  __syncthreads();
  if ((t&63)==0){ sred[(t>>6)*2] = a; sred[(t>>6)*2+1] = b; }
  __syncthreads();
  a = sred[0]+sred[2]+sred[4]+sred[6];
  b = sred[1]+sred[3]+sred[5]+sred[7];
}

__device__ __forceinline__ void blkred4(float& a, float& b, float& c, float& d,
                                        float* sred, int t){
  #pragma unroll
  for (int off=32; off; off>>=1){
    a += __shfl_xor(a, off); b += __shfl_xor(b, off);
    c += __shfl_xor(c, off); d += __shfl_xor(d, off);
  }
  __syncthreads();
  if ((t&63)==0){
    sred[(t>>6)*4]   = a; sred[(t>>6)*4+1] = b;
    sred[(t>>6)*4+2] = c; sred[(t>>6)*4+3] = d;
  }
  __syncthreads();
  a = sred[0]+sred[4]+sred[8]+sred[12];
  b = sred[1]+sred[5]+sred[9]+sred[13];
  c = sred[2]+sred[6]+sred[10]+sred[14];
  d = sred[3]+sred[7]+sred[11]+sred[15];
}

// 16 row-groups per batch; sp-LN stats folded into the first reduction
// (blkred4) -> 4 barriers/row instead of 6.
__global__ __launch_bounds__(256)
void k_stats(const float* __restrict__ h, const float* __restrict__ intf,
             const unsigned short* __restrict__ sp,
             const float* __restrict__ g_pfs, const float* __restrict__ b_pfs,
             const float* __restrict__ g_sfs, const float* __restrict__ b_sfs,
             float* __restrict__ part_p, float* __restrict__ part_s, int g0)
{
  __shared__ float sred[16];
  const int bl = blockIdx.x, grp = blockIdx.y, t = threadIdx.x;
  float zacc[20], wacc[16];
  #pragma unroll
  for (int j=0;j<20;++j) zacc[j]=0.f;
  #pragma unroll
  for (int j=0;j<16;++j) wacc[j]=0.f;
  for (int rr=0; rr<16; ++rr){
    const size_t r = (size_t)bl*256 + grp*16 + rr;
    float hv[4], iv[16], sv[16];
    #pragma unroll
    for (int j=0;j<4;++j) hv[j] = h[r*1024 + j*256 + t];
    float s1=0.f, s2=0.f;
    #pragma unroll
    for (int j=0;j<16;++j){ float x = intf[r*4096 + j*256 + t]; iv[j]=x; s1+=x; s2+=x*x; }
    float u1=0.f, u2=0.f;
    #pragma unroll
    for (int j=0;j<16;++j){ float x = bf2f(sp[r*4096 + j*256 + t]); sv[j]=x; u1+=x; u2+=x*x; }
    blkred4(s1,s2,u1,u2,sred,t);
    const float m1 = s1*(1.f/4096.f);
    const float rs1 = rsqrtf(fmaxf(s2*(1.f/4096.f) - m1*m1, 0.f) + EPSV);
    const float m3 = u1*(1.f/4096.f);
    const float rs3 = rsqrtf(fmaxf(u2*(1.f/4096.f) - m3*m3, 0.f) + EPSV);
    #pragma unroll
    for (int j=0;j<16;++j){ int idx = j*256+t; wacc[j] += ((sv[j]-m3)*rs3)*g_sfs[idx] + b_sfs[idx]; }
    float t1=0.f, t2=0.f;
    #pragma unroll
    for (int j=0;j<4;++j){ t1 += hv[j]; t2 += hv[j]*hv[j]; }
    #pragma unroll
    for (int j=0;j<16;++j){ float y = (iv[j]-m1)*rs1; iv[j]=y; t1+=y; t2+=y*y; }
    blkred2(t1,t2,sred,t);
    const float m2 = t1*(1.f/5120.f);
    const float rs2 = rsqrtf(fmaxf(t2*(1.f/5120.f) - m2*m2, 0.f) + EPSV);
    #pragma unroll
    for (int j=0;j<4;++j){ int idx = j*256+t; zacc[j] += ((hv[j]-m2)*rs2)*g_pfs[idx] + b_pfs[idx]; }
    #pragma unroll
    for (int j=0;j<16;++j){ int idx = 1024 + j*256+t; zacc[4+j] += ((iv[j]-m2)*rs2)*g_pfs[idx] + b_pfs[idx]; }
  }
  const size_t pb = (size_t)(g0 + bl)*16 + grp;
  #pragma unroll
  for (int j=0;j<20;++j) part_p[pb*5120 + j*256 + t] = zacc[j];
  #pragma unroll
  for (int j=0;j<16;++j) part_s[pb*4096 + j*256 + t] = wacc[j];
}

__global__ __launch_bounds__(256)
void k_reduce(const float* __restrict__ part_p, const float* __restrict__ part_s,
              float* __restrict__ xbar, float* __restrict__ ybar){
  int id = blockIdx.x*256 + threadIdx.x;
  if (id < 32*5120){
    const int b = id / 5120, i = id % 5120;
    float s = 0.f;
    for (int g=0; g<16; ++g) s += part_p[((size_t)b*16+g)*5120 + i];
    xbar[(size_t)b*5120 + i] = s * (1.f/256.f);
  } else {
    id -= 32*5120;
    const int b = id / 4096, i = id % 4096;
    float s = 0.f;
    for (int g=0; g<16; ++g) s += part_s[((size_t)b*16+g)*4096 + i];
    ybar[(size_t)b*4096 + i] = s * (1.f/256.f);
  }
}

__global__ __launch_bounds__(256)
void k_proj_part(const float* __restrict__ xbar, const float* __restrict__ ybar,
                 const float* __restrict__ Wpfs, const float* __restrict__ Wsfs,
                 float* __restrict__ pbuf){
  const int path = blockIdx.z;
  const int y = blockIdx.y;
  if (path == 1 && y >= 8) return;
  const int Kp = path ? 4096 : 5120;
  const float* X = path ? ybar : xbar;
  const float* W = path ? Wsfs : Wpfs;
  const int t = threadIdx.x;
  const int col = blockIdx.x*64 + (t & 63);
  const int sub = t >> 6;
  const int k0 = y*512 + sub*128;
  float acc[32];
  #pragma unroll
  for (int b=0;b<32;++b) acc[b] = 0.f;
  for (int i4=0; i4<32; ++i4){
    const int k = k0 + i4*4;
    float wv0 = W[(size_t)(k  )*1024 + col];
    float wv1 = W[(size_t)(k+1)*1024 + col];
    float wv2 = W[(size_t)(k+2)*1024 + col];
    float wv3 = W[(size_t)(k+3)*1024 + col];
    #pragma unroll
    for (int b=0;b<32;++b){
      float4 xv = *(const float4*)(X + (size_t)b*Kp + k);
      acc[b] += xv.x*wv0 + xv.y*wv1 + xv.z*wv2 + xv.w*wv3;
    }
  }
  float* dst = pbuf + ((size_t)(path*40 + y*4 + sub)*32)*1024 + col;
  #pragma unroll
  for (int b=0;b<32;++b) dst[(size_t)b*1024] = acc[b];
}

__global__ __launch_bounds__(256)
void k_projred(const float* __restrict__ pbuf,
               const float* __restrict__ bpfs, const float* __restrict__ bsfs,
               float* __restrict__ tpre, float* __restrict__ spre){
  const int id = blockIdx.x*256 + threadIdx.x;
  const int path = id >> 15;
  const int rem = id & 32767;
  const int b = rem >> 10, col = rem & 1023;
  const int ns = path ? 32 : 40;
  const float* src = pbuf + ((size_t)(path*40)*32 + b)*1024 + col;
  float s = path ? bsfs[col] : bpfs[col];
  for (int g=0; g<ns; ++g) s += src[(size_t)g*32*1024];
  (path ? spre : tpre)[(size_t)b*1024 + col] = s;
}

__global__ __launch_bounds__(256)
void k_lnrow(const float* __restrict__ tpre, const float* __restrict__ spre,
             float* __restrict__ out){
  __shared__ float sred[16];
  const int id = blockIdx.x, t = threadIdx.x;
  const int path = id >> 5, b = id & 31;
  const float* src = (path ? spre : tpre) + (size_t)b*1024;
  float v[4]; float s1=0.f, s2=0.f;
  #pragma unroll
  for (int j=0;j<4;++j){ v[j] = src[j*256+t]; s1 += v[j]; s2 += v[j]*v[j]; }
  blkred2(s1,s2,sred,t);
  const float m = s1*(1.f/1024.f);
  const float rs = rsqrtf(fmaxf(s2*(1.f/1024.f)-m*m,0.f)+EPSV);
  float* dst = out + (path ? 35072 : 2304) + (size_t)b*1024;
  #pragma unroll
  for (int j=0;j<4;++j) dst[j*256+t] = (v[j]-m)*rs;
}

__global__ __launch_bounds__(256)
void k_head(const float* __restrict__ Wpc, const float* __restrict__ bpc,
            const float* __restrict__ Wc0, const float* __restrict__ bc0,
            const float* __restrict__ Wc1, const float* __restrict__ bc1,
            const float* __restrict__ Wc2, const float* __restrict__ bc2,
            float* __restrict__ out){
  __shared__ float slog[16];
  __shared__ int sy;
  const int b = blockIdx.x, t = threadIdx.x, w = t>>6, l = t&63;
  const float* pv = out + 2304 + (size_t)b*1024;
  const float* sv = out + 35072 + (size_t)b*1024;
  #pragma unroll
  for (int jj=0; jj<4; ++jj){
    const int j = w*4 + jj;
    float a = 0.f;
    for (int i=l; i<1024; i+=64) a += pv[i]*Wpc[(size_t)i*16 + j];
    #pragma unroll
    for (int off=32; off; off>>=1) a += __shfl_xor(a, off);
    if (l==0){ const float lgv = a + bpc[j]; slog[j] = lgv; out[b*16 + j] = lgv; }
  }
  __syncthreads();
  if (t==0){
    int best=0; float bvv = slog[0];
    for (int i=1;i<16;++i) if (slog[i] > bvv){ bvv = slog[i]; best = i; }
    sy = best;
  }
  __syncthreads();
  const int y = sy;
  const float* Ws[3] = {Wc0, Wc1, Wc2};
  const float* bs[3] = {bc0, bc1, bc2};
  const int nouts[3] = {8,16,32};
  const int ooff[3]  = {512, 768, 1280};
  for (int hI=0; hI<3; ++hI){
    const int no = nouts[hI];
    for (int n = w; n < no; n += 4){
      const float* wr = Ws[hI] + ((size_t)y*no + n)*1024;
      float a = 0.f;
      for (int i=l; i<1024; i+=64) a += sv[i]*wr[i];
      #pragma unroll
      for (int off=32; off; off>>=1) a += __shfl_xor(a, off);
      if (l==0) out[ooff[hI] + b*no + n] = a + bs[hI][(size_t)y*no + n];
    }
  }
}

// ---------------------------------------------------------------------------
extern "C" void kernel_launch(void* const* d_in, const int* in_sizes, int n_in,
                              void* d_out, int out_size, void* d_ws, size_t ws_size,
                              hipStream_t stream)
{
  const float* h    = (const float*)d_in[0];
  const float* Wpp  = (const float*)d_in[1];
  const float* bpp  = (const float*)d_in[2];
  const float* Wsp  = (const float*)d_in[3];
  const float* bsp  = (const float*)d_in[4];
  const float* Wq   = (const float*)d_in[5];
  const float* bq   = (const float*)d_in[6];
  const float* Wk   = (const float*)d_in[7];
  const float* bk   = (const float*)d_in[8];
  const float* Wv   = (const float*)d_in[9];
  const float* bv   = (const float*)d_in[10];
  const float* g_pfs= (const float*)d_in[11];
  const float* b_pfs= (const float*)d_in[12];
  const float* Wpfs = (const float*)d_in[13];
  const float* bpfs = (const float*)d_in[14];
  const float* g_sfs= (const float*)d_in[15];
  const float* b_sfs= (const float*)d_in[16];
  const float* Wsfs = (const float*)d_in[17];
  const float* bsfs = (const float*)d_in[18];
  const float* Wpc  = (const float*)d_in[19];
  const float* bpc  = (const float*)d_in[20];
  const float* Wc0  = (const float*)d_in[21];
  const float* bc0  = (const float*)d_in[22];
  const float* Wc1  = (const float*)d_in[23];
  const float* bc1  = (const float*)d_in[24];
  const float* Wc2  = (const float*)d_in[25];
  const float* bc2  = (const float*)d_in[26];
  float* out = (float*)d_out;
  char* ws = (char*)d_ws;
  (void)in_sizes; (void)n_in; (void)out_size;

  // ---- plan selection (unchanged from R10) ----
  struct PlanT { int G, NS, hoist; };
  const PlanT plans[7] = {{16,4096,1},{16,4096,0},{8,4096,0},{4,4096,0},{2,4096,0},{1,4096,0},{1,1024,0}};
  int G = 0, NS = 0, HOIST = 0;
  size_t oWt=0,oWps=0,oWq=0,oWk2=0,oWv2=0,oSP=0;
  size_t oPp=0,oPs=0,oXb=0,oYb=0,oTp=0,oSp=0,oPbf=0,oHb=0,oPb=0,oSb=0,oQ=0,oK=0,oVt=0;
  for (int pi = 0; pi < 7; ++pi){
    const size_t g = plans[pi].G, ns = plans[pi].NS;
    const int hoist = plans[pi].hoist;
    size_t off = 0;
    auto alloc = [&](size_t bytes){ size_t o = off; off += (bytes + 255) & ~255ULL; return o; };
    size_t wt=0, wps=0, wq=0, wk2=0, wv2=0, sp2=0, pbf=0, hb=0, pb=0;
    size_t pp_, ps_, xb, yb, tp, sp_, sb, q, k, vt;
    if (hoist){
      wps = alloc(8192ULL*1024*2);
      wq  = alloc(4096ULL*4096*2);
      wk2 = alloc(4096ULL*4096*2);
      wv2 = alloc(4096ULL*4096*2);
      pp_ = alloc(32ULL*16*5120*4);
      ps_ = alloc(32ULL*16*4096*4);
      xb = alloc(32*5120*4); yb = alloc(32*4096*4);
      tp = alloc(32*1024*4); sp_ = alloc(32*1024*4);
      sb = alloc(g*2097152);
      q  = alloc(g*2097152);
      k  = alloc(g*2097152);
      vt = alloc(g*2097152);
      sp2 = alloc(g*1572864);
      pbf = q; hb = vt; pb = k;
    } else {
      wt = alloc(ns*4096*2);
      pp_ = alloc(32ULL*16*5120*4);
      ps_ = alloc(32ULL*16*4096*4);
      xb = alloc(32*5120*4); yb = alloc(32*4096*4);
      tp = alloc(32*1024*4); sp_ = alloc(32*1024*4);
      pbf = alloc(2*40*32*1024*4);
      hb = alloc(g*524288);
      pb = alloc(g*2097152);
      sb = alloc(g*2097152);
      q  = alloc(g*2097152);
      k  = alloc(g*2097152);
      vt = alloc(g*2097152);
      sp2 = pb;
    }
    if (off <= ws_size){
      G = (int)g; NS = (int)ns; HOIST = hoist;
      oWt=wt; oWps=wps; oWq=wq; oWk2=wk2; oWv2=wv2; oSP=sp2;
      oPp=pp_; oPs=ps_; oXb=xb; oYb=yb; oTp=tp; oSp=sp_; oPbf=pbf;
      oHb=hb; oPb=pb; oSb=sb; oQ=q; oK=k; oVt=vt;
      break;
    }
  }
  if (!G) return;

  unsigned short* Wt   = (unsigned short*)(ws + oWt);
  unsigned short* WpsT = (unsigned short*)(ws + oWps);
  unsigned short* WqT  = (unsigned short*)(ws + oWq);
  unsigned short* WkT  = (unsigned short*)(ws + oWk2);
  unsigned short* WvT  = (unsigned short*)(ws + oWv2);
  float* part_p = (float*)(ws + oPp);
  float* part_s = (float*)(ws + oPs);
  float* xbar   = (float*)(ws + oXb);
  float* ybar   = (float*)(ws + oYb);
  float* tpre   = (float*)(ws + oTp);
  float* spre   = (float*)(ws + oSp);
  float* pbuf   = (float*)(ws + oPbf);
  unsigned short* h_bf = (unsigned short*)(ws + oHb);
  unsigned short* pp   = (unsigned short*)(ws + oPb);
  unsigned short* sp   = (unsigned short*)(ws + oSb);
  unsigned short* Q    = (unsigned short*)(ws + oQ);
  unsigned short* Kb   = (unsigned short*)(ws + oK);
  unsigned short* Vt   = (unsigned short*)(ws + oVt);
  float*          S    = (float*)(ws + oSP);
  unsigned short* P    = (unsigned short*)(ws + oSP + (size_t)G*1048576);
  float*          intf = (float*)(ws + oQ);

  const float scale = 1.0f/32.0f;
  (void)oK;

  if (HOIST){
    hipLaunchKernelGGL(k_tconv, dim3(64,16), dim3(256), 0, stream, Wpp, WpsT, 1024, 4096);
    hipLaunchKernelGGL(k_tconv, dim3(64,16), dim3(256), 0, stream, Wsp, WpsT + 4096ULL*1024, 1024, 4096);
    hipLaunchKernelGGL(k_tconv, dim3(64,64), dim3(256), 0, stream, Wq, WqT, 4096, 4096);
    hipLaunchKernelGGL(k_tconv, dim3(64,64), dim3(256), 0, stream, Wk, WkT, 4096, 4096);
    hipLaunchKernelGGL(k_tconv, dim3(64,64), dim3(256), 0, stream, Wv, WvT, 4096, 4096);
  }

  for (int g0 = 0; g0 < 32; g0 += G){
    const float* h_g = h + (size_t)g0*262144;

    hipLaunchKernelGGL(k_convh, dim3(G*256), dim3(256), 0, stream, h_g, h_bf);

    if (HOIST){
      // pp,sp = gelu(h @ [Wpp;Wsp]) in ONE dual-output dispatch (N=8192)
      hipLaunchKernelGGL(gemm256<0>, dim3(32,G), dim3(512), 0, stream,
                         h_bf, WpsT, bpp, bsp, (void*)pp, (void*)sp, 1024, 1024,1024,4096);
      hipLaunchKernelGGL(gemm256<1>, dim3(16,G), dim3(512), 0, stream,
                         pp, WqT, bq, bq, (void*)Q, (void*)Q, 4096, 4096,4096,4096);
      hipLaunchKernelGGL(gemm256<1>, dim3(16,G), dim3(512), 0, stream,
                         sp, WkT, bk, bk, (void*)Kb, (void*)Kb, 4096, 4096,4096,4096);
      hipLaunchKernelGGL(gemm256<3>, dim3(16,G), dim3(512), 0, stream,
                         sp, WvT, bv, bv, (void*)Vt, (void*)Vt, 4096, 4096,4096,256);
    } else {
      hipLaunchKernelGGL(k_tconv, dim3(64,16), dim3(256), 0, stream, Wpp, Wt, 1024, 4096);
      hipLaunchKernelGGL(gemm256<0>, dim3(16,G), dim3(512), 0, stream,
                         h_bf, Wt, bpp, bpp, (void*)pp, (void*)pp, 1024, 1024,1024,4096);
      for (int nso = 0; nso < 4096; nso += NS){
        hipLaunchKernelGGL(k_tconv, dim3(NS/64,64), dim3(256), 0, stream, Wq + nso, Wt, 4096, 4096);
        hipLaunchKernelGGL(gemm256<1>, dim3(NS/256,G), dim3(512), 0, stream,
                           pp, Wt, bq + nso, bq + nso, (void*)(Q + nso), (void*)(Q + nso), 4096, 4096,4096,4096);
      }
      hipLaunchKernelGGL(k_tconv, dim3(64,16), dim3(256), 0, stream, Wsp, Wt, 1024, 4096);
      hipLaunchKernelGGL(gemm256<0>, dim3(16,G), dim3(512), 0, stream,
                         h_bf, Wt, bsp, bsp, (void*)sp, (void*)sp, 1024, 1024,1024,4096);
      for (int nso = 0; nso < 4096; nso += NS){
        hipLaunchKernelGGL(k_tconv, dim3(NS/64,64), dim3(256), 0, stream, Wk + nso, Wt, 4096, 4096);
        hipLaunchKernelGGL(gemm256<1>, dim3(NS/256,G), dim3(512), 0, stream,
                           sp, Wt, bk + nso, bk + nso, (void*)(Kb + nso), (void*)(Kb + nso), 4096, 4096,4096,4096);
      }
      for (int nso = 0; nso < 4096; nso += NS){
        hipLaunchKernelGGL(k_tconv, dim3(NS/64,64), dim3(256), 0, stream, Wv + nso, Wt, 4096, 4096);
        hipLaunchKernelGGL(gemm256<3>, dim3(NS/256,G), dim3(512), 0, stream,
                           sp, Wt, bv + nso, bv + nso, (void*)(Vt + (size_t)nso*256), (void*)(Vt + (size_t)nso*256), 4096, 4096,4096,256);
      }
    }
    // S = scale * Q K^T (z = b_local*4 + h) ; softmax ; intf = P V (fp32)
    hipLaunchKernelGGL(gemm_bt<2>, dim3(2,2,G*4), dim3(256), 0, stream,
                       Q, Kb, (const float*)nullptr, (void*)S, 1024, 4096,4096,256,
                       1048576L,1024L, 1048576L,1024L, 262144L,65536L, scale);
    hipLaunchKernelGGL(k_softmax, dim3(G*256), dim3(256), 0, stream, S, P);
    hipLaunchKernelGGL(gemm_bt<2>, dim3(8,2,G*4), dim3(256), 0, stream,
                       P, Vt, (const float*)nullptr, (void*)intf, 256, 256,256,4096,
                       262144L,65536L, 1048576L,262144L, 1048576L,1024L, 1.f);
    hipLaunchKernelGGL(k_stats, dim3(G,16), dim3(256), 0, stream,
                       h_g, intf, sp, g_pfs, b_pfs, g_sfs, b_sfs, part_p, part_s, g0);
  }

  hipLaunchKernelGGL(k_reduce, dim3(1152), dim3(256), 0, stream, part_p, part_s, xbar, ybar);
  hipLaunchKernelGGL(k_proj_part, dim3(16,10,2), dim3(256), 0, stream,
                     xbar, ybar, Wpfs, Wsfs, pbuf);
  hipLaunchKernelGGL(k_projred, dim3(256), dim3(256), 0, stream,
                     pbuf, bpfs, bsfs, tpre, spre);
  hipLaunchKernelGGL(k_lnrow, dim3(64), dim3(256), 0, stream, tpre, spre, out);
  hipLaunchKernelGGL(k_head, dim3(32), dim3(256), 0, stream,
                     Wpc, bpc, Wc0, bc0, Wc1, bc1, Wc2, bc2, out);
}

// Round 12
// 1281.326 us; speedup vs baseline: 1.3925x; 1.0201x over previous
//
#include <hip/hip_runtime.h>
#include <hip/hip_bf16.h>

typedef __bf16 bf16x8 __attribute__((ext_vector_type(8)));
typedef float f32x4 __attribute__((ext_vector_type(4)));
typedef unsigned long long u64;

#define EPSV 1e-5f

__device__ __forceinline__ float bf2f(unsigned short u){
  unsigned int x = ((unsigned int)u) << 16;
  return __builtin_bit_cast(float, x);
}
__device__ __forceinline__ unsigned short f2bf(float f){
  __bf16 b = (__bf16)f;
  return __builtin_bit_cast(unsigned short, b);
}
__device__ __forceinline__ float gelu_exact(float x){
  return 0.5f * x * (1.0f + erff(x * 0.7071067811865476f));
}
__device__ __forceinline__ void gload_lds16(const void* g, void* l){
  __builtin_amdgcn_global_load_lds((const __attribute__((address_space(1))) unsigned int*)g,
                                   (__attribute__((address_space(3))) unsigned int*)l, 16, 0, 0);
}

// ---------------------------------------------------------------------------
// Shared 256x256 (BK=64) 8-wave 4-phase K-loop (R9 schedule, frozen:
// 1207 TF, MfmaUtil 52%). Used by gemm256<MODE> and gemm_qkv.
// ---------------------------------------------------------------------------
struct GemmCore {
  char* smem; int t, w, l, wm, wn, lr, lg, bm0, bn0, nk;
  int srow, sslot;
  const unsigned short *A, *B; int lda, ldb;
  f32x4 acc[8][4];
  bf16x8 a0[4][2], a1[4][2], b0[2][2], b1[2][2];

  __device__ __forceinline__ void stage(int kt, int mat, int hf, int q){
    if (kt >= nk) return;
    const int r_h = q*64 + srow;
    const int s_ = sslot ^ ((r_h >> 1) & 7);
    const unsigned short* gp = (mat ? B + (size_t)(bn0 + hf*128 + r_h)*ldb
                                    : A + (size_t)(bm0 + hf*128 + r_h)*lda)
                               + (kt << 6) + s_*8;
    char* lp = smem + mat*65536 + (kt&1)*32768 + hf*16384 + q*8192 + t*16;
    gload_lds16((const void*)gp, (void*)lp);
  }
  __device__ __forceinline__ bf16x8 rdA(int d, int fm, int kk){
    const int r = fm*16 + lr;
    const int s_ = (kk*4 + lg) ^ ((r >> 1) & 7);
    return *(const bf16x8*)(smem + d*32768 + wm*16384 + r*128 + s_*16);
  }
  __device__ __forceinline__ bf16x8 rdB(int d, int fn, int kk){
    const int r = (wn&1)*64 + fn*16 + lr;
    const int s_ = (kk*4 + lg) ^ ((r >> 1) & 7);
    return *(const bf16x8*)(smem + 65536 + d*32768 + (wn>>1)*16384 + r*128 + s_*16);
  }
  __device__ __forceinline__ void ktile(int kt, int d){
    stage(kt+1, 0, 0, 1); stage(kt+1, 0, 1, 1);
    #pragma unroll
    for (int fm=0; fm<4; ++fm){ a0[fm][0] = rdA(d, fm, 0); a0[fm][1] = rdA(d, fm, 1); }
    #pragma unroll
    for (int fn=0; fn<2; ++fn){ b0[fn][0] = rdB(d, fn, 0); b0[fn][1] = rdB(d, fn, 1); }
    __builtin_amdgcn_s_barrier();
    __builtin_amdgcn_s_setprio(1);
    #pragma unroll
    for (int fm=0; fm<4; ++fm)
      #pragma unroll
      for (int fn=0; fn<2; ++fn)
        #pragma unroll
        for (int kk=0; kk<2; ++kk)
          acc[fm][fn] = __builtin_amdgcn_mfma_f32_16x16x32_bf16(a0[fm][kk], b0[fn][kk], acc[fm][fn], 0,0,0);
    __builtin_amdgcn_s_setprio(0);
    #pragma unroll
    for (int fn=0; fn<2; ++fn){ b1[fn][0] = rdB(d, fn+2, 0); b1[fn][1] = rdB(d, fn+2, 1); }
    __builtin_amdgcn_s_barrier();
    __builtin_amdgcn_s_setprio(1);
    #pragma unroll
    for (int fm=0; fm<4; ++fm)
      #pragma unroll
      for (int fn=0; fn<2; ++fn)
        #pragma unroll
        for (int kk=0; kk<2; ++kk)
          acc[fm][fn+2] = __builtin_amdgcn_mfma_f32_16x16x32_bf16(a0[fm][kk], b1[fn][kk], acc[fm][fn+2], 0,0,0);
    __builtin_amdgcn_s_setprio(0);
    stage(kt+2, 0, 0, 0); stage(kt+2, 0, 1, 0);
    stage(kt+2, 1, 0, 0); stage(kt+2, 1, 1, 0);
    #pragma unroll
    for (int fm=0; fm<4; ++fm){ a1[fm][0] = rdA(d, fm+4, 0); a1[fm][1] = rdA(d, fm+4, 1); }
    __builtin_amdgcn_s_barrier();
    __builtin_amdgcn_s_setprio(1);
    #pragma unroll
    for (int fm=0; fm<4; ++fm)
      #pragma unroll
      for (int fn=0; fn<2; ++fn)
        #pragma unroll
        for (int kk=0; kk<2; ++kk)
          acc[fm+4][fn+2] = __builtin_amdgcn_mfma_f32_16x16x32_bf16(a1[fm][kk], b1[fn][kk], acc[fm+4][fn+2], 0,0,0);
    __builtin_amdgcn_s_setprio(0);
    stage(kt+2, 1, 0, 1); stage(kt+2, 1, 1, 1);
    __builtin_amdgcn_s_barrier();
    __builtin_amdgcn_s_setprio(1);
    #pragma unroll
    for (int fm=0; fm<4; ++fm)
      #pragma unroll
      for (int fn=0; fn<2; ++fn)
        #pragma unroll
        for (int kk=0; kk<2; ++kk)
          acc[fm+4][fn] = __builtin_amdgcn_mfma_f32_16x16x32_bf16(a1[fm][kk], b0[fn][kk], acc[fm+4][fn], 0,0,0);
    __builtin_amdgcn_s_setprio(0);
    if (kt + 2 < nk) { asm volatile("s_waitcnt vmcnt(6)" ::: "memory"); }
    else             { asm volatile("s_waitcnt vmcnt(0)" ::: "memory"); }
  }
  __device__ __forceinline__ void run(){
    #pragma unroll
    for (int i=0;i<8;++i)
      #pragma unroll
      for (int j=0;j<4;++j){ f32x4 zz = {0.f,0.f,0.f,0.f}; acc[i][j] = zz; }
    stage(0,0,0,0); stage(0,0,1,0); stage(0,0,0,1); stage(0,0,1,1);
    stage(0,1,0,0); stage(0,1,1,0); stage(0,1,0,1); stage(0,1,1,1);
    stage(1,0,0,0); stage(1,0,1,0);
    stage(1,1,0,0); stage(1,1,1,0);
    stage(1,1,0,1); stage(1,1,1,1);
    asm volatile("s_waitcnt vmcnt(6)" ::: "memory");
    __builtin_amdgcn_s_barrier();
    for (int kt = 0; kt < nk; kt += 2){ ktile(kt, 0); ktile(kt+1, 1); }
  }
  __device__ __forceinline__ void init(char* sm, int Kd, const unsigned short* A_,
                                       const unsigned short* B_, int lda_, int ldb_,
                                       int bm0_, int bn0_){
    smem = sm; t = threadIdx.x; w = t>>6; l = t&63;
    wm = w>>2; wn = w&3; lr = l&15; lg = l>>4;
    srow = t>>3; sslot = t&7;
    A = A_; B = B_; lda = lda_; ldb = ldb_; bm0 = bm0_; bn0 = bn0_;
    nk = Kd >> 6;
  }
};

// MODE 0: bias+GELU dual @4096; 1: bias; 3: V^T
template<int MODE>
__global__ __launch_bounds__(512, 2)
void gemm256(const unsigned short* __restrict__ A, const unsigned short* __restrict__ B,
             const float* __restrict__ bias0, const float* __restrict__ bias1,
             void* __restrict__ C0v, void* __restrict__ C1v,
             int Kd, int lda, int ldb, int ldc)
{
  __shared__ char smem[131072];
  const int nbx = gridDim.x;
  const int nwg = nbx * gridDim.y;
  int bid = blockIdx.y*nbx + blockIdx.x;
  if ((nwg & 7) == 0) bid = (bid & 7)*(nwg >> 3) + (bid >> 3);
  GemmCore g;
  g.init(smem, Kd, A, B, lda, ldb, (bid / nbx) * 256, (bid % nbx) * 256);
  g.run();
  #pragma unroll
  for (int fm=0; fm<8; ++fm){
    #pragma unroll
    for (int fn=0; fn<4; ++fn){
      const int row0 = g.bm0 + g.wm*128 + fm*16 + g.lg*4;
      const int col  = g.bn0 + g.wn*64 + fn*16 + g.lr;
      f32x4 v = g.acc[fm][fn];
      if constexpr (MODE == 3){
        unsigned short* C = (unsigned short*)C0v;
        const float bb = bias0[col];
        u64 pack = 0;
        #pragma unroll
        for (int j=0;j<4;++j) pack |= (u64)f2bf(v[j] + bb) << (16*j);
        *(u64*)(C + (size_t)col*256 + (size_t)(row0>>8)*1048576 + (row0&255)) = pack;
      } else {
        const bool hi = (MODE == 0) && (col >= 4096);
        unsigned short* C = (unsigned short*)(hi ? C1v : C0v);
        const int c2 = hi ? (col - 4096) : col;
        const float bb = hi ? bias1[c2] : bias0[c2];
        #pragma unroll
        for (int j=0;j<4;++j){
          float x = v[j] + bb;
          if constexpr (MODE==0) x = gelu_exact(x);
          C[(size_t)(row0+j)*ldc + c2] = f2bf(x);
        }
      }
    }
  }
}

// Merged Q/K/V: z=0: Q=pp@WqT+bq; z=1: Kb=sp@WkT+bk; z=2: Vt=(sp@WvT+bv)^T
__global__ __launch_bounds__(512, 2)
void gemm_qkv(const unsigned short* __restrict__ App, const unsigned short* __restrict__ Asp,
              const unsigned short* __restrict__ Wqkv,
              const float* __restrict__ bq, const float* __restrict__ bk,
              const float* __restrict__ bv,
              unsigned short* __restrict__ Qo, unsigned short* __restrict__ Ko,
              unsigned short* __restrict__ Vto)
{
  __shared__ char smem[131072];
  const int z = blockIdx.z;
  const int nbx = gridDim.x;
  const int nwg = nbx * gridDim.y;
  int bid = blockIdx.y*nbx + blockIdx.x;
  if ((nwg & 7) == 0) bid = (bid & 7)*(nwg >> 3) + (bid >> 3);
  GemmCore g;
  g.init(smem, 4096, (z==0) ? App : Asp, Wqkv + (size_t)z*16777216, 4096, 4096,
         (bid / nbx) * 256, (bid % nbx) * 256);
  g.run();
  const float* bias = (z==0) ? bq : (z==1) ? bk : bv;
  #pragma unroll
  for (int fm=0; fm<8; ++fm){
    #pragma unroll
    for (int fn=0; fn<4; ++fn){
      const int row0 = g.bm0 + g.wm*128 + fm*16 + g.lg*4;
      const int col  = g.bn0 + g.wn*64 + fn*16 + g.lr;
      f32x4 v = g.acc[fm][fn];
      const float bb = bias[col];
      if (z == 2){
        u64 pack = 0;
        #pragma unroll
        for (int j=0;j<4;++j) pack |= (u64)f2bf(v[j] + bb) << (16*j);
        *(u64*)(Vto + (size_t)col*256 + (size_t)(row0>>8)*1048576 + (row0&255)) = pack;
      } else {
        unsigned short* C = (z==0) ? Qo : Ko;
        #pragma unroll
        for (int j=0;j<4;++j) C[(size_t)(row0+j)*4096 + col] = f2bf(v[j] + bb);
      }
    }
  }
}

// ---------------------------------------------------------------------------
// 128x128 (BK=32) bf16 MFMA GEMM (small attention GEMMs). MODE 2: *scale->fp32.
// ---------------------------------------------------------------------------
template<int MODE>
__global__ __launch_bounds__(256)
void gemm_bt(const unsigned short* __restrict__ A, const unsigned short* __restrict__ B,
             const float* __restrict__ bias, void* __restrict__ Cv,
             int Kd, int lda, int ldb, int ldc,
             long sA2, long sA1, long sB2, long sB1, long sC2, long sC1,
             float scale)
{
  __shared__ unsigned short lds[2][2][4096];
  const int t = threadIdx.x;
  const int w = t >> 6, l = t & 63;
  const int z = blockIdx.z;
  A += (size_t)(z>>2)*sA2 + (size_t)(z&3)*sA1;
  B += (size_t)(z>>2)*sB2 + (size_t)(z&3)*sB1;
  const int bm0 = blockIdx.y * 128, bn0 = blockIdx.x * 128;
  const int nk = Kd >> 5;

  const int sr = l >> 2;
  const int ss = l & 3;

  f32x4 acc[4][4];
  #pragma unroll
  for (int i=0;i<4;++i){
    #pragma unroll
    for (int j=0;j<4;++j){ f32x4 zz = {0.f,0.f,0.f,0.f}; acc[i][j] = zz; }
  }

  const int wm = w >> 1, wn = w & 1;
  const int lr = l & 15, lg = l >> 4;

  auto stage = [&](int kt, int bb){
    const int k0 = kt << 5;
    #pragma unroll
    for (int i=0;i<2;++i){
      const int r  = w*32 + i*16 + sr;
      const int sa = ss ^ ((r>>1)&3);
      const unsigned short* ga = A + (size_t)(bm0 + r)*lda + (k0 + sa*8);
      gload_lds16((const void*)ga, (void*)((char*)&lds[bb][0][0] + w*2048 + i*1024));
      const unsigned short* gb = B + (size_t)(bn0 + r)*ldb + (k0 + sa*8);
      gload_lds16((const void*)gb, (void*)((char*)&lds[bb][1][0] + w*2048 + i*1024));
    }
  };

  int buf = 0;
  stage(0, 0);
  for (int kt=0; kt<nk; ++kt){
    __syncthreads();
    if (kt+1 < nk) stage(kt+1, buf^1);
    bf16x8 av[4], bv[4];
    #pragma unroll
    for (int fm=0; fm<4; ++fm){
      const int row = wm*64 + fm*16 + lr;
      const int sl  = lg ^ ((row>>1)&3);
      av[fm] = *(const bf16x8*)((const char*)&lds[buf][0][0] + row*64 + sl*16);
    }
    #pragma unroll
    for (int fn=0; fn<4; ++fn){
      const int col = wn*64 + fn*16 + lr;
      const int sl  = lg ^ ((col>>1)&3);
      bv[fn] = *(const bf16x8*)((const char*)&lds[buf][1][0] + col*64 + sl*16);
    }
    #pragma unroll
    for (int fm=0; fm<4; ++fm){
      #pragma unroll
      for (int fn=0; fn<4; ++fn)
        acc[fm][fn] = __builtin_amdgcn_mfma_f32_16x16x32_bf16(av[fm], bv[fn], acc[fm][fn], 0,0,0);
    }
    buf ^= 1;
  }

  const size_t coff = (size_t)(z>>2)*sC2 + (size_t)(z&3)*sC1;
  #pragma unroll
  for (int fm=0; fm<4; ++fm){
    #pragma unroll
    for (int fn=0; fn<4; ++fn){
      const int row0 = bm0 + wm*64 + fm*16 + lg*4;
      const int col  = bn0 + wn*64 + fn*16 + lr;
      f32x4 v = acc[fm][fn];
      if constexpr (MODE == 2){
        float* C = (float*)Cv + coff;
        #pragma unroll
        for (int j=0;j<4;++j) C[(size_t)(row0+j)*ldc + col] = v[j]*scale;
      }
    }
  }
}

// ---------------------------------------------------------------------------
__global__ __launch_bounds__(256)
void k_convh(const float* __restrict__ in, unsigned short* __restrict__ out){
  const size_t id = (size_t)blockIdx.x*256 + threadIdx.x;
  float4 v = ((const float4*)in)[id];
  u64 pack = (u64)f2bf(v.x) | ((u64)f2bf(v.y)<<16) | ((u64)f2bf(v.z)<<32) | ((u64)f2bf(v.w)<<48);
  *(u64*)(out + id*4) = pack;
}

// z-batched W[K,N] fp32 -> Wt[n,K] bf16; ptrs selected per blockIdx.z
__global__ __launch_bounds__(256)
void k_tconv3(const float* __restrict__ W0, const float* __restrict__ W1,
              const float* __restrict__ W2, unsigned short* __restrict__ Wt,
              int Kd, int N, long wtStride){
  __shared__ float lt[64][65];
  const int t = threadIdx.x;
  const int zz = blockIdx.z;
  const float* W = (zz==0) ? W0 : (zz==1) ? W1 : W2;
  unsigned short* Wtz = Wt + (size_t)zz * wtStride;
  const int n0 = blockIdx.x*64, k0 = blockIdx.y*64;
  #pragma unroll
  for (int i=0;i<16;++i){
    int lin = i*256 + t; int r = lin>>6, c = lin&63;
    lt[r][c] = W[(size_t)(k0+r)*N + n0 + c];
  }
  __syncthreads();
  #pragma unroll
  for (int i=0;i<16;++i){
    int lin = i*256 + t; int n = lin>>6, k = lin&63;
    Wtz[(size_t)(n0+n)*Kd + k0 + k] = f2bf(lt[k][n]);
  }
}

__global__ __launch_bounds__(256)
void k_tconv(const float* __restrict__ W, unsigned short* __restrict__ Wt, int Kd, int N){
  __shared__ float lt[64][65];
  const int t = threadIdx.x;
  const int n0 = blockIdx.x*64, k0 = blockIdx.y*64;
  #pragma unroll
  for (int i=0;i<16;++i){
    int lin = i*256 + t; int r = lin>>6, c = lin&63;
    lt[r][c] = W[(size_t)(k0+r)*N + n0 + c];
  }
  __syncthreads();
  #pragma unroll
  for (int i=0;i<16;++i){
    int lin = i*256 + t; int n = lin>>6, k = lin&63;
    Wt[(size_t)(n0+n)*Kd + k0 + k] = f2bf(lt[k][n]);
  }
}

__global__ __launch_bounds__(256)
void k_softmax(const float* __restrict__ S, unsigned short* __restrict__ P){
  const int t = threadIdx.x, w = t>>6, l = t&63;
  const size_t row = (size_t)blockIdx.x*4 + w;
  float4 v = *(const float4*)(S + row*256 + l*4);
  float m = fmaxf(fmaxf(v.x,v.y), fmaxf(v.z,v.w));
  #pragma unroll
  for (int off=32; off; off>>=1) m = fmaxf(m, __shfl_xor(m, off));
  float e0 = expf(v.x-m), e1 = expf(v.y-m), e2 = expf(v.z-m), e3 = expf(v.w-m);
  float s = e0+e1+e2+e3;
  #pragma unroll
  for (int off=32; off; off>>=1) s += __shfl_xor(s, off);
  const float inv = 1.0f/s;
  u64 pack = (u64)f2bf(e0*inv) | ((u64)f2bf(e1*inv)<<16) | ((u64)f2bf(e2*inv)<<32) | ((u64)f2bf(e3*inv)<<48);
  *(u64*)(P + row*256 + l*4) = pack;
}

__device__ __forceinline__ void blkred2(float& a, float& b, float* sred, int t){
  #pragma unroll
  for (int off=32; off; off>>=1){ a += __shfl_xor(a, off); b += __shfl_xor(b, off); }
  __syncthreads();
  if ((t&63)==0){ sred[(t>>6)*2] = a; sred[(t>>6)*2+1] = b; }
  __syncthreads();
  a = sred[0]+sred[2]+sred[4]+sred[6];
  b = sred[1]+sred[3]+sred[5]+sred[7];
}

__device__ __forceinline__ void blkred4(float& a, float& b, float& c, float& d,
                                        float* sred, int t){
  #pragma unroll
  for (int off=32; off; off>>=1){
    a += __shfl_xor(a, off); b += __shfl_xor(b, off);
    c += __shfl_xor(c, off); d += __shfl_xor(d, off);
  }
  __syncthreads();
  if ((t&63)==0){
    sred[(t>>6)*4]   = a; sred[(t>>6)*4+1] = b;
    sred[(t>>6)*4+2] = c; sred[(t>>6)*4+3] = d;
  }
  __syncthreads();
  a = sred[0]+sred[4]+sred[8]+sred[12];
  b = sred[1]+sred[5]+sred[9]+sred[13];
  c = sred[2]+sred[6]+sred[10]+sred[14];
  d = sred[3]+sred[7]+sred[11]+sred[15];
}

__global__ __launch_bounds__(256)
void k_stats(const float* __restrict__ h, const float* __restrict__ intf,
             const unsigned short* __restrict__ sp,
             const float* __restrict__ g_pfs, const float* __restrict__ b_pfs,
             const float* __restrict__ g_sfs, const float* __restrict__ b_sfs,
             float* __restrict__ part_p, float* __restrict__ part_s, int g0)
{
  __shared__ float sred[16];
  const int bl = blockIdx.x, grp = blockIdx.y, t = threadIdx.x;
  float zacc[20], wacc[16];
  #pragma unroll
  for (int j=0;j<20;++j) zacc[j]=0.f;
  #pragma unroll
  for (int j=0;j<16;++j) wacc[j]=0.f;
  for (int rr=0; rr<16; ++rr){
    const size_t r = (size_t)bl*256 + grp*16 + rr;
    float hv[4], iv[16], sv[16];
    #pragma unroll
    for (int j=0;j<4;++j) hv[j] = h[r*1024 + j*256 + t];
    float s1=0.f, s2=0.f;
    #pragma unroll
    for (int j=0;j<16;++j){ float x = intf[r*4096 + j*256 + t]; iv[j]=x; s1+=x; s2+=x*x; }
    float u1=0.f, u2=0.f;
    #pragma unroll
    for (int j=0;j<16;++j){ float x = bf2f(sp[r*4096 + j*256 + t]); sv[j]=x; u1+=x; u2+=x*x; }
    blkred4(s1,s2,u1,u2,sred,t);
    const float m1 = s1*(1.f/4096.f);
    const float rs1 = rsqrtf(fmaxf(s2*(1.f/4096.f) - m1*m1, 0.f) + EPSV);
    const float m3 = u1*(1.f/4096.f);
    const float rs3 = rsqrtf(fmaxf(u2*(1.f/4096.f) - m3*m3, 0.f) + EPSV);
    #pragma unroll
    for (int j=0;j<16;++j){ int idx = j*256+t; wacc[j] += ((sv[j]-m3)*rs3)*g_sfs[idx] + b_sfs[idx]; }
    float t1=0.f, t2=0.f;
    #pragma unroll
    for (int j=0;j<4;++j){ t1 += hv[j]; t2 += hv[j]*hv[j]; }
    #pragma unroll
    for (int j=0;j<16;++j){ float y = (iv[j]-m1)*rs1; iv[j]=y; t1+=y; t2+=y*y; }
    blkred2(t1,t2,sred,t);
    const float m2 = t1*(1.f/5120.f);
    const float rs2 = rsqrtf(fmaxf(t2*(1.f/5120.f) - m2*m2, 0.f) + EPSV);
    #pragma unroll
    for (int j=0;j<4;++j){ int idx = j*256+t; zacc[j] += ((hv[j]-m2)*rs2)*g_pfs[idx] + b_pfs[idx]; }
    #pragma unroll
    for (int j=0;j<16;++j){ int idx = 1024 + j*256+t; zacc[4+j] += ((iv[j]-m2)*rs2)*g_pfs[idx] + b_pfs[idx]; }
  }
  const size_t pb = (size_t)(g0 + bl)*16 + grp;
  #pragma unroll
  for (int j=0;j<20;++j) part_p[pb*5120 + j*256 + t] = zacc[j];
  #pragma unroll
  for (int j=0;j<16;++j) part_s[pb*4096 + j*256 + t] = wacc[j];
}

__global__ __launch_bounds__(256)
void k_reduce(const float* __restrict__ part_p, const float* __restrict__ part_s,
              float* __restrict__ xbar, float* __restrict__ ybar){
  int id = blockIdx.x*256 + threadIdx.x;
  if (id < 32*5120){
    const int b = id / 5120, i = id % 5120;
    float s = 0.f;
    for (int g=0; g<16; ++g) s += part_p[((size_t)b*16+g)*5120 + i];
    xbar[(size_t)b*5120 + i] = s * (1.f/256.f);
  } else {
    id -= 32*5120;
    const int b = id / 4096, i = id % 4096;
    float s = 0.f;
    for (int g=0; g<16; ++g) s += part_s[((size_t)b*16+g)*4096 + i];
    ybar[(size_t)b*4096 + i] = s * (1.f/256.f);
  }
}

__global__ __launch_bounds__(256)
void k_proj_part(const float* __restrict__ xbar, const float* __restrict__ ybar,
                 const float* __restrict__ Wpfs, const float* __restrict__ Wsfs,
                 float* __restrict__ pbuf){
  const int path = blockIdx.z;
  const int y = blockIdx.y;
  if (path == 1 && y >= 8) return;
  const int Kp = path ? 4096 : 5120;
  const float* X = path ? ybar : xbar;
  const float* W = path ? Wsfs : Wpfs;
  const int t = threadIdx.x;
  const int col = blockIdx.x*64 + (t & 63);
  const int sub = t >> 6;
  const int k0 = y*512 + sub*128;
  float acc[32];
  #pragma unroll
  for (int b=0;b<32;++b) acc[b] = 0.f;
  for (int i4=0; i4<32; ++i4){
    const int k = k0 + i4*4;
    float wv0 = W[(size_t)(k  )*1024 + col];
    float wv1 = W[(size_t)(k+1)*1024 + col];
    float wv2 = W[(size_t)(k+2)*1024 + col];
    float wv3 = W[(size_t)(k+3)*1024 + col];
    #pragma unroll
    for (int b=0;b<32;++b){
      float4 xv = *(const float4*)(X + (size_t)b*Kp + k);
      acc[b] += xv.x*wv0 + xv.y*wv1 + xv.z*wv2 + xv.w*wv3;
    }
  }
  float* dst = pbuf + ((size_t)(path*40 + y*4 + sub)*32)*1024 + col;
  #pragma unroll
  for (int b=0;b<32;++b) dst[(size_t)b*1024] = acc[b];
}

__global__ __launch_bounds__(256)
void k_projred(const float* __restrict__ pbuf,
               const float* __restrict__ bpfs, const float* __restrict__ bsfs,
               float* __restrict__ tpre, float* __restrict__ spre){
  const int id = blockIdx.x*256 + threadIdx.x;
  const int path = id >> 15;
  const int rem = id & 32767;
  const int b = rem >> 10, col = rem & 1023;
  const int ns = path ? 32 : 40;
  const float* src = pbuf + ((size_t)(path*40)*32 + b)*1024 + col;
  float s = path ? bsfs[col] : bpfs[col];
  for (int g=0; g<ns; ++g) s += src[(size_t)g*32*1024];
  (path ? spre : tpre)[(size_t)b*1024 + col] = s;
}

__global__ __launch_bounds__(256)
void k_lnrow(const float* __restrict__ tpre, const float* __restrict__ spre,
             float* __restrict__ out){
  __shared__ float sred[16];
  const int id = blockIdx.x, t = threadIdx.x;
  const int path = id >> 5, b = id & 31;
  const float* src = (path ? spre : tpre) + (size_t)b*1024;
  float v[4]; float s1=0.f, s2=0.f;
  #pragma unroll
  for (int j=0;j<4;++j){ v[j] = src[j*256+t]; s1 += v[j]; s2 += v[j]*v[j]; }
  blkred2(s1,s2,sred,t);
  const float m = s1*(1.f/1024.f);
  const float rs = rsqrtf(fmaxf(s2*(1.f/1024.f)-m*m,0.f)+EPSV);
  float* dst = out + (path ? 35072 : 2304) + (size_t)b*1024;
  #pragma unroll
  for (int j=0;j<4;++j) dst[j*256+t] = (v[j]-m)*rs;
}

__global__ __launch_bounds__(256)
void k_head(const float* __restrict__ Wpc, const float* __restrict__ bpc,
            const float* __restrict__ Wc0, const float* __restrict__ bc0,
            const float* __restrict__ Wc1, const float* __restrict__ bc1,
            const float* __restrict__ Wc2, const float* __restrict__ bc2,
            float* __restrict__ out){
  __shared__ float slog[16];
  __shared__ int sy;
  const int b = blockIdx.x, t = threadIdx.x, w = t>>6, l = t&63;
  const float* pv = out + 2304 + (size_t)b*1024;
  const float* sv = out + 35072 + (size_t)b*1024;
  #pragma unroll
  for (int jj=0; jj<4; ++jj){
    const int j = w*4 + jj;
    float a = 0.f;
    for (int i=l; i<1024; i+=64) a += pv[i]*Wpc[(size_t)i*16 + j];
    #pragma unroll
    for (int off=32; off; off>>=1) a += __shfl_xor(a, off);
    if (l==0){ const float lgv = a + bpc[j]; slog[j] = lgv; out[b*16 + j] = lgv; }
  }
  __syncthreads();
  if (t==0){
    int best=0; float bvv = slog[0];
    for (int i=1;i<16;++i) if (slog[i] > bvv){ bvv = slog[i]; best = i; }
    sy = best;
  }
  __syncthreads();
  const int y = sy;
  const float* Ws[3] = {Wc0, Wc1, Wc2};
  const float* bs[3] = {bc0, bc1, bc2};
  const int nouts[3] = {8,16,32};
  const int ooff[3]  = {512, 768, 1280};
  for (int hI=0; hI<3; ++hI){
    const int no = nouts[hI];
    for (int n = w; n < no; n += 4){
      const float* wr = Ws[hI] + ((size_t)y*no + n)*1024;
      float a = 0.f;
      for (int i=l; i<1024; i+=64) a += sv[i]*wr[i];
      #pragma unroll
      for (int off=32; off; off>>=1) a += __shfl_xor(a, off);
      if (l==0) out[ooff[hI] + b*no + n] = a + bs[hI][(size_t)y*no + n];
    }
  }
}

// ---------------------------------------------------------------------------
extern "C" void kernel_launch(void* const* d_in, const int* in_sizes, int n_in,
                              void* d_out, int out_size, void* d_ws, size_t ws_size,
                              hipStream_t stream)
{
  const float* h    = (const float*)d_in[0];
  const float* Wpp  = (const float*)d_in[1];
  const float* bpp  = (const float*)d_in[2];
  const float* Wsp  = (const float*)d_in[3];
  const float* bsp  = (const float*)d_in[4];
  const float* Wq   = (const float*)d_in[5];
  const float* bq   = (const float*)d_in[6];
  const float* Wk   = (const float*)d_in[7];
  const float* bk   = (const float*)d_in[8];
  const float* Wv   = (const float*)d_in[9];
  const float* bv   = (const float*)d_in[10];
  const float* g_pfs= (const float*)d_in[11];
  const float* b_pfs= (const float*)d_in[12];
  const float* Wpfs = (const float*)d_in[13];
  const float* bpfs = (const float*)d_in[14];
  const float* g_sfs= (const float*)d_in[15];
  const float* b_sfs= (const float*)d_in[16];
  const float* Wsfs = (const float*)d_in[17];
  const float* bsfs = (const float*)d_in[18];
  const float* Wpc  = (const float*)d_in[19];
  const float* bpc  = (const float*)d_in[20];
  const float* Wc0  = (const float*)d_in[21];
  const float* bc0  = (const float*)d_in[22];
  const float* Wc1  = (const float*)d_in[23];
  const float* bc1  = (const float*)d_in[24];
  const float* Wc2  = (const float*)d_in[25];
  const float* bc2  = (const float*)d_in[26];
  float* out = (float*)d_out;
  char* ws = (char*)d_ws;
  (void)in_sizes; (void)n_in; (void)out_size;

  // ---- plan selection ----
  // hoist=2: merged QKV (pp lives in the 32MB S/P slab; Kb exclusive) ~291MB
  // hoist=1: R11 layout (pp aliases Kb; QKV separate dispatches)       ~284MB
  // hoist=0: per-group tconv fallback
  struct PlanT { int G, NS, hoist; };
  const PlanT plans[8] = {{16,4096,2},{16,4096,1},{16,4096,0},{8,4096,0},{4,4096,0},{2,4096,0},{1,4096,0},{1,1024,0}};
  int G = 0, NS = 0, HOIST = 0;
  size_t oWt=0,oWps=0,oWq=0,oSP=0;
  size_t oPp=0,oPs=0,oXb=0,oYb=0,oTp=0,oSp=0,oPbf=0,oHb=0,oPb=0,oSb=0,oQ=0,oK=0,oVt=0;
  for (int pi = 0; pi < 8; ++pi){
    const size_t g = plans[pi].G, ns = plans[pi].NS;
    const int hoist = plans[pi].hoist;
    size_t off = 0;
    auto alloc = [&](size_t bytes){ size_t o = off; off += (bytes + 255) & ~255ULL; return o; };
    size_t wt=0, wps=0, wq=0, sp2=0, pbf=0, hb=0, pb=0;
    size_t pp_, ps_, xb, yb, tp, sp_, sb, q, k, vt;
    if (hoist >= 1){
      wps = alloc(8192ULL*1024*2);
      wq  = alloc(3*4096ULL*4096*2);     // WqT | WkT | WvT contiguous
      pp_ = alloc(32ULL*16*5120*4);
      ps_ = alloc(32ULL*16*4096*4);
      xb = alloc(32*5120*4); yb = alloc(32*4096*4);
      tp = alloc(32*1024*4); sp_ = alloc(32*1024*4);
      sb = alloc(g*2097152);
      q  = alloc(g*2097152);
      k  = alloc(g*2097152);
      vt = alloc(g*2097152);
      if (hoist == 2){
        sp2 = alloc(g*2097152);          // 32MB slab: pp, then S+P
        pb = sp2;
      } else {
        sp2 = alloc(g*1572864);          // 24MB: S+P
        pb = k;                          // pp aliases Kb (sequential use)
      }
      pbf = q; hb = vt;
    } else {
      wt = alloc(ns*4096*2);
      pp_ = alloc(32ULL*16*5120*4);
      ps_ = alloc(32ULL*16*4096*4);
      xb = alloc(32*5120*4); yb = alloc(32*4096*4);
      tp = alloc(32*1024*4); sp_ = alloc(32*1024*4);
      pbf = alloc(2*40*32*1024*4);
      hb = alloc(g*524288);
      pb = alloc(g*2097152);
      sb = alloc(g*2097152);
      q  = alloc(g*2097152);
      k  = alloc(g*2097152);
      vt = alloc(g*2097152);
      sp2 = pb;
    }
    if (off <= ws_size){
      G = (int)g; NS = (int)ns; HOIST = hoist;
      oWt=wt; oWps=wps; oWq=wq; oSP=sp2;
      oPp=pp_; oPs=ps_; oXb=xb; oYb=yb; oTp=tp; oSp=sp_; oPbf=pbf;
      oHb=hb; oPb=pb; oSb=sb; oQ=q; oK=k; oVt=vt;
      break;
    }
  }
  if (!G) return;

  unsigned short* Wt    = (unsigned short*)(ws + oWt);
  unsigned short* WpsT  = (unsigned short*)(ws + oWps);
  unsigned short* WqkvT = (unsigned short*)(ws + oWq);
  float* part_p = (float*)(ws + oPp);
  float* part_s = (float*)(ws + oPs);
  float* xbar   = (float*)(ws + oXb);
  float* ybar   = (float*)(ws + oYb);
  float* tpre   = (float*)(ws + oTp);
  float* spre   = (float*)(ws + oSp);
  float* pbuf   = (float*)(ws + oPbf);
  unsigned short* h_bf = (unsigned short*)(ws + oHb);
  unsigned short* pp   = (unsigned short*)(ws + oPb);
  unsigned short* sp   = (unsigned short*)(ws + oSb);
  unsigned short* Q    = (unsigned short*)(ws + oQ);
  unsigned short* Kb   = (unsigned short*)(ws + oK);
  unsigned short* Vt   = (unsigned short*)(ws + oVt);
  float*          S    = (float*)(ws + oSP);
  unsigned short* P    = (unsigned short*)(ws + oSP + (size_t)G*1048576);
  float*          intf = (float*)(ws + oQ);

  const float scale = 1.0f/32.0f;
  (void)oK;

  if (HOIST >= 1){
    hipLaunchKernelGGL(k_tconv, dim3(64,16), dim3(256), 0, stream, Wpp, WpsT, 1024, 4096);
    hipLaunchKernelGGL(k_tconv, dim3(64,16), dim3(256), 0, stream, Wsp, WpsT + 4096ULL*1024, 1024, 4096);
    hipLaunchKernelGGL(k_tconv3, dim3(64,64,3), dim3(256), 0, stream,
                       Wq, Wk, Wv, WqkvT, 4096, 4096, 16777216L);
  }

  for (int g0 = 0; g0 < 32; g0 += G){
    const float* h_g = h + (size_t)g0*262144;

    hipLaunchKernelGGL(k_convh, dim3(G*256), dim3(256), 0, stream, h_g, h_bf);

    if (HOIST == 2){
      hipLaunchKernelGGL(gemm256<0>, dim3(32,G), dim3(512), 0, stream,
                         h_bf, WpsT, bpp, bsp, (void*)pp, (void*)sp, 1024, 1024,1024,4096);
      hipLaunchKernelGGL(gemm_qkv, dim3(16,G,3), dim3(512), 0, stream,
                         pp, sp, WqkvT, bq, bk, bv, Q, Kb, Vt);
    } else if (HOIST == 1){
      hipLaunchKernelGGL(gemm256<0>, dim3(32,G), dim3(512), 0, stream,
                         h_bf, WpsT, bpp, bsp, (void*)pp, (void*)sp, 1024, 1024,1024,4096);
      hipLaunchKernelGGL(gemm256<1>, dim3(16,G), dim3(512), 0, stream,
                         pp, WqkvT, bq, bq, (void*)Q, (void*)Q, 4096, 4096,4096,4096);
      hipLaunchKernelGGL(gemm256<1>, dim3(16,G), dim3(512), 0, stream,
                         sp, WqkvT + 16777216ULL, bk, bk, (void*)Kb, (void*)Kb, 4096, 4096,4096,4096);
      hipLaunchKernelGGL(gemm256<3>, dim3(16,G), dim3(512), 0, stream,
                         sp, WqkvT + 33554432ULL, bv, bv, (void*)Vt, (void*)Vt, 4096, 4096,4096,256);
    } else {
      hipLaunchKernelGGL(k_tconv, dim3(64,16), dim3(256), 0, stream, Wpp, Wt, 1024, 4096);
      hipLaunchKernelGGL(gemm256<0>, dim3(16,G), dim3(512), 0, stream,
                         h_bf, Wt, bpp, bpp, (void*)pp, (void*)pp, 1024, 1024,1024,4096);
      for (int nso = 0; nso < 4096; nso += NS){
        hipLaunchKernelGGL(k_tconv, dim3(NS/64,64), dim3(256), 0, stream, Wq + nso, Wt, 4096, 4096);
        hipLaunchKernelGGL(gemm256<1>, dim3(NS/256,G), dim3(512), 0, stream,
                           pp, Wt, bq + nso, bq + nso, (void*)(Q + nso), (void*)(Q + nso), 4096, 4096,4096,4096);
      }
      hipLaunchKernelGGL(k_tconv, dim3(64,16), dim3(256), 0, stream, Wsp, Wt, 1024, 4096);
      hipLaunchKernelGGL(gemm256<0>, dim3(16,G), dim3(512), 0, stream,
                         h_bf, Wt, bsp, bsp, (void*)sp, (void*)sp, 1024, 1024,1024,4096);
      for (int nso = 0; nso < 4096; nso += NS){
        hipLaunchKernelGGL(k_tconv, dim3(NS/64,64), dim3(256), 0, stream, Wk + nso, Wt, 4096, 4096);
        hipLaunchKernelGGL(gemm256<1>, dim3(NS/256,G), dim3(512), 0, stream,
                           sp, Wt, bk + nso, bk + nso, (void*)(Kb + nso), (void*)(Kb + nso), 4096, 4096,4096,4096);
      }
      for (int nso = 0; nso < 4096; nso += NS){
        hipLaunchKernelGGL(k_tconv, dim3(NS/64,64), dim3(256), 0, stream, Wv + nso, Wt, 4096, 4096);
        hipLaunchKernelGGL(gemm256<3>, dim3(NS/256,G), dim3(512), 0, stream,
                           sp, Wt, bv + nso, bv + nso, (void*)(Vt + (size_t)nso*256), (void*)(Vt + (size_t)nso*256), 4096, 4096,4096,256);
      }
    }
    // S = scale * Q K^T (z = b_local*4 + h) ; softmax ; intf = P V (fp32)
    hipLaunchKernelGGL(gemm_bt<2>, dim3(2,2,G*4), dim3(256), 0, stream,
                       Q, Kb, (const float*)nullptr, (void*)S, 1024, 4096,4096,256,
                       1048576L,1024L, 1048576L,1024L, 262144L,65536L, scale);
    hipLaunchKernelGGL(k_softmax, dim3(G*256), dim3(256), 0, stream, S, P);
    hipLaunchKernelGGL(gemm_bt<2>, dim3(8,2,G*4), dim3(256), 0, stream,
                       P, Vt, (const float*)nullptr, (void*)intf, 256, 256,256,4096,
                       262144L,65536L, 1048576L,262144L, 1048576L,1024L, 1.f);
    hipLaunchKernelGGL(k_stats, dim3(G,16), dim3(256), 0, stream,
                       h_g, intf, sp, g_pfs, b_pfs, g_sfs, b_sfs, part_p, part_s, g0);
  }

  hipLaunchKernelGGL(k_reduce, dim3(1152), dim3(256), 0, stream, part_p, part_s, xbar, ybar);
  hipLaunchKernelGGL(k_proj_part, dim3(16,10,2), dim3(256), 0, stream,
                     xbar, ybar, Wpfs, Wsfs, pbuf);
  hipLaunchKernelGGL(k_projred, dim3(256), dim3(256), 0, stream,
                     pbuf, bpfs, bsfs, tpre, spre);
  hipLaunchKernelGGL(k_lnrow, dim3(64), dim3(256), 0, stream, tpre, spre, out);
  hipLaunchKernelGGL(k_head, dim3(32), dim3(256), 0, stream,
                     Wpc, bpc, Wc0, bc0, Wc1, bc1, Wc2, bc2, out);
}

// Round 13
// 1277.311 us; speedup vs baseline: 1.3968x; 1.0031x over previous
//
#include <hip/hip_runtime.h>
#include <hip/hip_bf16.h>

typedef __bf16 bf16x8 __attribute__((ext_vector_type(8)));
typedef float f32x4 __attribute__((ext_vector_type(4)));
typedef unsigned long long u64;

#define EPSV 1e-5f

__device__ __forceinline__ float bf2f(unsigned short u){
  unsigned int x = ((unsigned int)u) << 16;
  return __builtin_bit_cast(float, x);
}
__device__ __forceinline__ unsigned short f2bf(float f){
  __bf16 b = (__bf16)f;
  return __builtin_bit_cast(unsigned short, b);
}
__device__ __forceinline__ float gelu_exact(float x){
  return 0.5f * x * (1.0f + erff(x * 0.7071067811865476f));
}
__device__ __forceinline__ void gload_lds16(const void* g, void* l){
  __builtin_amdgcn_global_load_lds((const __attribute__((address_space(1))) unsigned int*)g,
                                   (__attribute__((address_space(3))) unsigned int*)l, 16, 0, 0);
}

// ---------------------------------------------------------------------------
// Shared 256x256 (BK=64) 8-wave 4-phase K-loop (R9 schedule, frozen).
// ---------------------------------------------------------------------------
struct GemmCore {
  char* smem; int t, w, l, wm, wn, lr, lg, bm0, bn0, nk;
  int srow, sslot;
  const unsigned short *A, *B; int lda, ldb;
  f32x4 acc[8][4];
  bf16x8 a0[4][2], a1[4][2], b0[2][2], b1[2][2];

  __device__ __forceinline__ void stage(int kt, int mat, int hf, int q){
    if (kt >= nk) return;
    const int r_h = q*64 + srow;
    const int s_ = sslot ^ ((r_h >> 1) & 7);
    const unsigned short* gp = (mat ? B + (size_t)(bn0 + hf*128 + r_h)*ldb
                                    : A + (size_t)(bm0 + hf*128 + r_h)*lda)
                               + (kt << 6) + s_*8;
    char* lp = smem + mat*65536 + (kt&1)*32768 + hf*16384 + q*8192 + t*16;
    gload_lds16((const void*)gp, (void*)lp);
  }
  __device__ __forceinline__ bf16x8 rdA(int d, int fm, int kk){
    const int r = fm*16 + lr;
    const int s_ = (kk*4 + lg) ^ ((r >> 1) & 7);
    return *(const bf16x8*)(smem + d*32768 + wm*16384 + r*128 + s_*16);
  }
  __device__ __forceinline__ bf16x8 rdB(int d, int fn, int kk){
    const int r = (wn&1)*64 + fn*16 + lr;
    const int s_ = (kk*4 + lg) ^ ((r >> 1) & 7);
    return *(const bf16x8*)(smem + 65536 + d*32768 + (wn>>1)*16384 + r*128 + s_*16);
  }
  __device__ __forceinline__ void ktile(int kt, int d){
    stage(kt+1, 0, 0, 1); stage(kt+1, 0, 1, 1);
    #pragma unroll
    for (int fm=0; fm<4; ++fm){ a0[fm][0] = rdA(d, fm, 0); a0[fm][1] = rdA(d, fm, 1); }
    #pragma unroll
    for (int fn=0; fn<2; ++fn){ b0[fn][0] = rdB(d, fn, 0); b0[fn][1] = rdB(d, fn, 1); }
    __builtin_amdgcn_s_barrier();
    __builtin_amdgcn_s_setprio(1);
    #pragma unroll
    for (int fm=0; fm<4; ++fm)
      #pragma unroll
      for (int fn=0; fn<2; ++fn)
        #pragma unroll
        for (int kk=0; kk<2; ++kk)
          acc[fm][fn] = __builtin_amdgcn_mfma_f32_16x16x32_bf16(a0[fm][kk], b0[fn][kk], acc[fm][fn], 0,0,0);
    __builtin_amdgcn_s_setprio(0);
    #pragma unroll
    for (int fn=0; fn<2; ++fn){ b1[fn][0] = rdB(d, fn+2, 0); b1[fn][1] = rdB(d, fn+2, 1); }
    __builtin_amdgcn_s_barrier();
    __builtin_amdgcn_s_setprio(1);
    #pragma unroll
    for (int fm=0; fm<4; ++fm)
      #pragma unroll
      for (int fn=0; fn<2; ++fn)
        #pragma unroll
        for (int kk=0; kk<2; ++kk)
          acc[fm][fn+2] = __builtin_amdgcn_mfma_f32_16x16x32_bf16(a0[fm][kk], b1[fn][kk], acc[fm][fn+2], 0,0,0);
    __builtin_amdgcn_s_setprio(0);
    stage(kt+2, 0, 0, 0); stage(kt+2, 0, 1, 0);
    stage(kt+2, 1, 0, 0); stage(kt+2, 1, 1, 0);
    #pragma unroll
    for (int fm=0; fm<4; ++fm){ a1[fm][0] = rdA(d, fm+4, 0); a1[fm][1] = rdA(d, fm+4, 1); }
    __builtin_amdgcn_s_barrier();
    __builtin_amdgcn_s_setprio(1);
    #pragma unroll
    for (int fm=0; fm<4; ++fm)
      #pragma unroll
      for (int fn=0; fn<2; ++fn)
        #pragma unroll
        for (int kk=0; kk<2; ++kk)
          acc[fm+4][fn+2] = __builtin_amdgcn_mfma_f32_16x16x32_bf16(a1[fm][kk], b1[fn][kk], acc[fm+4][fn+2], 0,0,0);
    __builtin_amdgcn_s_setprio(0);
    stage(kt+2, 1, 0, 1); stage(kt+2, 1, 1, 1);
    __builtin_amdgcn_s_barrier();
    __builtin_amdgcn_s_setprio(1);
    #pragma unroll
    for (int fm=0; fm<4; ++fm)
      #pragma unroll
      for (int fn=0; fn<2; ++fn)
        #pragma unroll
        for (int kk=0; kk<2; ++kk)
          acc[fm+4][fn] = __builtin_amdgcn_mfma_f32_16x16x32_bf16(a1[fm][kk], b0[fn][kk], acc[fm+4][fn], 0,0,0);
    __builtin_amdgcn_s_setprio(0);
    if (kt + 2 < nk) { asm volatile("s_waitcnt vmcnt(6)" ::: "memory"); }
    else             { asm volatile("s_waitcnt vmcnt(0)" ::: "memory"); }
  }
  __device__ __forceinline__ void run(){
    #pragma unroll
    for (int i=0;i<8;++i)
      #pragma unroll
      for (int j=0;j<4;++j){ f32x4 zz = {0.f,0.f,0.f,0.f}; acc[i][j] = zz; }
    stage(0,0,0,0); stage(0,0,1,0); stage(0,0,0,1); stage(0,0,1,1);
    stage(0,1,0,0); stage(0,1,1,0); stage(0,1,0,1); stage(0,1,1,1);
    stage(1,0,0,0); stage(1,0,1,0);
    stage(1,1,0,0); stage(1,1,1,0);
    stage(1,1,0,1); stage(1,1,1,1);
    asm volatile("s_waitcnt vmcnt(6)" ::: "memory");
    __builtin_amdgcn_s_barrier();
    for (int kt = 0; kt < nk; kt += 2){ ktile(kt, 0); ktile(kt+1, 1); }
  }
  __device__ __forceinline__ void init(char* sm, int Kd, const unsigned short* A_,
                                       const unsigned short* B_, int lda_, int ldb_,
                                       int bm0_, int bn0_){
    smem = sm; t = threadIdx.x; w = t>>6; l = t&63;
    wm = w>>2; wn = w&3; lr = l&15; lg = l>>4;
    srow = t>>3; sslot = t&7;
    A = A_; B = B_; lda = lda_; ldb = ldb_; bm0 = bm0_; bn0 = bn0_;
    nk = Kd >> 6;
  }
};

// MODE 0: bias+GELU dual @4096; 1: bias; 3: V^T
template<int MODE>
__global__ __launch_bounds__(512, 2)
void gemm256(const unsigned short* __restrict__ A, const unsigned short* __restrict__ B,
             const float* __restrict__ bias0, const float* __restrict__ bias1,
             void* __restrict__ C0v, void* __restrict__ C1v,
             int Kd, int lda, int ldb, int ldc)
{
  __shared__ char smem[131072];
  const int nbx = gridDim.x;
  const int nwg = nbx * gridDim.y;
  int bid = blockIdx.y*nbx + blockIdx.x;
  if ((nwg & 7) == 0) bid = (bid & 7)*(nwg >> 3) + (bid >> 3);
  GemmCore g;
  g.init(smem, Kd, A, B, lda, ldb, (bid / nbx) * 256, (bid % nbx) * 256);
  g.run();
  #pragma unroll
  for (int fm=0; fm<8; ++fm){
    #pragma unroll
    for (int fn=0; fn<4; ++fn){
      const int row0 = g.bm0 + g.wm*128 + fm*16 + g.lg*4;
      const int col  = g.bn0 + g.wn*64 + fn*16 + g.lr;
      f32x4 v = g.acc[fm][fn];
      if constexpr (MODE == 3){
        unsigned short* C = (unsigned short*)C0v;
        const float bb = bias0[col];
        u64 pack = 0;
        #pragma unroll
        for (int j=0;j<4;++j) pack |= (u64)f2bf(v[j] + bb) << (16*j);
        *(u64*)(C + (size_t)col*256 + (size_t)(row0>>8)*1048576 + (row0&255)) = pack;
      } else {
        const bool hi = (MODE == 0) && (col >= 4096);
        unsigned short* C = (unsigned short*)(hi ? C1v : C0v);
        const int c2 = hi ? (col - 4096) : col;
        const float bb = hi ? bias1[c2] : bias0[c2];
        #pragma unroll
        for (int j=0;j<4;++j){
          float x = v[j] + bb;
          if constexpr (MODE==0) x = gelu_exact(x);
          C[(size_t)(row0+j)*ldc + c2] = f2bf(x);
        }
      }
    }
  }
}

// Merged Q/K/V: z=0: Q=pp@WqT+bq; z=1: Kb=sp@WkT+bk; z=2: Vt=(sp@WvT+bv)^T
__global__ __launch_bounds__(512, 2)
void gemm_qkv(const unsigned short* __restrict__ App, const unsigned short* __restrict__ Asp,
              const unsigned short* __restrict__ Wqkv,
              const float* __restrict__ bq, const float* __restrict__ bk,
              const float* __restrict__ bv,
              unsigned short* __restrict__ Qo, unsigned short* __restrict__ Ko,
              unsigned short* __restrict__ Vto)
{
  __shared__ char smem[131072];
  const int z = blockIdx.z;
  const int nbx = gridDim.x;
  const int nwg = nbx * gridDim.y;
  int bid = blockIdx.y*nbx + blockIdx.x;
  if ((nwg & 7) == 0) bid = (bid & 7)*(nwg >> 3) + (bid >> 3);
  GemmCore g;
  g.init(smem, 4096, (z==0) ? App : Asp, Wqkv + (size_t)z*16777216, 4096, 4096,
         (bid / nbx) * 256, (bid % nbx) * 256);
  g.run();
  const float* bias = (z==0) ? bq : (z==1) ? bk : bv;
  #pragma unroll
  for (int fm=0; fm<8; ++fm){
    #pragma unroll
    for (int fn=0; fn<4; ++fn){
      const int row0 = g.bm0 + g.wm*128 + fm*16 + g.lg*4;
      const int col  = g.bn0 + g.wn*64 + fn*16 + g.lr;
      f32x4 v = g.acc[fm][fn];
      const float bb = bias[col];
      if (z == 2){
        u64 pack = 0;
        #pragma unroll
        for (int j=0;j<4;++j) pack |= (u64)f2bf(v[j] + bb) << (16*j);
        *(u64*)(Vto + (size_t)col*256 + (size_t)(row0>>8)*1048576 + (row0&255)) = pack;
      } else {
        unsigned short* C = (z==0) ? Qo : Ko;
        #pragma unroll
        for (int j=0;j<4;++j) C[(size_t)(row0+j)*4096 + col] = f2bf(v[j] + bb);
      }
    }
  }
}

// ---------------------------------------------------------------------------
// 128x128 (BK=32) bf16 MFMA GEMM (attention). MODE 2: *scale->fp32.
// MODE 5: *scale->bf16 (PV -> intf).
// ---------------------------------------------------------------------------
template<int MODE>
__global__ __launch_bounds__(256)
void gemm_bt(const unsigned short* __restrict__ A, const unsigned short* __restrict__ B,
             const float* __restrict__ bias, void* __restrict__ Cv,
             int Kd, int lda, int ldb, int ldc,
             long sA2, long sA1, long sB2, long sB1, long sC2, long sC1,
             float scale)
{
  __shared__ unsigned short lds[2][2][4096];
  const int t = threadIdx.x;
  const int w = t >> 6, l = t & 63;
  const int z = blockIdx.z;
  A += (size_t)(z>>2)*sA2 + (size_t)(z&3)*sA1;
  B += (size_t)(z>>2)*sB2 + (size_t)(z&3)*sB1;
  const int bm0 = blockIdx.y * 128, bn0 = blockIdx.x * 128;
  const int nk = Kd >> 5;

  const int sr = l >> 2;
  const int ss = l & 3;

  f32x4 acc[4][4];
  #pragma unroll
  for (int i=0;i<4;++i){
    #pragma unroll
    for (int j=0;j<4;++j){ f32x4 zz = {0.f,0.f,0.f,0.f}; acc[i][j] = zz; }
  }

  const int wm = w >> 1, wn = w & 1;
  const int lr = l & 15, lg = l >> 4;

  auto stage = [&](int kt, int bb){
    const int k0 = kt << 5;
    #pragma unroll
    for (int i=0;i<2;++i){
      const int r  = w*32 + i*16 + sr;
      const int sa = ss ^ ((r>>1)&3);
      const unsigned short* ga = A + (size_t)(bm0 + r)*lda + (k0 + sa*8);
      gload_lds16((const void*)ga, (void*)((char*)&lds[bb][0][0] + w*2048 + i*1024));
      const unsigned short* gb = B + (size_t)(bn0 + r)*ldb + (k0 + sa*8);
      gload_lds16((const void*)gb, (void*)((char*)&lds[bb][1][0] + w*2048 + i*1024));
    }
  };

  int buf = 0;
  stage(0, 0);
  for (int kt=0; kt<nk; ++kt){
    __syncthreads();
    if (kt+1 < nk) stage(kt+1, buf^1);
    bf16x8 av[4], bv[4];
    #pragma unroll
    for (int fm=0; fm<4; ++fm){
      const int row = wm*64 + fm*16 + lr;
      const int sl  = lg ^ ((row>>1)&3);
      av[fm] = *(const bf16x8*)((const char*)&lds[buf][0][0] + row*64 + sl*16);
    }
    #pragma unroll
    for (int fn=0; fn<4; ++fn){
      const int col = wn*64 + fn*16 + lr;
      const int sl  = lg ^ ((col>>1)&3);
      bv[fn] = *(const bf16x8*)((const char*)&lds[buf][1][0] + col*64 + sl*16);
    }
    #pragma unroll
    for (int fm=0; fm<4; ++fm){
      #pragma unroll
      for (int fn=0; fn<4; ++fn)
        acc[fm][fn] = __builtin_amdgcn_mfma_f32_16x16x32_bf16(av[fm], bv[fn], acc[fm][fn], 0,0,0);
    }
    buf ^= 1;
  }

  const size_t coff = (size_t)(z>>2)*sC2 + (size_t)(z&3)*sC1;
  #pragma unroll
  for (int fm=0; fm<4; ++fm){
    #pragma unroll
    for (int fn=0; fn<4; ++fn){
      const int row0 = bm0 + wm*64 + fm*16 + lg*4;
      const int col  = bn0 + wn*64 + fn*16 + lr;
      f32x4 v = acc[fm][fn];
      if constexpr (MODE == 2){
        float* C = (float*)Cv + coff;
        #pragma unroll
        for (int j=0;j<4;++j) C[(size_t)(row0+j)*ldc + col] = v[j]*scale;
      } else if constexpr (MODE == 5){
        unsigned short* C = (unsigned short*)Cv + coff;
        #pragma unroll
        for (int j=0;j<4;++j) C[(size_t)(row0+j)*ldc + col] = f2bf(v[j]*scale);
      }
    }
  }
}

// ---------------------------------------------------------------------------
__global__ __launch_bounds__(256)
void k_convh(const float* __restrict__ in, unsigned short* __restrict__ out){
  const size_t id = (size_t)blockIdx.x*256 + threadIdx.x;
  float4 v = ((const float4*)in)[id];
  u64 pack = (u64)f2bf(v.x) | ((u64)f2bf(v.y)<<16) | ((u64)f2bf(v.z)<<32) | ((u64)f2bf(v.w)<<48);
  *(u64*)(out + id*4) = pack;
}

__global__ __launch_bounds__(256)
void k_tconv(const float* __restrict__ W, unsigned short* __restrict__ Wt, int Kd, int N){
  __shared__ float lt[64][65];
  const int t = threadIdx.x;
  const int n0 = blockIdx.x*64, k0 = blockIdx.y*64;
  #pragma unroll
  for (int i=0;i<16;++i){
    int lin = i*256 + t; int r = lin>>6, c = lin&63;
    lt[r][c] = W[(size_t)(k0+r)*N + n0 + c];
  }
  __syncthreads();
  #pragma unroll
  for (int i=0;i<16;++i){
    int lin = i*256 + t; int n = lin>>6, k = lin&63;
    Wt[(size_t)(n0+n)*Kd + k0 + k] = f2bf(lt[k][n]);
  }
}

__global__ __launch_bounds__(256)
void k_tconv3(const float* __restrict__ W0, const float* __restrict__ W1,
              const float* __restrict__ W2, unsigned short* __restrict__ Wt,
              int Kd, int N, long wtStride){
  __shared__ float lt[64][65];
  const int t = threadIdx.x;
  const int zz = blockIdx.z;
  const float* W = (zz==0) ? W0 : (zz==1) ? W1 : W2;
  unsigned short* Wtz = Wt + (size_t)zz * wtStride;
  const int n0 = blockIdx.x*64, k0 = blockIdx.y*64;
  #pragma unroll
  for (int i=0;i<16;++i){
    int lin = i*256 + t; int r = lin>>6, c = lin&63;
    lt[r][c] = W[(size_t)(k0+r)*N + n0 + c];
  }
  __syncthreads();
  #pragma unroll
  for (int i=0;i<16;++i){
    int lin = i*256 + t; int n = lin>>6, k = lin&63;
    Wtz[(size_t)(n0+n)*Kd + k0 + k] = f2bf(lt[k][n]);
  }
}

__global__ __launch_bounds__(256)
void k_softmax(const float* __restrict__ S, unsigned short* __restrict__ P){
  const int t = threadIdx.x, w = t>>6, l = t&63;
  const size_t row = (size_t)blockIdx.x*4 + w;
  float4 v = *(const float4*)(S + row*256 + l*4);
  float m = fmaxf(fmaxf(v.x,v.y), fmaxf(v.z,v.w));
  #pragma unroll
  for (int off=32; off; off>>=1) m = fmaxf(m, __shfl_xor(m, off));
  float e0 = expf(v.x-m), e1 = expf(v.y-m), e2 = expf(v.z-m), e3 = expf(v.w-m);
  float s = e0+e1+e2+e3;
  #pragma unroll
  for (int off=32; off; off>>=1) s += __shfl_xor(s, off);
  const float inv = 1.0f/s;
  u64 pack = (u64)f2bf(e0*inv) | ((u64)f2bf(e1*inv)<<16) | ((u64)f2bf(e2*inv)<<32) | ((u64)f2bf(e3*inv)<<48);
  *(u64*)(P + row*256 + l*4) = pack;
}

__device__ __forceinline__ void blkred2(float& a, float& b, float* sred, int t){
  #pragma unroll
  for (int off=32; off; off>>=1){ a += __shfl_xor(a, off); b += __shfl_xor(b, off); }
  __syncthreads();
  if ((t&63)==0){ sred[(t>>6)*2] = a; sred[(t>>6)*2+1] = b; }
  __syncthreads();
  a = sred[0]+sred[2]+sred[4]+sred[6];
  b = sred[1]+sred[3]+sred[5]+sred[7];
}

__device__ __forceinline__ void blkred4(float& a, float& b, float& c, float& d,
                                        float* sred, int t){
  #pragma unroll
  for (int off=32; off; off>>=1){
    a += __shfl_xor(a, off); b += __shfl_xor(b, off);
    c += __shfl_xor(c, off); d += __shfl_xor(d, off);
  }
  __syncthreads();
  if ((t&63)==0){
    sred[(t>>6)*4]   = a; sred[(t>>6)*4+1] = b;
    sred[(t>>6)*4+2] = c; sred[(t>>6)*4+3] = d;
  }
  __syncthreads();
  a = sred[0]+sred[4]+sred[8]+sred[12];
  b = sred[1]+sred[5]+sred[9]+sred[13];
  c = sred[2]+sred[6]+sred[10]+sred[14];
  d = sred[3]+sred[7]+sred[11]+sred[15];
}

// intf is bf16 now.
__global__ __launch_bounds__(256)
void k_stats(const float* __restrict__ h, const unsigned short* __restrict__ intf,
             const unsigned short* __restrict__ sp,
             const float* __restrict__ g_pfs, const float* __restrict__ b_pfs,
             const float* __restrict__ g_sfs, const float* __restrict__ b_sfs,
             float* __restrict__ part_p, float* __restrict__ part_s, int g0)
{
  __shared__ float sred[16];
  const int bl = blockIdx.x, grp = blockIdx.y, t = threadIdx.x;
  float zacc[20], wacc[16];
  #pragma unroll
  for (int j=0;j<20;++j) zacc[j]=0.f;
  #pragma unroll
  for (int j=0;j<16;++j) wacc[j]=0.f;
  for (int rr=0; rr<16; ++rr){
    const size_t r = (size_t)bl*256 + grp*16 + rr;
    float hv[4], iv[16], sv[16];
    #pragma unroll
    for (int j=0;j<4;++j) hv[j] = h[r*1024 + j*256 + t];
    float s1=0.f, s2=0.f;
    #pragma unroll
    for (int j=0;j<16;++j){ float x = bf2f(intf[r*4096 + j*256 + t]); iv[j]=x; s1+=x; s2+=x*x; }
    float u1=0.f, u2=0.f;
    #pragma unroll
    for (int j=0;j<16;++j){ float x = bf2f(sp[r*4096 + j*256 + t]); sv[j]=x; u1+=x; u2+=x*x; }
    blkred4(s1,s2,u1,u2,sred,t);
    const float m1 = s1*(1.f/4096.f);
    const float rs1 = rsqrtf(fmaxf(s2*(1.f/4096.f) - m1*m1, 0.f) + EPSV);
    const float m3 = u1*(1.f/4096.f);
    const float rs3 = rsqrtf(fmaxf(u2*(1.f/4096.f) - m3*m3, 0.f) + EPSV);
    #pragma unroll
    for (int j=0;j<16;++j){ int idx = j*256+t; wacc[j] += ((sv[j]-m3)*rs3)*g_sfs[idx] + b_sfs[idx]; }
    float t1=0.f, t2=0.f;
    #pragma unroll
    for (int j=0;j<4;++j){ t1 += hv[j]; t2 += hv[j]*hv[j]; }
    #pragma unroll
    for (int j=0;j<16;++j){ float y = (iv[j]-m1)*rs1; iv[j]=y; t1+=y; t2+=y*y; }
    blkred2(t1,t2,sred,t);
    const float m2 = t1*(1.f/5120.f);
    const float rs2 = rsqrtf(fmaxf(t2*(1.f/5120.f) - m2*m2, 0.f) + EPSV);
    #pragma unroll
    for (int j=0;j<4;++j){ int idx = j*256+t; zacc[j] += ((hv[j]-m2)*rs2)*g_pfs[idx] + b_pfs[idx]; }
    #pragma unroll
    for (int j=0;j<16;++j){ int idx = 1024 + j*256+t; zacc[4+j] += ((iv[j]-m2)*rs2)*g_pfs[idx] + b_pfs[idx]; }
  }
  const size_t pb = (size_t)(g0 + bl)*16 + grp;
  #pragma unroll
  for (int j=0;j<20;++j) part_p[pb*5120 + j*256 + t] = zacc[j];
  #pragma unroll
  for (int j=0;j<16;++j) part_s[pb*4096 + j*256 + t] = wacc[j];
}

__global__ __launch_bounds__(256)
void k_reduce(const float* __restrict__ part_p, const float* __restrict__ part_s,
              float* __restrict__ xbar, float* __restrict__ ybar){
  int id = blockIdx.x*256 + threadIdx.x;
  if (id < 32*5120){
    const int b = id / 5120, i = id % 5120;
    float s = 0.f;
    for (int g=0; g<16; ++g) s += part_p[((size_t)b*16+g)*5120 + i];
    xbar[(size_t)b*5120 + i] = s * (1.f/256.f);
  } else {
    id -= 32*5120;
    const int b = id / 4096, i = id % 4096;
    float s = 0.f;
    for (int g=0; g<16; ++g) s += part_s[((size_t)b*16+g)*4096 + i];
    ybar[(size_t)b*4096 + i] = s * (1.f/256.f);
  }
}

__global__ __launch_bounds__(256)
void k_proj_part(const float* __restrict__ xbar, const float* __restrict__ ybar,
                 const float* __restrict__ Wpfs, const float* __restrict__ Wsfs,
                 float* __restrict__ pbuf){
  const int path = blockIdx.z;
  const int y = blockIdx.y;
  if (path == 1 && y >= 8) return;
  const int Kp = path ? 4096 : 5120;
  const float* X = path ? ybar : xbar;
  const float* W = path ? Wsfs : Wpfs;
  const int t = threadIdx.x;
  const int col = blockIdx.x*64 + (t & 63);
  const int sub = t >> 6;
  const int k0 = y*512 + sub*128;
  float acc[32];
  #pragma unroll
  for (int b=0;b<32;++b) acc[b] = 0.f;
  for (int i4=0; i4<32; ++i4){
    const int k = k0 + i4*4;
    float wv0 = W[(size_t)(k  )*1024 + col];
    float wv1 = W[(size_t)(k+1)*1024 + col];
    float wv2 = W[(size_t)(k+2)*1024 + col];
    float wv3 = W[(size_t)(k+3)*1024 + col];
    #pragma unroll
    for (int b=0;b<32;++b){
      float4 xv = *(const float4*)(X + (size_t)b*Kp + k);
      acc[b] += xv.x*wv0 + xv.y*wv1 + xv.z*wv2 + xv.w*wv3;
    }
  }
  float* dst = pbuf + ((size_t)(path*40 + y*4 + sub)*32)*1024 + col;
  #pragma unroll
  for (int b=0;b<32;++b) dst[(size_t)b*1024] = acc[b];
}

__global__ __launch_bounds__(256)
void k_projred(const float* __restrict__ pbuf,
               const float* __restrict__ bpfs, const float* __restrict__ bsfs,
               float* __restrict__ tpre, float* __restrict__ spre){
  const int id = blockIdx.x*256 + threadIdx.x;
  const int path = id >> 15;
  const int rem = id & 32767;
  const int b = rem >> 10, col = rem & 1023;
  const int ns = path ? 32 : 40;
  const float* src = pbuf + ((size_t)(path*40)*32 + b)*1024 + col;
  float s = path ? bsfs[col] : bpfs[col];
  for (int g=0; g<ns; ++g) s += src[(size_t)g*32*1024];
  (path ? spre : tpre)[(size_t)b*1024 + col] = s;
}

__global__ __launch_bounds__(256)
void k_lnrow(const float* __restrict__ tpre, const float* __restrict__ spre,
             float* __restrict__ out){
  __shared__ float sred[16];
  const int id = blockIdx.x, t = threadIdx.x;
  const int path = id >> 5, b = id & 31;
  const float* src = (path ? spre : tpre) + (size_t)b*1024;
  float v[4]; float s1=0.f, s2=0.f;
  #pragma unroll
  for (int j=0;j<4;++j){ v[j] = src[j*256+t]; s1 += v[j]; s2 += v[j]*v[j]; }
  blkred2(s1,s2,sred,t);
  const float m = s1*(1.f/1024.f);
  const float rs = rsqrtf(fmaxf(s2*(1.f/1024.f)-m*m,0.f)+EPSV);
  float* dst = out + (path ? 35072 : 2304) + (size_t)b*1024;
  #pragma unroll
  for (int j=0;j<4;++j) dst[j*256+t] = (v[j]-m)*rs;
}

__global__ __launch_bounds__(256)
void k_head(const float* __restrict__ Wpc, const float* __restrict__ bpc,
            const float* __restrict__ Wc0, const float* __restrict__ bc0,
            const float* __restrict__ Wc1, const float* __restrict__ bc1,
            const float* __restrict__ Wc2, const float* __restrict__ bc2,
            float* __restrict__ out){
  __shared__ float slog[16];
  __shared__ int sy;
  const int b = blockIdx.x, t = threadIdx.x, w = t>>6, l = t&63;
  const float* pv = out + 2304 + (size_t)b*1024;
  const float* sv = out + 35072 + (size_t)b*1024;
  #pragma unroll
  for (int jj=0; jj<4; ++jj){
    const int j = w*4 + jj;
    float a = 0.f;
    for (int i=l; i<1024; i+=64) a += pv[i]*Wpc[(size_t)i*16 + j];
    #pragma unroll
    for (int off=32; off; off>>=1) a += __shfl_xor(a, off);
    if (l==0){ const float lgv = a + bpc[j]; slog[j] = lgv; out[b*16 + j] = lgv; }
  }
  __syncthreads();
  if (t==0){
    int best=0; float bvv = slog[0];
    for (int i=1;i<16;++i) if (slog[i] > bvv){ bvv = slog[i]; best = i; }
    sy = best;
  }
  __syncthreads();
  const int y = sy;
  const float* Ws[3] = {Wc0, Wc1, Wc2};
  const float* bs[3] = {bc0, bc1, bc2};
  const int nouts[3] = {8,16,32};
  const int ooff[3]  = {512, 768, 1280};
  for (int hI=0; hI<3; ++hI){
    const int no = nouts[hI];
    for (int n = w; n < no; n += 4){
      const float* wr = Ws[hI] + ((size_t)y*no + n)*1024;
      float a = 0.f;
      for (int i=l; i<1024; i+=64) a += sv[i]*wr[i];
      #pragma unroll
      for (int off=32; off; off>>=1) a += __shfl_xor(a, off);
      if (l==0) out[ooff[hI] + b*no + n] = a + bs[hI][(size_t)y*no + n];
    }
  }
}

// ---------------------------------------------------------------------------
extern "C" void kernel_launch(void* const* d_in, const int* in_sizes, int n_in,
                              void* d_out, int out_size, void* d_ws, size_t ws_size,
                              hipStream_t stream)
{
  const float* h    = (const float*)d_in[0];
  const float* Wpp  = (const float*)d_in[1];
  const float* bpp  = (const float*)d_in[2];
  const float* Wsp  = (const float*)d_in[3];
  const float* bsp  = (const float*)d_in[4];
  const float* Wq   = (const float*)d_in[5];
  const float* bq   = (const float*)d_in[6];
  const float* Wk   = (const float*)d_in[7];
  const float* bk   = (const float*)d_in[8];
  const float* Wv   = (const float*)d_in[9];
  const float* bv   = (const float*)d_in[10];
  const float* g_pfs= (const float*)d_in[11];
  const float* b_pfs= (const float*)d_in[12];
  const float* Wpfs = (const float*)d_in[13];
  const float* bpfs = (const float*)d_in[14];
  const float* g_sfs= (const float*)d_in[15];
  const float* b_sfs= (const float*)d_in[16];
  const float* Wsfs = (const float*)d_in[17];
  const float* bsfs = (const float*)d_in[18];
  const float* Wpc  = (const float*)d_in[19];
  const float* bpc  = (const float*)d_in[20];
  const float* Wc0  = (const float*)d_in[21];
  const float* bc0  = (const float*)d_in[22];
  const float* Wc1  = (const float*)d_in[23];
  const float* bc1  = (const float*)d_in[24];
  const float* Wc2  = (const float*)d_in[25];
  const float* bc2  = (const float*)d_in[26];
  float* out = (float*)d_out;
  char* ws = (char*)d_ws;
  (void)in_sizes; (void)n_in; (void)out_size;

  const float scale = 1.0f/32.0f;

  // ---- tier 3: single-pass G=32 (~306 MiB) ----
  {
    size_t off = 0;
    auto alloc = [&](size_t bytes){ size_t o = off; off += (bytes + 255) & ~255ULL; return o; };
    size_t oWps = alloc(8192ULL*1024*2);       // 16MB  [WppT;WspT]; later P (16MB)
    size_t oWb  = alloc(4096ULL*4096*2);       // 32MB  Wq/Wk/Wv serially; later S; later partials
    size_t oA   = alloc(64ULL<<20);            // pp -> Vt
    size_t oB   = alloc(64ULL<<20);            // sp
    size_t oC   = alloc(64ULL<<20);            // Q -> intf(bf16, 64MB)
    size_t oD   = alloc(64ULL<<20);            // h_bf(16MB) -> Kb -> pbuf(10MB)
    size_t oXb  = alloc(32*5120*4);
    size_t oYb  = alloc(32*4096*4);
    size_t oTp  = alloc(32*1024*4);
    size_t oSp  = alloc(32*1024*4);
    if (off <= ws_size){
      unsigned short* WpsT = (unsigned short*)(ws + oWps);
      unsigned short* wbuf = (unsigned short*)(ws + oWb);
      unsigned short* pp   = (unsigned short*)(ws + oA);
      unsigned short* Vt   = (unsigned short*)(ws + oA);
      unsigned short* sp   = (unsigned short*)(ws + oB);
      unsigned short* Q    = (unsigned short*)(ws + oC);
      unsigned short* intf = (unsigned short*)(ws + oC);
      unsigned short* h_bf = (unsigned short*)(ws + oD);
      unsigned short* Kb   = (unsigned short*)(ws + oD);
      float* pbuf   = (float*)(ws + oD);
      float* S      = (float*)(ws + oWb);
      unsigned short* P = (unsigned short*)(ws + oWps);
      float* part_p = (float*)(ws + oWb);
      float* part_s = (float*)(ws + oWb + ((32ULL*16*5120*4 + 255) & ~255ULL));
      float* xbar   = (float*)(ws + oXb);
      float* ybar   = (float*)(ws + oYb);
      float* tpre   = (float*)(ws + oTp);
      float* spre   = (float*)(ws + oSp);

      hipLaunchKernelGGL(k_tconv, dim3(64,16), dim3(256), 0, stream, Wpp, WpsT, 1024, 4096);
      hipLaunchKernelGGL(k_tconv, dim3(64,16), dim3(256), 0, stream, Wsp, WpsT + 4096ULL*1024, 1024, 4096);
      hipLaunchKernelGGL(k_convh, dim3(8192), dim3(256), 0, stream, h, h_bf);
      // pp,sp = gelu(h @ [Wpp;Wsp])  (M=8192, N=8192)
      hipLaunchKernelGGL(gemm256<0>, dim3(32,32), dim3(512), 0, stream,
                         h_bf, WpsT, bpp, bsp, (void*)pp, (void*)sp, 1024, 1024,1024,4096);
      // Q = pp @ Wq  (pp dead after; h_bf dead after ppsp)
      hipLaunchKernelGGL(k_tconv, dim3(64,64), dim3(256), 0, stream, Wq, wbuf, 4096, 4096);
      hipLaunchKernelGGL(gemm256<1>, dim3(16,32), dim3(512), 0, stream,
                         pp, wbuf, bq, bq, (void*)Q, (void*)Q, 4096, 4096,4096,4096);
      // Kb = sp @ Wk   (writes over h_bf region)
      hipLaunchKernelGGL(k_tconv, dim3(64,64), dim3(256), 0, stream, Wk, wbuf, 4096, 4096);
      hipLaunchKernelGGL(gemm256<1>, dim3(16,32), dim3(512), 0, stream,
                         sp, wbuf, bk, bk, (void*)Kb, (void*)Kb, 4096, 4096,4096,4096);
      // Vt = (sp @ Wv)^T  (writes over pp region)
      hipLaunchKernelGGL(k_tconv, dim3(64,64), dim3(256), 0, stream, Wv, wbuf, 4096, 4096);
      hipLaunchKernelGGL(gemm256<3>, dim3(16,32), dim3(512), 0, stream,
                         sp, wbuf, bv, bv, (void*)Vt, (void*)Vt, 4096, 4096,4096,256);
      // S = scale*Q K^T  (S over wbuf, dead);  softmax -> P (over WpsT, dead)
      hipLaunchKernelGGL(gemm_bt<2>, dim3(2,2,128), dim3(256), 0, stream,
                         Q, Kb, (const float*)nullptr, (void*)S, 1024, 4096,4096,256,
                         1048576L,1024L, 1048576L,1024L, 262144L,65536L, scale);
      hipLaunchKernelGGL(k_softmax, dim3(8192), dim3(256), 0, stream, S, P);
      // intf(bf16) = P V  (over Q region, Q dead after S)
      hipLaunchKernelGGL(gemm_bt<5>, dim3(8,2,128), dim3(256), 0, stream,
                         P, Vt, (const float*)nullptr, (void*)intf, 256, 256,256,4096,
                         262144L,65536L, 1048576L,262144L, 1048576L,1024L, 1.f);
      // stats (partials over S region, S dead after softmax)
      hipLaunchKernelGGL(k_stats, dim3(32,16), dim3(256), 0, stream,
                         h, intf, sp, g_pfs, b_pfs, g_sfs, b_sfs, part_p, part_s, 0);
      hipLaunchKernelGGL(k_reduce, dim3(1152), dim3(256), 0, stream, part_p, part_s, xbar, ybar);
      hipLaunchKernelGGL(k_proj_part, dim3(16,10,2), dim3(256), 0, stream,
                         xbar, ybar, Wpfs, Wsfs, pbuf);
      hipLaunchKernelGGL(k_projred, dim3(256), dim3(256), 0, stream,
                         pbuf, bpfs, bsfs, tpre, spre);
      hipLaunchKernelGGL(k_lnrow, dim3(64), dim3(256), 0, stream, tpre, spre, out);
      hipLaunchKernelGGL(k_head, dim3(32), dim3(256), 0, stream,
                         Wpc, bpc, Wc0, bc0, Wc1, bc1, Wc2, bc2, out);
      return;
    }
  }

  // ---- tier 2 fallback: R12 plan (G=16, merged qkv dispatch) ----
  struct PlanT { int G, hoist; };
  const PlanT plans[3] = {{16,2},{16,1},{8,1}};
  int G = 0, HOIST = 0;
  size_t oWps=0,oWq=0,oSP=0;
  size_t oPp=0,oPs=0,oXb=0,oYb=0,oTp=0,oSp=0,oPbf=0,oHb=0,oPb=0,oSb=0,oQ=0,oK=0,oVt=0;
  for (int pi = 0; pi < 3; ++pi){
    const size_t g = plans[pi].G;
    const int hoist = plans[pi].hoist;
    size_t off = 0;
    auto alloc = [&](size_t bytes){ size_t o = off; off += (bytes + 255) & ~255ULL; return o; };
    size_t wps = alloc(8192ULL*1024*2);
    size_t wq  = alloc(3*4096ULL*4096*2);
    size_t pp_ = alloc(32ULL*16*5120*4);
    size_t ps_ = alloc(32ULL*16*4096*4);
    size_t xb = alloc(32*5120*4); size_t yb = alloc(32*4096*4);
    size_t tp = alloc(32*1024*4); size_t sp_ = alloc(32*1024*4);
    size_t sb = alloc(g*2097152);
    size_t q  = alloc(g*2097152);
    size_t k  = alloc(g*2097152);
    size_t vt = alloc(g*2097152);
    size_t sp2, pb;
    if (hoist == 2){ sp2 = alloc(g*2097152); pb = sp2; }
    else           { sp2 = alloc(g*1572864); pb = k; }
    if (off <= ws_size){
      G = (int)g; HOIST = hoist;
      oWps=wps; oWq=wq; oSP=sp2;
      oPp=pp_; oPs=ps_; oXb=xb; oYb=yb; oTp=tp; oSp=sp_; oPbf=q;
      oHb=vt; oPb=pb; oSb=sb; oQ=q; oK=k; oVt=vt;
      break;
    }
  }
  if (!G) return;

  unsigned short* WpsT  = (unsigned short*)(ws + oWps);
  unsigned short* WqkvT = (unsigned short*)(ws + oWq);
  float* part_p = (float*)(ws + oPp);
  float* part_s = (float*)(ws + oPs);
  float* xbar   = (float*)(ws + oXb);
  float* ybar   = (float*)(ws + oYb);
  float* tpre   = (float*)(ws + oTp);
  float* spre   = (float*)(ws + oSp);
  float* pbuf   = (float*)(ws + oPbf);
  unsigned short* h_bf = (unsigned short*)(ws + oHb);
  unsigned short* pp   = (unsigned short*)(ws + oPb);
  unsigned short* sp   = (unsigned short*)(ws + oSb);
  unsigned short* Q    = (unsigned short*)(ws + oQ);
  unsigned short* Kb   = (unsigned short*)(ws + oK);
  unsigned short* Vt   = (unsigned short*)(ws + oVt);
  float*          S    = (float*)(ws + oSP);
  unsigned short* P    = (unsigned short*)(ws + oSP + (size_t)G*1048576);
  unsigned short* intf = (unsigned short*)(ws + oQ);

  hipLaunchKernelGGL(k_tconv, dim3(64,16), dim3(256), 0, stream, Wpp, WpsT, 1024, 4096);
  hipLaunchKernelGGL(k_tconv, dim3(64,16), dim3(256), 0, stream, Wsp, WpsT + 4096ULL*1024, 1024, 4096);
  hipLaunchKernelGGL(k_tconv3, dim3(64,64,3), dim3(256), 0, stream,
                     Wq, Wk, Wv, WqkvT, 4096, 4096, 16777216L);

  for (int g0 = 0; g0 < 32; g0 += G){
    const float* h_g = h + (size_t)g0*262144;
    hipLaunchKernelGGL(k_convh, dim3(G*256), dim3(256), 0, stream, h_g, h_bf);
    hipLaunchKernelGGL(gemm256<0>, dim3(32,G), dim3(512), 0, stream,
                       h_bf, WpsT, bpp, bsp, (void*)pp, (void*)sp, 1024, 1024,1024,4096);
    if (HOIST == 2){
      hipLaunchKernelGGL(gemm_qkv, dim3(16,G,3), dim3(512), 0, stream,
                         pp, sp, WqkvT, bq, bk, bv, Q, Kb, Vt);
    } else {
      hipLaunchKernelGGL(gemm256<1>, dim3(16,G), dim3(512), 0, stream,
                         pp, WqkvT, bq, bq, (void*)Q, (void*)Q, 4096, 4096,4096,4096);
      hipLaunchKernelGGL(gemm256<1>, dim3(16,G), dim3(512), 0, stream,
                         sp, WqkvT + 16777216ULL, bk, bk, (void*)Kb, (void*)Kb, 4096, 4096,4096,4096);
      hipLaunchKernelGGL(gemm256<3>, dim3(16,G), dim3(512), 0, stream,
                         sp, WqkvT + 33554432ULL, bv, bv, (void*)Vt, (void*)Vt, 4096, 4096,4096,256);
    }
    hipLaunchKernelGGL(gemm_bt<2>, dim3(2,2,G*4), dim3(256), 0, stream,
                       Q, Kb, (const float*)nullptr, (void*)S, 1024, 4096,4096,256,
                       1048576L,1024L, 1048576L,1024L, 262144L,65536L, scale);
    hipLaunchKernelGGL(k_softmax, dim3(G*256), dim3(256), 0, stream, S, P);
    hipLaunchKernelGGL(gemm_bt<5>, dim3(8,2,G*4), dim3(256), 0, stream,
                       P, Vt, (const float*)nullptr, (void*)intf, 256, 256,256,4096,
                       262144L,65536L, 1048576L,262144L, 1048576L,1024L, 1.f);
    hipLaunchKernelGGL(k_stats, dim3(G,16), dim3(256), 0, stream,
                       h_g, intf, sp, g_pfs, b_pfs, g_sfs, b_sfs, part_p, part_s, g0);
  }

  hipLaunchKernelGGL(k_reduce, dim3(1152), dim3(256), 0, stream, part_p, part_s, xbar, ybar);
  hipLaunchKernelGGL(k_proj_part, dim3(16,10,2), dim3(256), 0, stream,
                     xbar, ybar, Wpfs, Wsfs, pbuf);
  hipLaunchKernelGGL(k_projred, dim3(256), dim3(256), 0, stream,
                     pbuf, bpfs, bsfs, tpre, spre);
  hipLaunchKernelGGL(k_lnrow, dim3(64), dim3(256), 0, stream, tpre, spre, out);
  hipLaunchKernelGGL(k_head, dim3(32), dim3(256), 0, stream,
                     Wpc, bpc, Wc0, bc0, Wc1, bc1, Wc2, bc2, out);
}

// Round 14
// 1270.671 us; speedup vs baseline: 1.4041x; 1.0052x over previous
//
#include <hip/hip_runtime.h>
#include <hip/hip_bf16.h>

typedef __bf16 bf16x8 __attribute__((ext_vector_type(8)));
typedef float f32x4 __attribute__((ext_vector_type(4)));
typedef unsigned long long u64;

#define EPSV 1e-5f

__device__ __forceinline__ float bf2f(unsigned short u){
  unsigned int x = ((unsigned int)u) << 16;
  return __builtin_bit_cast(float, x);
}
__device__ __forceinline__ unsigned short f2bf(float f){
  __bf16 b = (__bf16)f;
  return __builtin_bit_cast(unsigned short, b);
}
__device__ __forceinline__ float gelu_exact(float x){
  return 0.5f * x * (1.0f + erff(x * 0.7071067811865476f));
}
__device__ __forceinline__ void gload_lds16(const void* g, void* l){
  __builtin_amdgcn_global_load_lds((const __attribute__((address_space(1))) unsigned int*)g,
                                   (__attribute__((address_space(3))) unsigned int*)l, 16, 0, 0);
}

// ---------------------------------------------------------------------------
// Shared 256x256 (BK=64) 8-wave 4-phase K-loop (R9 schedule, frozen).
// ---------------------------------------------------------------------------
struct GemmCore {
  char* smem; int t, w, l, wm, wn, lr, lg, bm0, bn0, nk;
  int srow, sslot;
  const unsigned short *A, *B; int lda, ldb;
  f32x4 acc[8][4];
  bf16x8 a0[4][2], a1[4][2], b0[2][2], b1[2][2];

  __device__ __forceinline__ void stage(int kt, int mat, int hf, int q){
    if (kt >= nk) return;
    const int r_h = q*64 + srow;
    const int s_ = sslot ^ ((r_h >> 1) & 7);
    const unsigned short* gp = (mat ? B + (size_t)(bn0 + hf*128 + r_h)*ldb
                                    : A + (size_t)(bm0 + hf*128 + r_h)*lda)
                               + (kt << 6) + s_*8;
    char* lp = smem + mat*65536 + (kt&1)*32768 + hf*16384 + q*8192 + t*16;
    gload_lds16((const void*)gp, (void*)lp);
  }
  __device__ __forceinline__ bf16x8 rdA(int d, int fm, int kk){
    const int r = fm*16 + lr;
    const int s_ = (kk*4 + lg) ^ ((r >> 1) & 7);
    return *(const bf16x8*)(smem + d*32768 + wm*16384 + r*128 + s_*16);
  }
  __device__ __forceinline__ bf16x8 rdB(int d, int fn, int kk){
    const int r = (wn&1)*64 + fn*16 + lr;
    const int s_ = (kk*4 + lg) ^ ((r >> 1) & 7);
    return *(const bf16x8*)(smem + 65536 + d*32768 + (wn>>1)*16384 + r*128 + s_*16);
  }
  __device__ __forceinline__ void ktile(int kt, int d){
    stage(kt+1, 0, 0, 1); stage(kt+1, 0, 1, 1);
    #pragma unroll
    for (int fm=0; fm<4; ++fm){ a0[fm][0] = rdA(d, fm, 0); a0[fm][1] = rdA(d, fm, 1); }
    #pragma unroll
    for (int fn=0; fn<2; ++fn){ b0[fn][0] = rdB(d, fn, 0); b0[fn][1] = rdB(d, fn, 1); }
    __builtin_amdgcn_s_barrier();
    __builtin_amdgcn_s_setprio(1);
    #pragma unroll
    for (int fm=0; fm<4; ++fm)
      #pragma unroll
      for (int fn=0; fn<2; ++fn)
        #pragma unroll
        for (int kk=0; kk<2; ++kk)
          acc[fm][fn] = __builtin_amdgcn_mfma_f32_16x16x32_bf16(a0[fm][kk], b0[fn][kk], acc[fm][fn], 0,0,0);
    __builtin_amdgcn_s_setprio(0);
    #pragma unroll
    for (int fn=0; fn<2; ++fn){ b1[fn][0] = rdB(d, fn+2, 0); b1[fn][1] = rdB(d, fn+2, 1); }
    __builtin_amdgcn_s_barrier();
    __builtin_amdgcn_s_setprio(1);
    #pragma unroll
    for (int fm=0; fm<4; ++fm)
      #pragma unroll
      for (int fn=0; fn<2; ++fn)
        #pragma unroll
        for (int kk=0; kk<2; ++kk)
          acc[fm][fn+2] = __builtin_amdgcn_mfma_f32_16x16x32_bf16(a0[fm][kk], b1[fn][kk], acc[fm][fn+2], 0,0,0);
    __builtin_amdgcn_s_setprio(0);
    stage(kt+2, 0, 0, 0); stage(kt+2, 0, 1, 0);
    stage(kt+2, 1, 0, 0); stage(kt+2, 1, 1, 0);
    #pragma unroll
    for (int fm=0; fm<4; ++fm){ a1[fm][0] = rdA(d, fm+4, 0); a1[fm][1] = rdA(d, fm+4, 1); }
    __builtin_amdgcn_s_barrier();
    __builtin_amdgcn_s_setprio(1);
    #pragma unroll
    for (int fm=0; fm<4; ++fm)
      #pragma unroll
      for (int fn=0; fn<2; ++fn)
        #pragma unroll
        for (int kk=0; kk<2; ++kk)
          acc[fm+4][fn+2] = __builtin_amdgcn_mfma_f32_16x16x32_bf16(a1[fm][kk], b1[fn][kk], acc[fm+4][fn+2], 0,0,0);
    __builtin_amdgcn_s_setprio(0);
    stage(kt+2, 1, 0, 1); stage(kt+2, 1, 1, 1);
    __builtin_amdgcn_s_barrier();
    __builtin_amdgcn_s_setprio(1);
    #pragma unroll
    for (int fm=0; fm<4; ++fm)
      #pragma unroll
      for (int fn=0; fn<2; ++fn)
        #pragma unroll
        for (int kk=0; kk<2; ++kk)
          acc[fm+4][fn] = __builtin_amdgcn_mfma_f32_16x16x32_bf16(a1[fm][kk], b0[fn][kk], acc[fm+4][fn], 0,0,0);
    __builtin_amdgcn_s_setprio(0);
    if (kt + 2 < nk) { asm volatile("s_waitcnt vmcnt(6)" ::: "memory"); }
    else             { asm volatile("s_waitcnt vmcnt(0)" ::: "memory"); }
  }
  __device__ __forceinline__ void run(){
    #pragma unroll
    for (int i=0;i<8;++i)
      #pragma unroll
      for (int j=0;j<4;++j){ f32x4 zz = {0.f,0.f,0.f,0.f}; acc[i][j] = zz; }
    stage(0,0,0,0); stage(0,0,1,0); stage(0,0,0,1); stage(0,0,1,1);
    stage(0,1,0,0); stage(0,1,1,0); stage(0,1,0,1); stage(0,1,1,1);
    stage(1,0,0,0); stage(1,0,1,0);
    stage(1,1,0,0); stage(1,1,1,0);
    stage(1,1,0,1); stage(1,1,1,1);
    asm volatile("s_waitcnt vmcnt(6)" ::: "memory");
    __builtin_amdgcn_s_barrier();
    for (int kt = 0; kt < nk; kt += 2){ ktile(kt, 0); ktile(kt+1, 1); }
  }
  __device__ __forceinline__ void init(char* sm, int Kd, const unsigned short* A_,
                                       const unsigned short* B_, int lda_, int ldb_,
                                       int bm0_, int bn0_){
    smem = sm; t = threadIdx.x; w = t>>6; l = t&63;
    wm = w>>2; wn = w&3; lr = l&15; lg = l>>4;
    srow = t>>3; sslot = t&7;
    A = A_; B = B_; lda = lda_; ldb = ldb_; bm0 = bm0_; bn0 = bn0_;
    nk = Kd >> 6;
  }
};

// MODE 0: bias+GELU dual @4096; 1: bias; 3: V^T
template<int MODE>
__global__ __launch_bounds__(512, 2)
void gemm256(const unsigned short* __restrict__ A, const unsigned short* __restrict__ B,
             const float* __restrict__ bias0, const float* __restrict__ bias1,
             void* __restrict__ C0v, void* __restrict__ C1v,
             int Kd, int lda, int ldb, int ldc)
{
  __shared__ char smem[131072];
  const int nbx = gridDim.x;
  const int nwg = nbx * gridDim.y;
  int bid = blockIdx.y*nbx + blockIdx.x;
  if ((nwg & 7) == 0) bid = (bid & 7)*(nwg >> 3) + (bid >> 3);
  GemmCore g;
  g.init(smem, Kd, A, B, lda, ldb, (bid / nbx) * 256, (bid % nbx) * 256);
  g.run();
  #pragma unroll
  for (int fm=0; fm<8; ++fm){
    #pragma unroll
    for (int fn=0; fn<4; ++fn){
      const int row0 = g.bm0 + g.wm*128 + fm*16 + g.lg*4;
      const int col  = g.bn0 + g.wn*64 + fn*16 + g.lr;
      f32x4 v = g.acc[fm][fn];
      if constexpr (MODE == 3){
        unsigned short* C = (unsigned short*)C0v;
        const float bb = bias0[col];
        u64 pack = 0;
        #pragma unroll
        for (int j=0;j<4;++j) pack |= (u64)f2bf(v[j] + bb) << (16*j);
        *(u64*)(C + (size_t)col*256 + (size_t)(row0>>8)*1048576 + (row0&255)) = pack;
      } else {
        const bool hi = (MODE == 0) && (col >= 4096);
        unsigned short* C = (unsigned short*)(hi ? C1v : C0v);
        const int c2 = hi ? (col - 4096) : col;
        const float bb = hi ? bias1[c2] : bias0[c2];
        #pragma unroll
        for (int j=0;j<4;++j){
          float x = v[j] + bb;
          if constexpr (MODE==0) x = gelu_exact(x);
          C[(size_t)(row0+j)*ldc + c2] = f2bf(x);
        }
      }
    }
  }
}

// Merged Q/K/V: z=0: Q=pp@WqT+bq; z=1: Kb=sp@WkT+bk; z=2: Vt=(sp@WvT+bv)^T
__global__ __launch_bounds__(512, 2)
void gemm_qkv(const unsigned short* __restrict__ App, const unsigned short* __restrict__ Asp,
              const unsigned short* __restrict__ Wqkv,
              const float* __restrict__ bq, const float* __restrict__ bk,
              const float* __restrict__ bv,
              unsigned short* __restrict__ Qo, unsigned short* __restrict__ Ko,
              unsigned short* __restrict__ Vto)
{
  __shared__ char smem[131072];
  const int z = blockIdx.z;
  const int nbx = gridDim.x;
  const int nwg = nbx * gridDim.y;
  int bid = blockIdx.y*nbx + blockIdx.x;
  if ((nwg & 7) == 0) bid = (bid & 7)*(nwg >> 3) + (bid >> 3);
  GemmCore g;
  g.init(smem, 4096, (z==0) ? App : Asp, Wqkv + (size_t)z*16777216, 4096, 4096,
         (bid / nbx) * 256, (bid % nbx) * 256);
  g.run();
  const float* bias = (z==0) ? bq : (z==1) ? bk : bv;
  #pragma unroll
  for (int fm=0; fm<8; ++fm){
    #pragma unroll
    for (int fn=0; fn<4; ++fn){
      const int row0 = g.bm0 + g.wm*128 + fm*16 + g.lg*4;
      const int col  = g.bn0 + g.wn*64 + fn*16 + g.lr;
      f32x4 v = g.acc[fm][fn];
      const float bb = bias[col];
      if (z == 2){
        u64 pack = 0;
        #pragma unroll
        for (int j=0;j<4;++j) pack |= (u64)f2bf(v[j] + bb) << (16*j);
        *(u64*)(Vto + (size_t)col*256 + (size_t)(row0>>8)*1048576 + (row0&255)) = pack;
      } else {
        unsigned short* C = (z==0) ? Qo : Ko;
        #pragma unroll
        for (int j=0;j<4;++j) C[(size_t)(row0+j)*4096 + col] = f2bf(v[j] + bb);
      }
    }
  }
}

// ---------------------------------------------------------------------------
// 128x128 (BK=32) bf16 MFMA GEMM (attention). MODE 2: *scale->fp32.
// MODE 5: *scale->bf16 (PV -> intf).
// ---------------------------------------------------------------------------
template<int MODE>
__global__ __launch_bounds__(256)
void gemm_bt(const unsigned short* __restrict__ A, const unsigned short* __restrict__ B,
             const float* __restrict__ bias, void* __restrict__ Cv,
             int Kd, int lda, int ldb, int ldc,
             long sA2, long sA1, long sB2, long sB1, long sC2, long sC1,
             float scale)
{
  __shared__ unsigned short lds[2][2][4096];
  const int t = threadIdx.x;
  const int w = t >> 6, l = t & 63;
  const int z = blockIdx.z;
  A += (size_t)(z>>2)*sA2 + (size_t)(z&3)*sA1;
  B += (size_t)(z>>2)*sB2 + (size_t)(z&3)*sB1;
  const int bm0 = blockIdx.y * 128, bn0 = blockIdx.x * 128;
  const int nk = Kd >> 5;

  const int sr = l >> 2;
  const int ss = l & 3;

  f32x4 acc[4][4];
  #pragma unroll
  for (int i=0;i<4;++i){
    #pragma unroll
    for (int j=0;j<4;++j){ f32x4 zz = {0.f,0.f,0.f,0.f}; acc[i][j] = zz; }
  }

  const int wm = w >> 1, wn = w & 1;
  const int lr = l & 15, lg = l >> 4;

  auto stage = [&](int kt, int bb){
    const int k0 = kt << 5;
    #pragma unroll
    for (int i=0;i<2;++i){
      const int r  = w*32 + i*16 + sr;
      const int sa = ss ^ ((r>>1)&3);
      const unsigned short* ga = A + (size_t)(bm0 + r)*lda + (k0 + sa*8);
      gload_lds16((const void*)ga, (void*)((char*)&lds[bb][0][0] + w*2048 + i*1024));
      const unsigned short* gb = B + (size_t)(bn0 + r)*ldb + (k0 + sa*8);
      gload_lds16((const void*)gb, (void*)((char*)&lds[bb][1][0] + w*2048 + i*1024));
    }
  };

  int buf = 0;
  stage(0, 0);
  for (int kt=0; kt<nk; ++kt){
    __syncthreads();
    if (kt+1 < nk) stage(kt+1, buf^1);
    bf16x8 av[4], bv[4];
    #pragma unroll
    for (int fm=0; fm<4; ++fm){
      const int row = wm*64 + fm*16 + lr;
      const int sl  = lg ^ ((row>>1)&3);
      av[fm] = *(const bf16x8*)((const char*)&lds[buf][0][0] + row*64 + sl*16);
    }
    #pragma unroll
    for (int fn=0; fn<4; ++fn){
      const int col = wn*64 + fn*16 + lr;
      const int sl  = lg ^ ((col>>1)&3);
      bv[fn] = *(const bf16x8*)((const char*)&lds[buf][1][0] + col*64 + sl*16);
    }
    #pragma unroll
    for (int fm=0; fm<4; ++fm){
      #pragma unroll
      for (int fn=0; fn<4; ++fn)
        acc[fm][fn] = __builtin_amdgcn_mfma_f32_16x16x32_bf16(av[fm], bv[fn], acc[fm][fn], 0,0,0);
    }
    buf ^= 1;
  }

  const size_t coff = (size_t)(z>>2)*sC2 + (size_t)(z&3)*sC1;
  #pragma unroll
  for (int fm=0; fm<4; ++fm){
    #pragma unroll
    for (int fn=0; fn<4; ++fn){
      const int row0 = bm0 + wm*64 + fm*16 + lg*4;
      const int col  = bn0 + wn*64 + fn*16 + lr;
      f32x4 v = acc[fm][fn];
      if constexpr (MODE == 2){
        float* C = (float*)Cv + coff;
        #pragma unroll
        for (int j=0;j<4;++j) C[(size_t)(row0+j)*ldc + col] = v[j]*scale;
      } else if constexpr (MODE == 5){
        unsigned short* C = (unsigned short*)Cv + coff;
        #pragma unroll
        for (int j=0;j<4;++j) C[(size_t)(row0+j)*ldc + col] = f2bf(v[j]*scale);
      }
    }
  }
}

// ---------------------------------------------------------------------------
__global__ __launch_bounds__(256)
void k_convh(const float* __restrict__ in, unsigned short* __restrict__ out){
  const size_t id = (size_t)blockIdx.x*256 + threadIdx.x;
  float4 v = ((const float4*)in)[id];
  u64 pack = (u64)f2bf(v.x) | ((u64)f2bf(v.y)<<16) | ((u64)f2bf(v.z)<<32) | ((u64)f2bf(v.w)<<48);
  *(u64*)(out + id*4) = pack;
}

__global__ __launch_bounds__(256)
void k_tconv(const float* __restrict__ W, unsigned short* __restrict__ Wt, int Kd, int N){
  __shared__ float lt[64][65];
  const int t = threadIdx.x;
  const int n0 = blockIdx.x*64, k0 = blockIdx.y*64;
  #pragma unroll
  for (int i=0;i<16;++i){
    int lin = i*256 + t; int r = lin>>6, c = lin&63;
    lt[r][c] = W[(size_t)(k0+r)*N + n0 + c];
  }
  __syncthreads();
  #pragma unroll
  for (int i=0;i<16;++i){
    int lin = i*256 + t; int n = lin>>6, k = lin&63;
    Wt[(size_t)(n0+n)*Kd + k0 + k] = f2bf(lt[k][n]);
  }
}

__global__ __launch_bounds__(256)
void k_tconv3(const float* __restrict__ W0, const float* __restrict__ W1,
              const float* __restrict__ W2, unsigned short* __restrict__ Wt,
              int Kd, int N, long wtStride){
  __shared__ float lt[64][65];
  const int t = threadIdx.x;
  const int zz = blockIdx.z;
  const float* W = (zz==0) ? W0 : (zz==1) ? W1 : W2;
  unsigned short* Wtz = Wt + (size_t)zz * wtStride;
  const int n0 = blockIdx.x*64, k0 = blockIdx.y*64;
  #pragma unroll
  for (int i=0;i<16;++i){
    int lin = i*256 + t; int r = lin>>6, c = lin&63;
    lt[r][c] = W[(size_t)(k0+r)*N + n0 + c];
  }
  __syncthreads();
  #pragma unroll
  for (int i=0;i<16;++i){
    int lin = i*256 + t; int n = lin>>6, k = lin&63;
    Wtz[(size_t)(n0+n)*Kd + k0 + k] = f2bf(lt[k][n]);
  }
}

__global__ __launch_bounds__(256)
void k_softmax(const float* __restrict__ S, unsigned short* __restrict__ P){
  const int t = threadIdx.x, w = t>>6, l = t&63;
  const size_t row = (size_t)blockIdx.x*4 + w;
  float4 v = *(const float4*)(S + row*256 + l*4);
  float m = fmaxf(fmaxf(v.x,v.y), fmaxf(v.z,v.w));
  #pragma unroll
  for (int off=32; off; off>>=1) m = fmaxf(m, __shfl_xor(m, off));
  float e0 = expf(v.x-m), e1 = expf(v.y-m), e2 = expf(v.z-m), e3 = expf(v.w-m);
  float s = e0+e1+e2+e3;
  #pragma unroll
  for (int off=32; off; off>>=1) s += __shfl_xor(s, off);
  const float inv = 1.0f/s;
  u64 pack = (u64)f2bf(e0*inv) | ((u64)f2bf(e1*inv)<<16) | ((u64)f2bf(e2*inv)<<32) | ((u64)f2bf(e3*inv)<<48);
  *(u64*)(P + row*256 + l*4) = pack;
}

__device__ __forceinline__ void blkred2(float& a, float& b, float* sred, int t){
  #pragma unroll
  for (int off=32; off; off>>=1){ a += __shfl_xor(a, off); b += __shfl_xor(b, off); }
  __syncthreads();
  if ((t&63)==0){ sred[(t>>6)*2] = a; sred[(t>>6)*2+1] = b; }
  __syncthreads();
  a = sred[0]+sred[2]+sred[4]+sred[6];
  b = sred[1]+sred[3]+sred[5]+sred[7];
}

__device__ __forceinline__ void blkred4(float& a, float& b, float& c, float& d,
                                        float* sred, int t){
  #pragma unroll
  for (int off=32; off; off>>=1){
    a += __shfl_xor(a, off); b += __shfl_xor(b, off);
    c += __shfl_xor(c, off); d += __shfl_xor(d, off);
  }
  __syncthreads();
  if ((t&63)==0){
    sred[(t>>6)*4]   = a; sred[(t>>6)*4+1] = b;
    sred[(t>>6)*4+2] = c; sred[(t>>6)*4+3] = d;
  }
  __syncthreads();
  a = sred[0]+sred[4]+sred[8]+sred[12];
  b = sred[1]+sred[5]+sred[9]+sred[13];
  c = sred[2]+sred[6]+sred[10]+sred[14];
  d = sred[3]+sred[7]+sred[11]+sred[15];
}

// intf is bf16.
__global__ __launch_bounds__(256)
void k_stats(const float* __restrict__ h, const unsigned short* __restrict__ intf,
             const unsigned short* __restrict__ sp,
             const float* __restrict__ g_pfs, const float* __restrict__ b_pfs,
             const float* __restrict__ g_sfs, const float* __restrict__ b_sfs,
             float* __restrict__ part_p, float* __restrict__ part_s, int g0)
{
  __shared__ float sred[16];
  const int bl = blockIdx.x, grp = blockIdx.y, t = threadIdx.x;
  float zacc[20], wacc[16];
  #pragma unroll
  for (int j=0;j<20;++j) zacc[j]=0.f;
  #pragma unroll
  for (int j=0;j<16;++j) wacc[j]=0.f;
  for (int rr=0; rr<16; ++rr){
    const size_t r = (size_t)bl*256 + grp*16 + rr;
    float hv[4], iv[16], sv[16];
    #pragma unroll
    for (int j=0;j<4;++j) hv[j] = h[r*1024 + j*256 + t];
    float s1=0.f, s2=0.f;
    #pragma unroll
    for (int j=0;j<16;++j){ float x = bf2f(intf[r*4096 + j*256 + t]); iv[j]=x; s1+=x; s2+=x*x; }
    float u1=0.f, u2=0.f;
    #pragma unroll
    for (int j=0;j<16;++j){ float x = bf2f(sp[r*4096 + j*256 + t]); sv[j]=x; u1+=x; u2+=x*x; }
    blkred4(s1,s2,u1,u2,sred,t);
    const float m1 = s1*(1.f/4096.f);
    const float rs1 = rsqrtf(fmaxf(s2*(1.f/4096.f) - m1*m1, 0.f) + EPSV);
    const float m3 = u1*(1.f/4096.f);
    const float rs3 = rsqrtf(fmaxf(u2*(1.f/4096.f) - m3*m3, 0.f) + EPSV);
    #pragma unroll
    for (int j=0;j<16;++j){ int idx = j*256+t; wacc[j] += ((sv[j]-m3)*rs3)*g_sfs[idx] + b_sfs[idx]; }
    float t1=0.f, t2=0.f;
    #pragma unroll
    for (int j=0;j<4;++j){ t1 += hv[j]; t2 += hv[j]*hv[j]; }
    #pragma unroll
    for (int j=0;j<16;++j){ float y = (iv[j]-m1)*rs1; iv[j]=y; t1+=y; t2+=y*y; }
    blkred2(t1,t2,sred,t);
    const float m2 = t1*(1.f/5120.f);
    const float rs2 = rsqrtf(fmaxf(t2*(1.f/5120.f) - m2*m2, 0.f) + EPSV);
    #pragma unroll
    for (int j=0;j<4;++j){ int idx = j*256+t; zacc[j] += ((hv[j]-m2)*rs2)*g_pfs[idx] + b_pfs[idx]; }
    #pragma unroll
    for (int j=0;j<16;++j){ int idx = 1024 + j*256+t; zacc[4+j] += ((iv[j]-m2)*rs2)*g_pfs[idx] + b_pfs[idx]; }
  }
  const size_t pb = (size_t)(g0 + bl)*16 + grp;
  #pragma unroll
  for (int j=0;j<20;++j) part_p[pb*5120 + j*256 + t] = zacc[j];
  #pragma unroll
  for (int j=0;j<16;++j) part_s[pb*4096 + j*256 + t] = wacc[j];
}

__global__ __launch_bounds__(256)
void k_reduce(const float* __restrict__ part_p, const float* __restrict__ part_s,
              float* __restrict__ xbar, float* __restrict__ ybar){
  int id = blockIdx.x*256 + threadIdx.x;
  if (id < 32*5120){
    const int b = id / 5120, i = id % 5120;
    float s = 0.f;
    for (int g=0; g<16; ++g) s += part_p[((size_t)b*16+g)*5120 + i];
    xbar[(size_t)b*5120 + i] = s * (1.f/256.f);
  } else {
    id -= 32*5120;
    const int b = id / 4096, i = id % 4096;
    float s = 0.f;
    for (int g=0; g<16; ++g) s += part_s[((size_t)b*16+g)*4096 + i];
    ybar[(size_t)b*4096 + i] = s * (1.f/256.f);
  }
}

__global__ __launch_bounds__(256)
void k_proj_part(const float* __restrict__ xbar, const float* __restrict__ ybar,
                 const float* __restrict__ Wpfs, const float* __restrict__ Wsfs,
                 float* __restrict__ pbuf){
  const int path = blockIdx.z;
  const int y = blockIdx.y;
  if (path == 1 && y >= 8) return;
  const int Kp = path ? 4096 : 5120;
  const float* X = path ? ybar : xbar;
  const float* W = path ? Wsfs : Wpfs;
  const int t = threadIdx.x;
  const int col = blockIdx.x*64 + (t & 63);
  const int sub = t >> 6;
  const int k0 = y*512 + sub*128;
  float acc[32];
  #pragma unroll
  for (int b=0;b<32;++b) acc[b] = 0.f;
  for (int i4=0; i4<32; ++i4){
    const int k = k0 + i4*4;
    float wv0 = W[(size_t)(k  )*1024 + col];
    float wv1 = W[(size_t)(k+1)*1024 + col];
    float wv2 = W[(size_t)(k+2)*1024 + col];
    float wv3 = W[(size_t)(k+3)*1024 + col];
    #pragma unroll
    for (int b=0;b<32;++b){
      float4 xv = *(const float4*)(X + (size_t)b*Kp + k);
      acc[b] += xv.x*wv0 + xv.y*wv1 + xv.z*wv2 + xv.w*wv3;
    }
  }
  float* dst = pbuf + ((size_t)(path*40 + y*4 + sub)*32)*1024 + col;
  #pragma unroll
  for (int b=0;b<32;++b) dst[(size_t)b*1024] = acc[b];
}

__global__ __launch_bounds__(256)
void k_projred(const float* __restrict__ pbuf,
               const float* __restrict__ bpfs, const float* __restrict__ bsfs,
               float* __restrict__ tpre, float* __restrict__ spre){
  const int id = blockIdx.x*256 + threadIdx.x;
  const int path = id >> 15;
  const int rem = id & 32767;
  const int b = rem >> 10, col = rem & 1023;
  const int ns = path ? 32 : 40;
  const float* src = pbuf + ((size_t)(path*40)*32 + b)*1024 + col;
  float s = path ? bsfs[col] : bpfs[col];
  for (int g=0; g<ns; ++g) s += src[(size_t)g*32*1024];
  (path ? spre : tpre)[(size_t)b*1024 + col] = s;
}

__global__ __launch_bounds__(256)
void k_lnrow(const float* __restrict__ tpre, const float* __restrict__ spre,
             float* __restrict__ out){
  __shared__ float sred[16];
  const int id = blockIdx.x, t = threadIdx.x;
  const int path = id >> 5, b = id & 31;
  const float* src = (path ? spre : tpre) + (size_t)b*1024;
  float v[4]; float s1=0.f, s2=0.f;
  #pragma unroll
  for (int j=0;j<4;++j){ v[j] = src[j*256+t]; s1 += v[j]; s2 += v[j]*v[j]; }
  blkred2(s1,s2,sred,t);
  const float m = s1*(1.f/1024.f);
  const float rs = rsqrtf(fmaxf(s2*(1.f/1024.f)-m*m,0.f)+EPSV);
  float* dst = out + (path ? 35072 : 2304) + (size_t)b*1024;
  #pragma unroll
  for (int j=0;j<4;++j) dst[j*256+t] = (v[j]-m)*rs;
}

__global__ __launch_bounds__(256)
void k_head(const float* __restrict__ Wpc, const float* __restrict__ bpc,
            const float* __restrict__ Wc0, const float* __restrict__ bc0,
            const float* __restrict__ Wc1, const float* __restrict__ bc1,
            const float* __restrict__ Wc2, const float* __restrict__ bc2,
            float* __restrict__ out){
  __shared__ float slog[16];
  __shared__ int sy;
  const int b = blockIdx.x, t = threadIdx.x, w = t>>6, l = t&63;
  const float* pv = out + 2304 + (size_t)b*1024;
  const float* sv = out + 35072 + (size_t)b*1024;
  #pragma unroll
  for (int jj=0; jj<4; ++jj){
    const int j = w*4 + jj;
    float a = 0.f;
    for (int i=l; i<1024; i+=64) a += pv[i]*Wpc[(size_t)i*16 + j];
    #pragma unroll
    for (int off=32; off; off>>=1) a += __shfl_xor(a, off);
    if (l==0){ const float lgv = a + bpc[j]; slog[j] = lgv; out[b*16 + j] = lgv; }
  }
  __syncthreads();
  if (t==0){
    int best=0; float bvv = slog[0];
    for (int i=1;i<16;++i) if (slog[i] > bvv){ bvv = slog[i]; best = i; }
    sy = best;
  }
  __syncthreads();
  const int y = sy;
  const float* Ws[3] = {Wc0, Wc1, Wc2};
  const float* bs[3] = {bc0, bc1, bc2};
  const int nouts[3] = {8,16,32};
  const int ooff[3]  = {512, 768, 1280};
  for (int hI=0; hI<3; ++hI){
    const int no = nouts[hI];
    for (int n = w; n < no; n += 4){
      const float* wr = Ws[hI] + ((size_t)y*no + n)*1024;
      float a = 0.f;
      for (int i=l; i<1024; i+=64) a += sv[i]*wr[i];
      #pragma unroll
      for (int off=32; off; off>>=1) a += __shfl_xor(a, off);
      if (l==0) out[ooff[hI] + b*no + n] = a + bs[hI][(size_t)y*no + n];
    }
  }
}

// ---------------------------------------------------------------------------
extern "C" void kernel_launch(void* const* d_in, const int* in_sizes, int n_in,
                              void* d_out, int out_size, void* d_ws, size_t ws_size,
                              hipStream_t stream)
{
  const float* h    = (const float*)d_in[0];
  const float* Wpp  = (const float*)d_in[1];
  const float* bpp  = (const float*)d_in[2];
  const float* Wsp  = (const float*)d_in[3];
  const float* bsp  = (const float*)d_in[4];
  const float* Wq   = (const float*)d_in[5];
  const float* bq   = (const float*)d_in[6];
  const float* Wk   = (const float*)d_in[7];
  const float* bk   = (const float*)d_in[8];
  const float* Wv   = (const float*)d_in[9];
  const float* bv   = (const float*)d_in[10];
  const float* g_pfs= (const float*)d_in[11];
  const float* b_pfs= (const float*)d_in[12];
  const float* Wpfs = (const float*)d_in[13];
  const float* bpfs = (const float*)d_in[14];
  const float* g_sfs= (const float*)d_in[15];
  const float* b_sfs= (const float*)d_in[16];
  const float* Wsfs = (const float*)d_in[17];
  const float* bsfs = (const float*)d_in[18];
  const float* Wpc  = (const float*)d_in[19];
  const float* bpc  = (const float*)d_in[20];
  const float* Wc0  = (const float*)d_in[21];
  const float* bc0  = (const float*)d_in[22];
  const float* Wc1  = (const float*)d_in[23];
  const float* bc1  = (const float*)d_in[24];
  const float* Wc2  = (const float*)d_in[25];
  const float* bc2  = (const float*)d_in[26];
  float* out = (float*)d_out;
  char* ws = (char*)d_ws;
  (void)in_sizes; (void)n_in; (void)out_size;

  const float scale = 1.0f/32.0f;

  // ---- tier 3 (shrunk): single-pass G=32, ~289.4 MiB ----
  // wbuf(32MB): [WppT;WspT](16) -> WqT -> WkT -> WvT -> S(32,fp32) -> partials(18)
  // oA(64): pp -> Vt      oB(64): sp
  // oC(64): Q -> intf(bf16)
  // oD(64): h_bf(16) -> Kb(64) -> P(16,bf16) -> pbuf(10)
  {
    size_t off = 0;
    auto alloc = [&](size_t bytes){ size_t o = off; off += (bytes + 255) & ~255ULL; return o; };
    size_t oWb  = alloc(4096ULL*4096*2);       // 32MB
    size_t oA   = alloc(64ULL<<20);
    size_t oB   = alloc(64ULL<<20);
    size_t oC   = alloc(64ULL<<20);
    size_t oD   = alloc(64ULL<<20);
    size_t oXb  = alloc(32*5120*4);
    size_t oYb  = alloc(32*4096*4);
    size_t oTp  = alloc(32*1024*4);
    size_t oSp  = alloc(32*1024*4);
    if (off <= ws_size){
      unsigned short* wbuf = (unsigned short*)(ws + oWb);
      unsigned short* pp   = (unsigned short*)(ws + oA);
      unsigned short* Vt   = (unsigned short*)(ws + oA);
      unsigned short* sp   = (unsigned short*)(ws + oB);
      unsigned short* Q    = (unsigned short*)(ws + oC);
      unsigned short* intf = (unsigned short*)(ws + oC);
      unsigned short* h_bf = (unsigned short*)(ws + oD);
      unsigned short* Kb   = (unsigned short*)(ws + oD);
      unsigned short* P    = (unsigned short*)(ws + oD);
      float* pbuf   = (float*)(ws + oD);
      float* S      = (float*)(ws + oWb);
      float* part_p = (float*)(ws + oWb);
      float* part_s = (float*)(ws + oWb + ((32ULL*16*5120*4 + 255) & ~255ULL));
      float* xbar   = (float*)(ws + oXb);
      float* ybar   = (float*)(ws + oYb);
      float* tpre   = (float*)(ws + oTp);
      float* spre   = (float*)(ws + oSp);

      // ppsp weights -> wbuf (16MB of 32MB)
      hipLaunchKernelGGL(k_tconv, dim3(64,16), dim3(256), 0, stream, Wpp, wbuf, 1024, 4096);
      hipLaunchKernelGGL(k_tconv, dim3(64,16), dim3(256), 0, stream, Wsp, wbuf + 4096ULL*1024, 1024, 4096);
      hipLaunchKernelGGL(k_convh, dim3(8192), dim3(256), 0, stream, h, h_bf);
      // pp,sp = gelu(h @ [Wpp;Wsp])  (M=8192, N=8192; 1024 blocks)
      hipLaunchKernelGGL(gemm256<0>, dim3(32,32), dim3(512), 0, stream,
                         h_bf, wbuf, bpp, bsp, (void*)pp, (void*)sp, 1024, 1024,1024,4096);
      // Q = pp @ Wq   (wbuf: ppsp weights dead)
      hipLaunchKernelGGL(k_tconv, dim3(64,64), dim3(256), 0, stream, Wq, wbuf, 4096, 4096);
      hipLaunchKernelGGL(gemm256<1>, dim3(16,32), dim3(512), 0, stream,
                         pp, wbuf, bq, bq, (void*)Q, (void*)Q, 4096, 4096,4096,4096);
      // Kb = sp @ Wk  (over h_bf region; h_bf dead after ppsp)
      hipLaunchKernelGGL(k_tconv, dim3(64,64), dim3(256), 0, stream, Wk, wbuf, 4096, 4096);
      hipLaunchKernelGGL(gemm256<1>, dim3(16,32), dim3(512), 0, stream,
                         sp, wbuf, bk, bk, (void*)Kb, (void*)Kb, 4096, 4096,4096,4096);
      // Vt = (sp @ Wv)^T  (over pp region; pp dead after Q)
      hipLaunchKernelGGL(k_tconv, dim3(64,64), dim3(256), 0, stream, Wv, wbuf, 4096, 4096);
      hipLaunchKernelGGL(gemm256<3>, dim3(16,32), dim3(512), 0, stream,
                         sp, wbuf, bv, bv, (void*)Vt, (void*)Vt, 4096, 4096,4096,256);
      // S = scale*Q K^T  (S over wbuf; Wv weights dead)
      hipLaunchKernelGGL(gemm_bt<2>, dim3(2,2,128), dim3(256), 0, stream,
                         Q, Kb, (const float*)nullptr, (void*)S, 1024, 4096,4096,256,
                         1048576L,1024L, 1048576L,1024L, 262144L,65536L, scale);
      // softmax -> P (over Kb region; Kb dead after S)
      hipLaunchKernelGGL(k_softmax, dim3(8192), dim3(256), 0, stream, S, P);
      // intf(bf16) = P V  (over Q region; Q dead after S)
      hipLaunchKernelGGL(gemm_bt<5>, dim3(8,2,128), dim3(256), 0, stream,
                         P, Vt, (const float*)nullptr, (void*)intf, 256, 256,256,4096,
                         262144L,65536L, 1048576L,262144L, 1048576L,1024L, 1.f);
      // stats (partials over wbuf; S dead after softmax)
      hipLaunchKernelGGL(k_stats, dim3(32,16), dim3(256), 0, stream,
                         h, intf, sp, g_pfs, b_pfs, g_sfs, b_sfs, part_p, part_s, 0);
      hipLaunchKernelGGL(k_reduce, dim3(1152), dim3(256), 0, stream, part_p, part_s, xbar, ybar);
      // proj (pbuf over oD; P dead after PV)
      hipLaunchKernelGGL(k_proj_part, dim3(16,10,2), dim3(256), 0, stream,
                         xbar, ybar, Wpfs, Wsfs, pbuf);
      hipLaunchKernelGGL(k_projred, dim3(256), dim3(256), 0, stream,
                         pbuf, bpfs, bsfs, tpre, spre);
      hipLaunchKernelGGL(k_lnrow, dim3(64), dim3(256), 0, stream, tpre, spre, out);
      hipLaunchKernelGGL(k_head, dim3(32), dim3(256), 0, stream,
                         Wpc, bpc, Wc0, bc0, Wc1, bc1, Wc2, bc2, out);
      return;
    }
  }

  // ---- tier 2 fallback: R12/R13 plan (G=16, merged qkv dispatch) ----
  struct PlanT { int G, hoist; };
  const PlanT plans[3] = {{16,2},{16,1},{8,1}};
  int G = 0, HOIST = 0;
  size_t oWps=0,oWq=0,oSP=0;
  size_t oPp=0,oPs=0,oXb=0,oYb=0,oTp=0,oSp=0,oPbf=0,oHb=0,oPb=0,oSb=0,oQ=0,oK=0,oVt=0;
  for (int pi = 0; pi < 3; ++pi){
    const size_t g = plans[pi].G;
    const int hoist = plans[pi].hoist;
    size_t off = 0;
    auto alloc = [&](size_t bytes){ size_t o = off; off += (bytes + 255) & ~255ULL; return o; };
    size_t wps = alloc(8192ULL*1024*2);
    size_t wq  = alloc(3*4096ULL*4096*2);
    size_t pp_ = alloc(32ULL*16*5120*4);
    size_t ps_ = alloc(32ULL*16*4096*4);
    size_t xb = alloc(32*5120*4); size_t yb = alloc(32*4096*4);
    size_t tp = alloc(32*1024*4); size_t sp_ = alloc(32*1024*4);
    size_t sb = alloc(g*2097152);
    size_t q  = alloc(g*2097152);
    size_t k  = alloc(g*2097152);
    size_t vt = alloc(g*2097152);
    size_t sp2, pb;
    if (hoist == 2){ sp2 = alloc(g*2097152); pb = sp2; }
    else           { sp2 = alloc(g*1572864); pb = k; }
    if (off <= ws_size){
      G = (int)g; HOIST = hoist;
      oWps=wps; oWq=wq; oSP=sp2;
      oPp=pp_; oPs=ps_; oXb=xb; oYb=yb; oTp=tp; oSp=sp_; oPbf=q;
      oHb=vt; oPb=pb; oSb=sb; oQ=q; oK=k; oVt=vt;
      break;
    }
  }
  if (!G) return;

  unsigned short* WpsT  = (unsigned short*)(ws + oWps);
  unsigned short* WqkvT = (unsigned short*)(ws + oWq);
  float* part_p = (float*)(ws + oPp);
  float* part_s = (float*)(ws + oPs);
  float* xbar   = (float*)(ws + oXb);
  float* ybar   = (float*)(ws + oYb);
  float* tpre   = (float*)(ws + oTp);
  float* spre   = (float*)(ws + oSp);
  float* pbuf   = (float*)(ws + oPbf);
  unsigned short* h_bf = (unsigned short*)(ws + oHb);
  unsigned short* pp   = (unsigned short*)(ws + oPb);
  unsigned short* sp   = (unsigned short*)(ws + oSb);
  unsigned short* Q    = (unsigned short*)(ws + oQ);
  unsigned short* Kb   = (unsigned short*)(ws + oK);
  unsigned short* Vt   = (unsigned short*)(ws + oVt);
  float*          S    = (float*)(ws + oSP);
  unsigned short* P    = (unsigned short*)(ws + oSP + (size_t)G*1048576);
  unsigned short* intf = (unsigned short*)(ws + oQ);

  hipLaunchKernelGGL(k_tconv, dim3(64,16), dim3(256), 0, stream, Wpp, WpsT, 1024, 4096);
  hipLaunchKernelGGL(k_tconv, dim3(64,16), dim3(256), 0, stream, Wsp, WpsT + 4096ULL*1024, 1024, 4096);
  hipLaunchKernelGGL(k_tconv3, dim3(64,64,3), dim3(256), 0, stream,
                     Wq, Wk, Wv, WqkvT, 4096, 4096, 16777216L);

  for (int g0 = 0; g0 < 32; g0 += G){
    const float* h_g = h + (size_t)g0*262144;
    hipLaunchKernelGGL(k_convh, dim3(G*256), dim3(256), 0, stream, h_g, h_bf);
    hipLaunchKernelGGL(gemm256<0>, dim3(32,G), dim3(512), 0, stream,
                       h_bf, WpsT, bpp, bsp, (void*)pp, (void*)sp, 1024, 1024,1024,4096);
    if (HOIST == 2){
      hipLaunchKernelGGL(gemm_qkv, dim3(16,G,3), dim3(512), 0, stream,
                         pp, sp, WqkvT, bq, bk, bv, Q, Kb, Vt);
    } else {
      hipLaunchKernelGGL(gemm256<1>, dim3(16,G), dim3(512), 0, stream,
                         pp, WqkvT, bq, bq, (void*)Q, (void*)Q, 4096, 4096,4096,4096);
      hipLaunchKernelGGL(gemm256<1>, dim3(16,G), dim3(512), 0, stream,
                         sp, WqkvT + 16777216ULL, bk, bk, (void*)Kb, (void*)Kb, 4096, 4096,4096,4096);
      hipLaunchKernelGGL(gemm256<3>, dim3(16,G), dim3(512), 0, stream,
                         sp, WqkvT + 33554432ULL, bv, bv, (void*)Vt, (void*)Vt, 4096, 4096,4096,256);
    }
    hipLaunchKernelGGL(gemm_bt<2>, dim3(2,2,G*4), dim3(256), 0, stream,
                       Q, Kb, (const float*)nullptr, (void*)S, 1024, 4096,4096,256,
                       1048576L,1024L, 1048576L,1024L, 262144L,65536L, scale);
    hipLaunchKernelGGL(k_softmax, dim3(G*256), dim3(256), 0, stream, S, P);
    hipLaunchKernelGGL(gemm_bt<5>, dim3(8,2,G*4), dim3(256), 0, stream,
                       P, Vt, (const float*)nullptr, (void*)intf, 256, 256,256,4096,
                       262144L,65536L, 1048576L,262144L, 1048576L,1024L, 1.f);
    hipLaunchKernelGGL(k_stats, dim3(G,16), dim3(256), 0, stream,
                       h_g, intf, sp, g_pfs, b_pfs, g_sfs, b_sfs, part_p, part_s, g0);
  }

  hipLaunchKernelGGL(k_reduce, dim3(1152), dim3(256), 0, stream, part_p, part_s, xbar, ybar);
  hipLaunchKernelGGL(k_proj_part, dim3(16,10,2), dim3(256), 0, stream,
                     xbar, ybar, Wpfs, Wsfs, pbuf);
  hipLaunchKernelGGL(k_projred, dim3(256), dim3(256), 0, stream,
                     pbuf, bpfs, bsfs, tpre, spre);
  hipLaunchKernelGGL(k_lnrow, dim3(64), dim3(256), 0, stream, tpre, spre, out);
  hipLaunchKernelGGL(k_head, dim3(32), dim3(256), 0, stream,
                     Wpc, bpc, Wc0, bc0, Wc1, bc1, Wc2, bc2, out);
}